// Round 1
// baseline (1571.283 us; speedup 1.0000x reference)
//
#include <hip/hip_runtime.h>
#include <math.h>

// MultiPerspectiveMatch on MI355X — round 1: correct fp32, structured for VALU.
// Shapes: B=32, L(q)=L(d)=200, K=200, C=50. Output [B,200,250] f32.
// Pipeline (9 launches):
//  k_m2        : M2all[4][50][200] = M*M          (full, maxpool, att, maxatt)
//  k_pnorm     : inv plain norms of d,q rows
//  k_gemm1     : nsqT[n][row] = (row^2) @ M2all^T  rows = [d | q | q_last]
//  k_inv       : rsqrt(max(nsq,eps)) scattered into consumer-friendly layouts
//  k_rel       : rel[b][i][j] + 1/(sum_j+eps) + argmax_j (first-max tie-break)
//  k_wq        : wq[b][i][k] = rel @ q / (sum+eps)
//  k_gemm2     : G[m'][row][c] numerators (d*ql, d*wq, wq^2, d*q[argmax]) @ M2
//  k_epi       : out cols 0:50, 150:200, 200:250
//  k_maxpool   : out cols 50:150  (the 12.8 GMAC kernel, t-factorized)

#define EPS 1e-6f
#define NEG_HUGE -3.4e38f

// ---- ws offsets (floats) ----
constexpr size_t OFF_M2ALL = 0;            // 4*50*200 = 40000
constexpr size_t OFF_NSQT  = 40000;        // 200*12832
constexpr size_t OFF_INVFPN= 2606400;      // [row(6400)][50]
constexpr size_t OFF_INVMPN= 2926400;      // [row][50]
constexpr size_t OFF_INVAPN= 3246400;      // [row][50]
constexpr size_t OFF_INVXPN= 3566400;      // [row][50]
constexpr size_t OFF_INVMQN= 3886400;      // [c(50)][b*200+j]  (lane-coalesced for k_maxpool)
constexpr size_t OFF_INVXQN= 4206400;      // [b*200+j][50]
constexpr size_t OFF_INVFQN= 4526400;      // [b][50]
constexpr size_t OFF_INVDN = 4528000;      // [b*200+i]
constexpr size_t OFF_INVQN = 4534400;      // [b*200+j]
constexpr size_t OFF_REL   = 4540800;      // [b][i][j]
constexpr size_t OFF_INVRS = 5820800;      // [b*200+i]
constexpr size_t OFF_IDX   = 5827200;      // int [b*200+i]
constexpr size_t OFF_WQ    = 5833600;      // [b][i][k]
constexpr size_t OFF_G     = 7113600;      // [m'(4)][row(6400)][50]
// end = 8393600 floats = 33.6 MB

__global__ void k_m2(const float* __restrict__ fM, const float* __restrict__ mM,
                     const float* __restrict__ aM, const float* __restrict__ xM,
                     float* __restrict__ m2all)
{
  int i = blockIdx.x*256 + threadIdx.x;
  if (i >= 40000) return;
  int m = i / 10000, r = i % 10000;
  const float* s = (m==0)?fM:(m==1)?mM:(m==2)?aM:xM;
  float v = s[r];
  m2all[i] = v*v;
}

__global__ void k_pnorm(const float* __restrict__ dR, const float* __restrict__ qR,
                        float* __restrict__ invdn, float* __restrict__ invqn)
{
  int row = blockIdx.x; int l = threadIdx.x;
  const float* src = (row < 6400) ? dR + row*200 : qR + (row-6400)*200;
  float s = 0.f;
  for (int k = l; k < 200; k += 64) { float v = src[k]; s = fmaf(v, v, s); }
#pragma unroll
  for (int m = 32; m; m >>= 1) s += __shfl_xor(s, m);
  if (l == 0) {
    float r = rsqrtf(fmaxf(s, EPS));
    if (row < 6400) invdn[row] = r; else invqn[row-6400] = r;
  }
}

// rows = [d(6400) | q(6400) | q_last(32)]; each wave owns one 50-col n-tile.
__global__ __launch_bounds__(256) void k_gemm1(
    const float* __restrict__ dR, const float* __restrict__ qR,
    const float* __restrict__ qL, const float* __restrict__ m2all,
    float* __restrict__ nsqT)
{
  __shared__ float ash[16*65];
  int tid = threadIdx.x;
  int lane = tid & 63;
  int wavei = __builtin_amdgcn_readfirstlane(tid >> 6);
  int m0 = blockIdx.x * 64;
  const float* Bm = m2all + wavei*10000;
  float acc[50];
#pragma unroll
  for (int c = 0; c < 50; c++) acc[c] = 0.f;

  for (int p = 0; p < 13; p++) {
    int kp = p*16; int nk = (p < 12) ? 16 : 8;
    __syncthreads();
    if (nk == 16) {
      for (int s = tid; s < 64*16; s += 256) {
        int kk = s & 15, mi = s >> 4;
        int row = m0 + mi; int k = kp + kk; float v = 0.f;
        if (row < 12832) {
          float x;
          if (row < 6400)       x = dR[row*200 + k];
          else if (row < 12800) x = qR[(row-6400)*200 + k];
          else                  x = qL[(row-12800)*200 + k];
          v = x*x;
        }
        ash[kk*65 + mi] = v;
      }
    } else {
      for (int s = tid; s < 64*8; s += 256) {
        int kk = s & 7, mi = s >> 3;
        int row = m0 + mi; int k = kp + kk; float v = 0.f;
        if (row < 12832) {
          float x;
          if (row < 6400)       x = dR[row*200 + k];
          else if (row < 12800) x = qR[(row-6400)*200 + k];
          else                  x = qL[(row-12800)*200 + k];
          v = x*x;
        }
        ash[kk*65 + mi] = v;
      }
    }
    __syncthreads();
    for (int k4 = 0; k4 < nk; k4 += 4) {
      float av[4];
#pragma unroll
      for (int kk = 0; kk < 4; kk++) av[kk] = ash[(k4+kk)*65 + lane];
#pragma unroll
      for (int c = 0; c < 50; c++)
#pragma unroll
        for (int kk = 0; kk < 4; kk++)
          acc[c] = fmaf(av[kk], Bm[c*200 + kp + k4 + kk], acc[c]);
    }
  }
  int row = m0 + lane;
  if (row < 12832) {
#pragma unroll
    for (int c = 0; c < 50; c++)
      nsqT[(wavei*50 + c)*12832 + row] = acc[c];   // coalesced per c
  }
}

__global__ void k_inv(const float* __restrict__ nsqT,
    float* __restrict__ invfpn, float* __restrict__ invmpn,
    float* __restrict__ invapn, float* __restrict__ invxpn,
    float* __restrict__ invmqn, float* __restrict__ invxqn,
    float* __restrict__ invfqn)
{
  int n = blockIdx.x;                       // 0..199 = m*50+c
  int row = blockIdx.y*256 + threadIdx.x;
  if (row >= 12832) return;
  int m = n / 50, c = n % 50;
  float v = rsqrtf(fmaxf(nsqT[n*12832 + row], EPS));
  if (row < 6400) {
    if (m == 0)      invfpn[row*50 + c] = v;
    else if (m == 1) invmpn[row*50 + c] = v;
    else if (m == 2) invapn[row*50 + c] = v;
    else             invxpn[row*50 + c] = v;
  } else if (row < 12800) {
    int r2 = row - 6400;
    if (m == 1)      invmqn[c*6400 + r2] = v;
    else if (m == 3) invxqn[r2*50 + c] = v;
  } else {
    if (m == 0)      invfqn[(row-12800)*50 + c] = v;
  }
}

// block = (b, 8 i's); lane=j. d operands are wave-uniform -> s_load.
__global__ __launch_bounds__(256) void k_rel(
    const float* __restrict__ dR, const float* __restrict__ qR,
    const float* __restrict__ qMask, const float* __restrict__ dMask,
    const float* __restrict__ invdn, const float* __restrict__ invqn,
    float* __restrict__ rel, float* __restrict__ invrs, int* __restrict__ idxout)
{
  __shared__ float qsh[64*201];
  __shared__ float redv[4][8][2];
  __shared__ int   redi[4][8];
  int tid = threadIdx.x;
  int b  = blockIdx.x / 25;
  int i0 = (blockIdx.x % 25) * 8;
  int j = tid, jr = min(j, 199);
  bool jv = j < 200;
  const float* qb = qR + b*40000;
  const float* db = dR + (b*200 + i0)*200;
  float acc[8];
#pragma unroll
  for (int ii = 0; ii < 8; ii++) acc[ii] = 0.f;

  for (int p = 0; p < 4; p++) {
    int kp = p*64;
    __syncthreads();
    if (p < 3) {
      for (int s = tid; s < 200*64; s += 256) { int kk = s & 63, jj = s >> 6; qsh[kk*201 + jj] = qb[jj*200 + kp + kk]; }
    } else {
      for (int s = tid; s < 200*8; s += 256) { int kk = s & 7, jj = s >> 3; qsh[kk*201 + jj] = qb[jj*200 + kp + kk]; }
    }
    __syncthreads();
    int nk = (p < 3) ? 64 : 8;
    for (int k4 = 0; k4 < nk; k4 += 4) {
      float qv[4];
#pragma unroll
      for (int kk = 0; kk < 4; kk++) qv[kk] = qsh[(k4+kk)*201 + jr];
#pragma unroll
      for (int ii = 0; ii < 8; ii++)
#pragma unroll
        for (int kk = 0; kk < 4; kk++)
          acc[ii] = fmaf(db[ii*200 + kp + k4 + kk], qv[kk], acc[ii]);
    }
  }

  float iqn = invqn[b*200 + jr];
  float qm  = qMask[b*200 + jr];
  int w = tid >> 6, l = tid & 63;
  float rv[8];
#pragma unroll
  for (int ii = 0; ii < 8; ii++) {
    float idn = invdn[b*200 + i0 + ii];
    float dm  = dMask[b*200 + i0 + ii];
    float r = acc[ii]*iqn*idn*qm*dm;
    rv[ii] = r;
    if (jv) rel[(b*200 + i0 + ii)*200 + j] = r;   // coalesced
  }
#pragma unroll
  for (int ii = 0; ii < 8; ii++) {
    float vm = jv ? rv[ii] : NEG_HUGE;
    float vs = jv ? rv[ii] : 0.f;
    int bj = jr;
#pragma unroll
    for (int m = 32; m; m >>= 1) {
      float ov = __shfl_xor(vm, m);
      int   oj = __shfl_xor(bj, m);
      vs += __shfl_xor(vs, m);
      if (ov > vm || (ov == vm && oj < bj)) { vm = ov; bj = oj; }  // first-max wins
    }
    if (l == 0) { redv[w][ii][0] = vm; redv[w][ii][1] = vs; redi[w][ii] = bj; }
  }
  __syncthreads();
  if (tid < 8) {
    float bv = redv[0][tid][0], ss = redv[0][tid][1]; int bj = redi[0][tid];
    for (int w2 = 1; w2 < 4; w2++) {
      ss += redv[w2][tid][1];
      float wv = redv[w2][tid][0]; int wj = redi[w2][tid];
      if (wv > bv || (wv == bv && wj < bj)) { bv = wv; bj = wj; }
    }
    invrs[b*200 + i0 + tid] = 1.f/(ss + EPS);
    idxout[b*200 + i0 + tid] = bj;
  }
}

// block = (b, 8 i's); lane=k. rel operands wave-uniform -> s_load.
__global__ __launch_bounds__(256) void k_wq(
    const float* __restrict__ qR, const float* __restrict__ rel,
    const float* __restrict__ invrs, float* __restrict__ wq)
{
  int tid = threadIdx.x;
  int b = blockIdx.x / 25; int i0 = (blockIdx.x % 25) * 8;
  int kl = min(tid, 199); bool kv = tid < 200;
  const float* qb = qR + b*40000;
  const float* rb = rel + (b*200 + i0)*200;
  float acc[8];
#pragma unroll
  for (int ii = 0; ii < 8; ii++) acc[ii] = 0.f;
  for (int j0 = 0; j0 < 200; j0 += 8) {
    float qv[8];
#pragma unroll
    for (int jj = 0; jj < 8; jj++) qv[jj] = qb[(j0+jj)*200 + kl];
#pragma unroll
    for (int ii = 0; ii < 8; ii++)
#pragma unroll
      for (int jj = 0; jj < 8; jj++)
        acc[ii] = fmaf(rb[ii*200 + j0 + jj], qv[jj], acc[ii]);
  }
#pragma unroll
  for (int ii = 0; ii < 8; ii++) {
    float v = acc[ii]*invrs[b*200 + i0 + ii];
    if (kv) wq[(b*200 + i0 + ii)*200 + tid] = v;
  }
}

// 4 row-groups (m'): A rows built on the fly; N=50 GEMM vs selected M2.
__global__ __launch_bounds__(256) void k_gemm2(
    const float* __restrict__ dR, const float* __restrict__ qR,
    const float* __restrict__ qL, const float* __restrict__ wq,
    const int* __restrict__ idx, const float* __restrict__ m2all,
    float* __restrict__ G)
{
  __shared__ float ash[16*257];
  int tid = threadIdx.x;
  int mp = blockIdx.x / 25;                 // 0..3
  int r0 = (blockIdx.x % 25) * 256;
  int msel = (mp == 0) ? 0 : (mp == 3) ? 3 : 2;
  const float* Bm = m2all + msel*10000;
  float acc[50];
#pragma unroll
  for (int c = 0; c < 50; c++) acc[c] = 0.f;

  for (int p = 0; p < 13; p++) {
    int kp = p*16; int nk = (p < 12) ? 16 : 8;
    __syncthreads();
    for (int s = tid; s < 256*nk; s += 256) {
      int kk, mi;
      if (nk == 16) { kk = s & 15; mi = s >> 4; } else { kk = s & 7; mi = s >> 3; }
      int row = r0 + mi; int k = kp + kk;
      int bb = row / 200;
      float v;
      if (mp == 0)      v = dR[row*200 + k]*qL[bb*200 + k];
      else if (mp == 1) v = dR[row*200 + k]*wq[row*200 + k];
      else if (mp == 2) { float t = wq[row*200 + k]; v = t*t; }
      else { int jid = idx[row]; v = dR[row*200 + k]*qR[(bb*200 + jid)*200 + k]; }
      ash[kk*257 + mi] = v;
    }
    __syncthreads();
    for (int k4 = 0; k4 < nk; k4 += 4) {
      float av[4];
#pragma unroll
      for (int kk = 0; kk < 4; kk++) av[kk] = ash[(k4+kk)*257 + tid];
#pragma unroll
      for (int c = 0; c < 50; c++)
#pragma unroll
        for (int kk = 0; kk < 4; kk++)
          acc[c] = fmaf(av[kk], Bm[c*200 + kp + k4 + kk], acc[c]);
    }
  }
  int row = r0 + tid;
  float* g = G + ((size_t)mp*6400 + row)*50;
#pragma unroll
  for (int c = 0; c < 50; c++) g[c] = acc[c];
}

__global__ void k_epi(
    const float* __restrict__ G, const float* __restrict__ invfpn,
    const float* __restrict__ invapn, const float* __restrict__ invxpn,
    const float* __restrict__ invfqn, const float* __restrict__ invxqn,
    const int* __restrict__ idx, float* __restrict__ out)
{
  int row = blockIdx.x; int c = threadIdx.x;
  if (c >= 50) return;
  int b = row / 200;
  float g0 = G[(0*6400 + row)*50 + c];
  float g1 = G[(1*6400 + row)*50 + c];
  float g2 = G[(2*6400 + row)*50 + c];
  float g3 = G[(3*6400 + row)*50 + c];
  float o0 = g0*invfpn[row*50 + c]*invfqn[b*50 + c];
  float o3 = g1*invapn[row*50 + c]*rsqrtf(fmaxf(g2, EPS));
  int jid = idx[row];
  float o4 = g3*invxpn[row*50 + c]*invxqn[(b*200 + jid)*50 + c];
  out[row*250 + c]       = o0;
  out[row*250 + 150 + c] = o3;
  out[row*250 + 200 + c] = o4;
}

// THE dominant kernel. block=(b, 4 i's), lane=j, c split into two half-passes.
// mnum[i,j,c] = sum_k t[k]*M2[c,k], t = d_i[k]*q_j[k]; M2 & d via s_load,
// q via transposed LDS staging. max/mean over j, scaled by 1/mqn (per j) and
// 1/mpn (after reduce).
__global__ __launch_bounds__(256,3) void k_maxpool(
    const float* __restrict__ dR, const float* __restrict__ qR,
    const float* __restrict__ m2all, const float* __restrict__ invmqn,
    const float* __restrict__ invmpn, float* __restrict__ out)
{
  __shared__ float qsh[64*201];
  float* redp = qsh;                        // reused after compute, barriered
  int tid = threadIdx.x;
  int b  = blockIdx.x / 50;
  int i0 = (blockIdx.x % 50) * 4;
  int j = tid, jr = min(j, 199);
  bool jv = j < 200;
  const float* qb = qR + b*40000;
  const float* db = dR + (b*200 + i0)*200;
  const float* M2 = m2all + 10000;          // maxpool_M^2
  int w = tid >> 6, l = tid & 63;

  for (int ch = 0; ch < 2; ch++) {
    float acc[4][25];
#pragma unroll
    for (int ii = 0; ii < 4; ii++)
#pragma unroll
      for (int cc = 0; cc < 25; cc++) acc[ii][cc] = 0.f;

    for (int p = 0; p < 4; p++) {
      int kp = p*64;
      __syncthreads();
      if (p < 3) {
        for (int s = tid; s < 200*64; s += 256) { int kk = s & 63, jj = s >> 6; qsh[kk*201 + jj] = qb[jj*200 + kp + kk]; }
      } else {
        for (int s = tid; s < 200*8; s += 256) { int kk = s & 7, jj = s >> 3; qsh[kk*201 + jj] = qb[jj*200 + kp + kk]; }
      }
      __syncthreads();
      int nk = (p < 3) ? 64 : 8;
      for (int k4 = 0; k4 < nk; k4 += 4) {
        float qv[4];
#pragma unroll
        for (int kk = 0; kk < 4; kk++) qv[kk] = qsh[(k4+kk)*201 + jr];
#pragma unroll
        for (int ii = 0; ii < 4; ii++) {
          float t[4];
#pragma unroll
          for (int kk = 0; kk < 4; kk++) t[kk] = db[ii*200 + kp + k4 + kk]*qv[kk];
#pragma unroll
          for (int cc = 0; cc < 25; cc++)
#pragma unroll
            for (int kk = 0; kk < 4; kk++)
              acc[ii][cc] = fmaf(t[kk], M2[(ch*25 + cc)*200 + kp + k4 + kk], acc[ii][cc]);
        }
      }
    }
    // per-lane scale by 1/mqn[j,c], reduce max+sum over j
    float iq[25];
#pragma unroll
    for (int cc = 0; cc < 25; cc++) iq[cc] = invmqn[(ch*25 + cc)*6400 + b*200 + jr];
    __syncthreads();                        // qsh reads done; redp aliases qsh
#pragma unroll
    for (int ii = 0; ii < 4; ii++) {
#pragma unroll
      for (int cc = 0; cc < 25; cc++) {
        float v = acc[ii][cc]*iq[cc];
        float vm = jv ? v : NEG_HUGE;
        float vs = jv ? v : 0.f;
#pragma unroll
        for (int m = 32; m; m >>= 1) { vm = fmaxf(vm, __shfl_xor(vm, m)); vs += __shfl_xor(vs, m); }
        if (l == 0) { redp[((ii*4 + w)*26 + cc)*2 + 0] = vm; redp[((ii*4 + w)*26 + cc)*2 + 1] = vs; }
      }
    }
    __syncthreads();
    for (int t2 = tid; t2 < 100; t2 += 256) {
      int ii = t2/25, cc = t2%25;
      float vm = NEG_HUGE, vs = 0.f;
      for (int w2 = 0; w2 < 4; w2++) {
        vm = fmaxf(vm, redp[((ii*4 + w2)*26 + cc)*2 + 0]);
        vs += redp[((ii*4 + w2)*26 + cc)*2 + 1];
      }
      float ip = invmpn[(b*200 + i0 + ii)*50 + ch*25 + cc];
      int ob = (b*200 + i0 + ii)*250 + ch*25 + cc;
      out[ob + 50]  = vm*ip;                 // max over j
      out[ob + 100] = vs*ip*(1.f/200.f);     // mean over j
    }
    __syncthreads();
  }
}

extern "C" void kernel_launch(void* const* d_in, const int* in_sizes, int n_in,
                              void* d_out, int out_size, void* d_ws, size_t ws_size,
                              hipStream_t stream) {
  const float* qR = (const float*)d_in[0];
  const float* qL = (const float*)d_in[1];
  const float* qM = (const float*)d_in[2];
  const float* dR = (const float*)d_in[3];
  // d_in[4] = d_last: unused by the reference
  const float* dM = (const float*)d_in[5];
  const float* fullM = (const float*)d_in[6];
  const float* mpM   = (const float*)d_in[7];
  const float* attM  = (const float*)d_in[8];
  const float* xM    = (const float*)d_in[9];

  float* ws  = (float*)d_ws;
  float* out = (float*)d_out;

  float* m2all  = ws + OFF_M2ALL;
  float* nsqT   = ws + OFF_NSQT;
  float* invfpn = ws + OFF_INVFPN;
  float* invmpn = ws + OFF_INVMPN;
  float* invapn = ws + OFF_INVAPN;
  float* invxpn = ws + OFF_INVXPN;
  float* invmqn = ws + OFF_INVMQN;
  float* invxqn = ws + OFF_INVXQN;
  float* invfqn = ws + OFF_INVFQN;
  float* invdn  = ws + OFF_INVDN;
  float* invqn  = ws + OFF_INVQN;
  float* rel    = ws + OFF_REL;
  float* invrs  = ws + OFF_INVRS;
  int*   idxp   = (int*)(ws + OFF_IDX);
  float* wqp    = ws + OFF_WQ;
  float* G      = ws + OFF_G;

  k_m2<<<157, 256, 0, stream>>>(fullM, mpM, attM, xM, m2all);
  k_pnorm<<<12800, 64, 0, stream>>>(dR, qR, invdn, invqn);
  k_gemm1<<<201, 256, 0, stream>>>(dR, qR, qL, m2all, nsqT);
  k_inv<<<dim3(200, 51), 256, 0, stream>>>(nsqT, invfpn, invmpn, invapn, invxpn,
                                           invmqn, invxqn, invfqn);
  k_rel<<<800, 256, 0, stream>>>(dR, qR, qM, dM, invdn, invqn, rel, invrs, idxp);
  k_wq<<<800, 256, 0, stream>>>(qR, rel, invrs, wqp);
  k_gemm2<<<100, 256, 0, stream>>>(dR, qR, qL, wqp, idxp, m2all, G);
  k_epi<<<6400, 64, 0, stream>>>(G, invfpn, invapn, invxpn, invfqn, invxqn, idxp, out);
  k_maxpool<<<1600, 256, 0, stream>>>(dR, qR, m2all, invmqn, invmpn, out);
}

// Round 2
// 1560.102 us; speedup vs baseline: 1.0072x; 1.0072x over previous
//
#include <hip/hip_runtime.h>
#include <math.h>

// MultiPerspectiveMatch on MI355X — round 2.
// Change vs round 1: k_maxpool restructured to kill AGPR round-tripping.
//   - acc per lane: 100 -> 50 (2 i's per block, 25-c chunks) => pure VGPRs
//   - LDS staging 40-k chunks (32.2 KB -> 4 blocks/CU; 200 = 5*40, no tail)
//   - float4 staging loads
// Everything else unchanged.

#define EPS 1e-6f
#define NEG_HUGE -3.4e38f

// ---- ws offsets (floats) ----
constexpr size_t OFF_M2ALL = 0;            // 4*50*200 = 40000
constexpr size_t OFF_NSQT  = 40000;        // 200*12832
constexpr size_t OFF_INVFPN= 2606400;      // [row(6400)][50]
constexpr size_t OFF_INVMPN= 2926400;      // [row][50]
constexpr size_t OFF_INVAPN= 3246400;      // [row][50]
constexpr size_t OFF_INVXPN= 3566400;      // [row][50]
constexpr size_t OFF_INVMQN= 3886400;      // [c(50)][b*200+j]  (lane-coalesced for k_maxpool)
constexpr size_t OFF_INVXQN= 4206400;      // [b*200+j][50]
constexpr size_t OFF_INVFQN= 4526400;      // [b][50]
constexpr size_t OFF_INVDN = 4528000;      // [b*200+i]
constexpr size_t OFF_INVQN = 4534400;      // [b*200+j]
constexpr size_t OFF_REL   = 4540800;      // [b][i][j]
constexpr size_t OFF_INVRS = 5820800;      // [b*200+i]
constexpr size_t OFF_IDX   = 5827200;      // int [b*200+i]
constexpr size_t OFF_WQ    = 5833600;      // [b][i][k]
constexpr size_t OFF_G     = 7113600;      // [m'(4)][row(6400)][50]
// end = 8393600 floats = 33.6 MB

__global__ void k_m2(const float* __restrict__ fM, const float* __restrict__ mM,
                     const float* __restrict__ aM, const float* __restrict__ xM,
                     float* __restrict__ m2all)
{
  int i = blockIdx.x*256 + threadIdx.x;
  if (i >= 40000) return;
  int m = i / 10000, r = i % 10000;
  const float* s = (m==0)?fM:(m==1)?mM:(m==2)?aM:xM;
  float v = s[r];
  m2all[i] = v*v;
}

__global__ void k_pnorm(const float* __restrict__ dR, const float* __restrict__ qR,
                        float* __restrict__ invdn, float* __restrict__ invqn)
{
  int row = blockIdx.x; int l = threadIdx.x;
  const float* src = (row < 6400) ? dR + row*200 : qR + (row-6400)*200;
  float s = 0.f;
  for (int k = l; k < 200; k += 64) { float v = src[k]; s = fmaf(v, v, s); }
#pragma unroll
  for (int m = 32; m; m >>= 1) s += __shfl_xor(s, m);
  if (l == 0) {
    float r = rsqrtf(fmaxf(s, EPS));
    if (row < 6400) invdn[row] = r; else invqn[row-6400] = r;
  }
}

// rows = [d(6400) | q(6400) | q_last(32)]; each wave owns one 50-col n-tile.
__global__ __launch_bounds__(256) void k_gemm1(
    const float* __restrict__ dR, const float* __restrict__ qR,
    const float* __restrict__ qL, const float* __restrict__ m2all,
    float* __restrict__ nsqT)
{
  __shared__ float ash[16*65];
  int tid = threadIdx.x;
  int lane = tid & 63;
  int wavei = __builtin_amdgcn_readfirstlane(tid >> 6);
  int m0 = blockIdx.x * 64;
  const float* Bm = m2all + wavei*10000;
  float acc[50];
#pragma unroll
  for (int c = 0; c < 50; c++) acc[c] = 0.f;

  for (int p = 0; p < 13; p++) {
    int kp = p*16; int nk = (p < 12) ? 16 : 8;
    __syncthreads();
    if (nk == 16) {
      for (int s = tid; s < 64*16; s += 256) {
        int kk = s & 15, mi = s >> 4;
        int row = m0 + mi; int k = kp + kk; float v = 0.f;
        if (row < 12832) {
          float x;
          if (row < 6400)       x = dR[row*200 + k];
          else if (row < 12800) x = qR[(row-6400)*200 + k];
          else                  x = qL[(row-12800)*200 + k];
          v = x*x;
        }
        ash[kk*65 + mi] = v;
      }
    } else {
      for (int s = tid; s < 64*8; s += 256) {
        int kk = s & 7, mi = s >> 3;
        int row = m0 + mi; int k = kp + kk; float v = 0.f;
        if (row < 12832) {
          float x;
          if (row < 6400)       x = dR[row*200 + k];
          else if (row < 12800) x = qR[(row-6400)*200 + k];
          else                  x = qL[(row-12800)*200 + k];
          v = x*x;
        }
        ash[kk*65 + mi] = v;
      }
    }
    __syncthreads();
    for (int k4 = 0; k4 < nk; k4 += 4) {
      float av[4];
#pragma unroll
      for (int kk = 0; kk < 4; kk++) av[kk] = ash[(k4+kk)*65 + lane];
#pragma unroll
      for (int c = 0; c < 50; c++)
#pragma unroll
        for (int kk = 0; kk < 4; kk++)
          acc[c] = fmaf(av[kk], Bm[c*200 + kp + k4 + kk], acc[c]);
    }
  }
  int row = m0 + lane;
  if (row < 12832) {
#pragma unroll
    for (int c = 0; c < 50; c++)
      nsqT[(wavei*50 + c)*12832 + row] = acc[c];   // coalesced per c
  }
}

__global__ void k_inv(const float* __restrict__ nsqT,
    float* __restrict__ invfpn, float* __restrict__ invmpn,
    float* __restrict__ invapn, float* __restrict__ invxpn,
    float* __restrict__ invmqn, float* __restrict__ invxqn,
    float* __restrict__ invfqn)
{
  int n = blockIdx.x;                       // 0..199 = m*50+c
  int row = blockIdx.y*256 + threadIdx.x;
  if (row >= 12832) return;
  int m = n / 50, c = n % 50;
  float v = rsqrtf(fmaxf(nsqT[n*12832 + row], EPS));
  if (row < 6400) {
    if (m == 0)      invfpn[row*50 + c] = v;
    else if (m == 1) invmpn[row*50 + c] = v;
    else if (m == 2) invapn[row*50 + c] = v;
    else             invxpn[row*50 + c] = v;
  } else if (row < 12800) {
    int r2 = row - 6400;
    if (m == 1)      invmqn[c*6400 + r2] = v;
    else if (m == 3) invxqn[r2*50 + c] = v;
  } else {
    if (m == 0)      invfqn[(row-12800)*50 + c] = v;
  }
}

// block = (b, 8 i's); lane=j. d operands are wave-uniform -> s_load.
__global__ __launch_bounds__(256) void k_rel(
    const float* __restrict__ dR, const float* __restrict__ qR,
    const float* __restrict__ qMask, const float* __restrict__ dMask,
    const float* __restrict__ invdn, const float* __restrict__ invqn,
    float* __restrict__ rel, float* __restrict__ invrs, int* __restrict__ idxout)
{
  __shared__ float qsh[64*201];
  __shared__ float redv[4][8][2];
  __shared__ int   redi[4][8];
  int tid = threadIdx.x;
  int b  = blockIdx.x / 25;
  int i0 = (blockIdx.x % 25) * 8;
  int j = tid, jr = min(j, 199);
  bool jv = j < 200;
  const float* qb = qR + b*40000;
  const float* db = dR + (b*200 + i0)*200;
  float acc[8];
#pragma unroll
  for (int ii = 0; ii < 8; ii++) acc[ii] = 0.f;

  for (int p = 0; p < 4; p++) {
    int kp = p*64;
    __syncthreads();
    if (p < 3) {
      for (int s = tid; s < 200*64; s += 256) { int kk = s & 63, jj = s >> 6; qsh[kk*201 + jj] = qb[jj*200 + kp + kk]; }
    } else {
      for (int s = tid; s < 200*8; s += 256) { int kk = s & 7, jj = s >> 3; qsh[kk*201 + jj] = qb[jj*200 + kp + kk]; }
    }
    __syncthreads();
    int nk = (p < 3) ? 64 : 8;
    for (int k4 = 0; k4 < nk; k4 += 4) {
      float qv[4];
#pragma unroll
      for (int kk = 0; kk < 4; kk++) qv[kk] = qsh[(k4+kk)*201 + jr];
#pragma unroll
      for (int ii = 0; ii < 8; ii++)
#pragma unroll
        for (int kk = 0; kk < 4; kk++)
          acc[ii] = fmaf(db[ii*200 + kp + k4 + kk], qv[kk], acc[ii]);
    }
  }

  float iqn = invqn[b*200 + jr];
  float qm  = qMask[b*200 + jr];
  int w = tid >> 6, l = tid & 63;
  float rv[8];
#pragma unroll
  for (int ii = 0; ii < 8; ii++) {
    float idn = invdn[b*200 + i0 + ii];
    float dm  = dMask[b*200 + i0 + ii];
    float r = acc[ii]*iqn*idn*qm*dm;
    rv[ii] = r;
    if (jv) rel[(b*200 + i0 + ii)*200 + j] = r;   // coalesced
  }
#pragma unroll
  for (int ii = 0; ii < 8; ii++) {
    float vm = jv ? rv[ii] : NEG_HUGE;
    float vs = jv ? rv[ii] : 0.f;
    int bj = jr;
#pragma unroll
    for (int m = 32; m; m >>= 1) {
      float ov = __shfl_xor(vm, m);
      int   oj = __shfl_xor(bj, m);
      vs += __shfl_xor(vs, m);
      if (ov > vm || (ov == vm && oj < bj)) { vm = ov; bj = oj; }  // first-max wins
    }
    if (l == 0) { redv[w][ii][0] = vm; redv[w][ii][1] = vs; redi[w][ii] = bj; }
  }
  __syncthreads();
  if (tid < 8) {
    float bv = redv[0][tid][0], ss = redv[0][tid][1]; int bj = redi[0][tid];
    for (int w2 = 1; w2 < 4; w2++) {
      ss += redv[w2][tid][1];
      float wv = redv[w2][tid][0]; int wj = redi[w2][tid];
      if (wv > bv || (wv == bv && wj < bj)) { bv = wv; bj = wj; }
    }
    invrs[b*200 + i0 + tid] = 1.f/(ss + EPS);
    idxout[b*200 + i0 + tid] = bj;
  }
}

// block = (b, 8 i's); lane=k. rel operands wave-uniform -> s_load.
__global__ __launch_bounds__(256) void k_wq(
    const float* __restrict__ qR, const float* __restrict__ rel,
    const float* __restrict__ invrs, float* __restrict__ wq)
{
  int tid = threadIdx.x;
  int b = blockIdx.x / 25; int i0 = (blockIdx.x % 25) * 8;
  int kl = min(tid, 199); bool kv = tid < 200;
  const float* qb = qR + b*40000;
  const float* rb = rel + (b*200 + i0)*200;
  float acc[8];
#pragma unroll
  for (int ii = 0; ii < 8; ii++) acc[ii] = 0.f;
  for (int j0 = 0; j0 < 200; j0 += 8) {
    float qv[8];
#pragma unroll
    for (int jj = 0; jj < 8; jj++) qv[jj] = qb[(j0+jj)*200 + kl];
#pragma unroll
    for (int ii = 0; ii < 8; ii++)
#pragma unroll
      for (int jj = 0; jj < 8; jj++)
        acc[ii] = fmaf(rb[ii*200 + j0 + jj], qv[jj], acc[ii]);
  }
#pragma unroll
  for (int ii = 0; ii < 8; ii++) {
    float v = acc[ii]*invrs[b*200 + i0 + ii];
    if (kv) wq[(b*200 + i0 + ii)*200 + tid] = v;
  }
}

// 4 row-groups (m'): A rows built on the fly; N=50 GEMM vs selected M2.
__global__ __launch_bounds__(256) void k_gemm2(
    const float* __restrict__ dR, const float* __restrict__ qR,
    const float* __restrict__ qL, const float* __restrict__ wq,
    const int* __restrict__ idx, const float* __restrict__ m2all,
    float* __restrict__ G)
{
  __shared__ float ash[16*257];
  int tid = threadIdx.x;
  int mp = blockIdx.x / 25;                 // 0..3
  int r0 = (blockIdx.x % 25) * 256;
  int msel = (mp == 0) ? 0 : (mp == 3) ? 3 : 2;
  const float* Bm = m2all + msel*10000;
  float acc[50];
#pragma unroll
  for (int c = 0; c < 50; c++) acc[c] = 0.f;

  for (int p = 0; p < 13; p++) {
    int kp = p*16; int nk = (p < 12) ? 16 : 8;
    __syncthreads();
    for (int s = tid; s < 256*nk; s += 256) {
      int kk, mi;
      if (nk == 16) { kk = s & 15; mi = s >> 4; } else { kk = s & 7; mi = s >> 3; }
      int row = r0 + mi; int k = kp + kk;
      int bb = row / 200;
      float v;
      if (mp == 0)      v = dR[row*200 + k]*qL[bb*200 + k];
      else if (mp == 1) v = dR[row*200 + k]*wq[row*200 + k];
      else if (mp == 2) { float t = wq[row*200 + k]; v = t*t; }
      else { int jid = idx[row]; v = dR[row*200 + k]*qR[(bb*200 + jid)*200 + k]; }
      ash[kk*257 + mi] = v;
    }
    __syncthreads();
    for (int k4 = 0; k4 < nk; k4 += 4) {
      float av[4];
#pragma unroll
      for (int kk = 0; kk < 4; kk++) av[kk] = ash[(k4+kk)*257 + tid];
#pragma unroll
      for (int c = 0; c < 50; c++)
#pragma unroll
        for (int kk = 0; kk < 4; kk++)
          acc[c] = fmaf(av[kk], Bm[c*200 + kp + k4 + kk], acc[c]);
    }
  }
  int row = r0 + tid;
  float* g = G + ((size_t)mp*6400 + row)*50;
#pragma unroll
  for (int c = 0; c < 50; c++) g[c] = acc[c];
}

__global__ void k_epi(
    const float* __restrict__ G, const float* __restrict__ invfpn,
    const float* __restrict__ invapn, const float* __restrict__ invxpn,
    const float* __restrict__ invfqn, const float* __restrict__ invxqn,
    const int* __restrict__ idx, float* __restrict__ out)
{
  int row = blockIdx.x; int c = threadIdx.x;
  if (c >= 50) return;
  int b = row / 200;
  float g0 = G[(0*6400 + row)*50 + c];
  float g1 = G[(1*6400 + row)*50 + c];
  float g2 = G[(2*6400 + row)*50 + c];
  float g3 = G[(3*6400 + row)*50 + c];
  float o0 = g0*invfpn[row*50 + c]*invfqn[b*50 + c];
  float o3 = g1*invapn[row*50 + c]*rsqrtf(fmaxf(g2, EPS));
  int jid = idx[row];
  float o4 = g3*invxpn[row*50 + c]*invxqn[(b*200 + jid)*50 + c];
  out[row*250 + c]       = o0;
  out[row*250 + 150 + c] = o3;
  out[row*250 + 200 + c] = o4;
}

// THE dominant kernel, round 2. block=(b, 2 i's), lane=j; c in 2 chunks of 25
// => acc[2][25]=50 live accumulators: fits VGPRs, no AGPR round-trips.
// k staged in 5 exact chunks of 40 (qsh 32.2 KB -> 4 blocks/CU).
// d & M2 wave-uniform -> s_load; q via transposed LDS.
__global__ __launch_bounds__(256,4) void k_maxpool(
    const float* __restrict__ dR, const float* __restrict__ qR,
    const float* __restrict__ m2all, const float* __restrict__ invmqn,
    const float* __restrict__ invmpn, float* __restrict__ out)
{
  __shared__ float qsh[40*201];             // 32160 B
  float* redp = qsh;                        // reused after compute, barriered
  int tid = threadIdx.x;
  int b  = blockIdx.x / 100;
  int i0 = (blockIdx.x % 100) * 2;
  int j = tid, jr = min(j, 199);
  bool jv = j < 200;
  const float* qb = qR + b*40000;
  const float* db = dR + (b*200 + i0)*200;
  const float* M2 = m2all + 10000;          // maxpool_M^2
  int w = tid >> 6, l = tid & 63;

  for (int ch = 0; ch < 2; ch++) {
    float acc[2][25];
#pragma unroll
    for (int ii = 0; ii < 2; ii++)
#pragma unroll
      for (int cc = 0; cc < 25; cc++) acc[ii][cc] = 0.f;

    for (int p = 0; p < 5; p++) {
      int kp = p*40;
      __syncthreads();
      // stage q[b][0:200][kp:kp+40] transposed: qsh[k][j], float4 loads
      for (int s = tid; s < 2000; s += 256) {
        int kk4 = (s % 10)*4, jj = s / 10;
        float4 v = *(const float4*)(qb + jj*200 + kp + kk4);
        qsh[(kk4+0)*201 + jj] = v.x;
        qsh[(kk4+1)*201 + jj] = v.y;
        qsh[(kk4+2)*201 + jj] = v.z;
        qsh[(kk4+3)*201 + jj] = v.w;
      }
      __syncthreads();
      for (int k4 = 0; k4 < 40; k4 += 4) {
        float qv[4];
#pragma unroll
        for (int kk = 0; kk < 4; kk++) qv[kk] = qsh[(k4+kk)*201 + jr];
#pragma unroll
        for (int ii = 0; ii < 2; ii++) {
          float t[4];
#pragma unroll
          for (int kk = 0; kk < 4; kk++) t[kk] = db[ii*200 + kp + k4 + kk]*qv[kk];
#pragma unroll
          for (int cc = 0; cc < 25; cc++)
#pragma unroll
            for (int kk = 0; kk < 4; kk++)
              acc[ii][cc] = fmaf(t[kk], M2[(ch*25 + cc)*200 + kp + k4 + kk], acc[ii][cc]);
        }
      }
    }
    // per-lane scale by 1/mqn[j,c], reduce max+sum over j
    float iq[25];
#pragma unroll
    for (int cc = 0; cc < 25; cc++) iq[cc] = invmqn[(ch*25 + cc)*6400 + b*200 + jr];
    __syncthreads();                        // qsh reads done; redp aliases qsh
#pragma unroll
    for (int ii = 0; ii < 2; ii++) {
#pragma unroll
      for (int cc = 0; cc < 25; cc++) {
        float v = acc[ii][cc]*iq[cc];
        float vm = jv ? v : NEG_HUGE;
        float vs = jv ? v : 0.f;
#pragma unroll
        for (int m = 32; m; m >>= 1) { vm = fmaxf(vm, __shfl_xor(vm, m)); vs += __shfl_xor(vs, m); }
        if (l == 0) { redp[((ii*4 + w)*26 + cc)*2 + 0] = vm; redp[((ii*4 + w)*26 + cc)*2 + 1] = vs; }
      }
    }
    __syncthreads();
    for (int t2 = tid; t2 < 50; t2 += 256) {
      int ii = t2/25, cc = t2%25;
      float vm = NEG_HUGE, vs = 0.f;
      for (int w2 = 0; w2 < 4; w2++) {
        vm = fmaxf(vm, redp[((ii*4 + w2)*26 + cc)*2 + 0]);
        vs += redp[((ii*4 + w2)*26 + cc)*2 + 1];
      }
      float ip = invmpn[(b*200 + i0 + ii)*50 + ch*25 + cc];
      int ob = (b*200 + i0 + ii)*250 + ch*25 + cc;
      out[ob + 50]  = vm*ip;                 // max over j
      out[ob + 100] = vs*ip*(1.f/200.f);     // mean over j
    }
    __syncthreads();
  }
}

extern "C" void kernel_launch(void* const* d_in, const int* in_sizes, int n_in,
                              void* d_out, int out_size, void* d_ws, size_t ws_size,
                              hipStream_t stream) {
  const float* qR = (const float*)d_in[0];
  const float* qL = (const float*)d_in[1];
  const float* qM = (const float*)d_in[2];
  const float* dR = (const float*)d_in[3];
  // d_in[4] = d_last: unused by the reference
  const float* dM = (const float*)d_in[5];
  const float* fullM = (const float*)d_in[6];
  const float* mpM   = (const float*)d_in[7];
  const float* attM  = (const float*)d_in[8];
  const float* xM    = (const float*)d_in[9];

  float* ws  = (float*)d_ws;
  float* out = (float*)d_out;

  float* m2all  = ws + OFF_M2ALL;
  float* nsqT   = ws + OFF_NSQT;
  float* invfpn = ws + OFF_INVFPN;
  float* invmpn = ws + OFF_INVMPN;
  float* invapn = ws + OFF_INVAPN;
  float* invxpn = ws + OFF_INVXPN;
  float* invmqn = ws + OFF_INVMQN;
  float* invxqn = ws + OFF_INVXQN;
  float* invfqn = ws + OFF_INVFQN;
  float* invdn  = ws + OFF_INVDN;
  float* invqn  = ws + OFF_INVQN;
  float* rel    = ws + OFF_REL;
  float* invrs  = ws + OFF_INVRS;
  int*   idxp   = (int*)(ws + OFF_IDX);
  float* wqp    = ws + OFF_WQ;
  float* G      = ws + OFF_G;

  k_m2<<<157, 256, 0, stream>>>(fullM, mpM, attM, xM, m2all);
  k_pnorm<<<12800, 64, 0, stream>>>(dR, qR, invdn, invqn);
  k_gemm1<<<201, 256, 0, stream>>>(dR, qR, qL, m2all, nsqT);
  k_inv<<<dim3(200, 51), 256, 0, stream>>>(nsqT, invfpn, invmpn, invapn, invxpn,
                                           invmqn, invxqn, invfqn);
  k_rel<<<800, 256, 0, stream>>>(dR, qR, qM, dM, invdn, invqn, rel, invrs, idxp);
  k_wq<<<800, 256, 0, stream>>>(qR, rel, invrs, wqp);
  k_gemm2<<<100, 256, 0, stream>>>(dR, qR, qL, wqp, idxp, m2all, G);
  k_epi<<<6400, 64, 0, stream>>>(G, invfpn, invapn, invxpn, invfqn, invxqn, idxp, out);
  k_maxpool<<<3200, 256, 0, stream>>>(dR, qR, m2all, invmqn, invmpn, out);
}

// Round 3
// 862.499 us; speedup vs baseline: 1.8218x; 1.8088x over previous
//
#include <hip/hip_runtime.h>
#include <math.h>

// MultiPerspectiveMatch on MI355X — round 3.
// Change vs round 2: maxpool stage (the 12.8 GMAC dominator) moved to bf16
// MFMA (32x32x16). Per (b,c): mnum = (d .* M2_c) @ q^T as 1600 padded
// 256x256x208 GEMMs. fp32 VALU version was AGPR-copy-bound (VGPR_Count=56
// with 50 live accs -> v_accvgpr round-trips, 4.5x VALU inflation).
// Norms stay exact fp32. Other kernels unchanged.

#define EPS 1e-6f
#define NEG_HUGE -3.4e38f

typedef __bf16 bf16x8 __attribute__((ext_vector_type(8)));
typedef float f32x16 __attribute__((ext_vector_type(16)));

// ---- ws offsets (floats) ----
constexpr size_t OFF_M2ALL = 0;            // 4*50*200 = 40000
constexpr size_t OFF_NSQT  = 40000;        // 200*12832 (dead after k_inv; qb16 reuses it)
constexpr size_t OFF_QB16  = 40000;        // ushort[32][256][208] = 851,968 floats < nsqT
constexpr size_t OFF_INVFPN= 2606400;      // [row(6400)][50]
constexpr size_t OFF_INVMPN= 2926400;      // [row][50]
constexpr size_t OFF_INVAPN= 3246400;      // [row][50]
constexpr size_t OFF_INVXPN= 3566400;      // [row][50]
constexpr size_t OFF_INVMQN= 3886400;      // [c(50)][b*200+j]
constexpr size_t OFF_INVXQN= 4206400;      // [b*200+j][50]
constexpr size_t OFF_INVFQN= 4526400;      // [b][50]
constexpr size_t OFF_INVDN = 4528000;      // [b*200+i]
constexpr size_t OFF_INVQN = 4534400;      // [b*200+j]
constexpr size_t OFF_REL   = 4540800;      // [b][i][j]
constexpr size_t OFF_INVRS = 5820800;      // [b*200+i]
constexpr size_t OFF_IDX   = 5827200;      // int [b*200+i]
constexpr size_t OFF_WQ    = 5833600;      // [b][i][k]
constexpr size_t OFF_G     = 7113600;      // [m'(4)][row(6400)][50]; dead after k_epi
constexpr size_t OFF_PMAX  = 7113600;      // [jh(2)][row(6400)][50] reuses G
constexpr size_t OFF_PSUM  = 7753600;      // [jh(2)][row(6400)][50]
// end = 8393600 floats = 33.6 MB

__device__ inline unsigned short f2bf(float f) {
  __bf16 h = (__bf16)f;
  return *(unsigned short*)&h;
}

__global__ void k_m2(const float* __restrict__ fM, const float* __restrict__ mM,
                     const float* __restrict__ aM, const float* __restrict__ xM,
                     float* __restrict__ m2all)
{
  int i = blockIdx.x*256 + threadIdx.x;
  if (i >= 40000) return;
  int m = i / 10000, r = i % 10000;
  const float* s = (m==0)?fM:(m==1)?mM:(m==2)?aM:xM;
  float v = s[r];
  m2all[i] = v*v;
}

__global__ void k_pnorm(const float* __restrict__ dR, const float* __restrict__ qR,
                        float* __restrict__ invdn, float* __restrict__ invqn)
{
  int row = blockIdx.x; int l = threadIdx.x;
  const float* src = (row < 6400) ? dR + row*200 : qR + (row-6400)*200;
  float s = 0.f;
  for (int k = l; k < 200; k += 64) { float v = src[k]; s = fmaf(v, v, s); }
#pragma unroll
  for (int m = 32; m; m >>= 1) s += __shfl_xor(s, m);
  if (l == 0) {
    float r = rsqrtf(fmaxf(s, EPS));
    if (row < 6400) invdn[row] = r; else invqn[row-6400] = r;
  }
}

// rows = [d(6400) | q(6400) | q_last(32)]; each wave owns one 50-col n-tile.
__global__ __launch_bounds__(256) void k_gemm1(
    const float* __restrict__ dR, const float* __restrict__ qR,
    const float* __restrict__ qL, const float* __restrict__ m2all,
    float* __restrict__ nsqT)
{
  __shared__ float ash[16*65];
  int tid = threadIdx.x;
  int lane = tid & 63;
  int wavei = __builtin_amdgcn_readfirstlane(tid >> 6);
  int m0 = blockIdx.x * 64;
  const float* Bm = m2all + wavei*10000;
  float acc[50];
#pragma unroll
  for (int c = 0; c < 50; c++) acc[c] = 0.f;

  for (int p = 0; p < 13; p++) {
    int kp = p*16; int nk = (p < 12) ? 16 : 8;
    __syncthreads();
    for (int s = tid; s < 64*nk; s += 256) {
      int kk, mi;
      if (nk == 16) { kk = s & 15; mi = s >> 4; } else { kk = s & 7; mi = s >> 3; }
      int row = m0 + mi; int k = kp + kk; float v = 0.f;
      if (row < 12832) {
        float x;
        if (row < 6400)       x = dR[row*200 + k];
        else if (row < 12800) x = qR[(row-6400)*200 + k];
        else                  x = qL[(row-12800)*200 + k];
        v = x*x;
      }
      ash[kk*65 + mi] = v;
    }
    __syncthreads();
    for (int k4 = 0; k4 < nk; k4 += 4) {
      float av[4];
#pragma unroll
      for (int kk = 0; kk < 4; kk++) av[kk] = ash[(k4+kk)*65 + lane];
#pragma unroll
      for (int c = 0; c < 50; c++)
#pragma unroll
        for (int kk = 0; kk < 4; kk++)
          acc[c] = fmaf(av[kk], Bm[c*200 + kp + k4 + kk], acc[c]);
    }
  }
  int row = m0 + lane;
  if (row < 12832) {
#pragma unroll
    for (int c = 0; c < 50; c++)
      nsqT[(wavei*50 + c)*12832 + row] = acc[c];   // coalesced per c
  }
}

__global__ void k_inv(const float* __restrict__ nsqT,
    float* __restrict__ invfpn, float* __restrict__ invmpn,
    float* __restrict__ invapn, float* __restrict__ invxpn,
    float* __restrict__ invmqn, float* __restrict__ invxqn,
    float* __restrict__ invfqn)
{
  int n = blockIdx.x;                       // 0..199 = m*50+c
  int row = blockIdx.y*256 + threadIdx.x;
  if (row >= 12832) return;
  int m = n / 50, c = n % 50;
  float v = rsqrtf(fmaxf(nsqT[n*12832 + row], EPS));
  if (row < 6400) {
    if (m == 0)      invfpn[row*50 + c] = v;
    else if (m == 1) invmpn[row*50 + c] = v;
    else if (m == 2) invapn[row*50 + c] = v;
    else             invxpn[row*50 + c] = v;
  } else if (row < 12800) {
    int r2 = row - 6400;
    if (m == 1)      invmqn[c*6400 + r2] = v;
    else if (m == 3) invxqn[r2*50 + c] = v;
  } else {
    if (m == 0)      invfqn[(row-12800)*50 + c] = v;
  }
}

// q -> padded bf16 [32][256][208]; rows>=200 and k>=200 are zero.
// MUST run after k_inv (overwrites nsqT region).
__global__ void k_qbf16(const float* __restrict__ qR, unsigned short* __restrict__ qb16)
{
  int idx = blockIdx.x*256 + threadIdx.x;   // 32*256*52
  if (idx >= 32*256*52) return;
  int k4 = (idx % 52)*4;
  int j  = (idx / 52) % 256;
  int b  = idx / (52*256);
  unsigned short o0=0,o1=0,o2=0,o3=0;
  if (j < 200 && k4 < 200) {
    const float* src = qR + (size_t)(b*200 + j)*200 + k4;
    float4 v = *(const float4*)src;
    o0 = f2bf(v.x); o1 = f2bf(v.y); o2 = f2bf(v.z); o3 = f2bf(v.w);
  }
  unsigned short* dst = qb16 + ((size_t)(b*256 + j)*208 + k4);
  dst[0]=o0; dst[1]=o1; dst[2]=o2; dst[3]=o3;
}

// block = (b, 8 i's); lane=j. d operands are wave-uniform -> s_load.
__global__ __launch_bounds__(256) void k_rel(
    const float* __restrict__ dR, const float* __restrict__ qR,
    const float* __restrict__ qMask, const float* __restrict__ dMask,
    const float* __restrict__ invdn, const float* __restrict__ invqn,
    float* __restrict__ rel, float* __restrict__ invrs, int* __restrict__ idxout)
{
  __shared__ float qsh[64*201];
  __shared__ float redv[4][8][2];
  __shared__ int   redi[4][8];
  int tid = threadIdx.x;
  int b  = blockIdx.x / 25;
  int i0 = (blockIdx.x % 25) * 8;
  int j = tid, jr = min(j, 199);
  bool jv = j < 200;
  const float* qb = qR + b*40000;
  const float* db = dR + (b*200 + i0)*200;
  float acc[8];
#pragma unroll
  for (int ii = 0; ii < 8; ii++) acc[ii] = 0.f;

  for (int p = 0; p < 4; p++) {
    int kp = p*64;
    __syncthreads();
    if (p < 3) {
      for (int s = tid; s < 200*64; s += 256) { int kk = s & 63, jj = s >> 6; qsh[kk*201 + jj] = qb[jj*200 + kp + kk]; }
    } else {
      for (int s = tid; s < 200*8; s += 256) { int kk = s & 7, jj = s >> 3; qsh[kk*201 + jj] = qb[jj*200 + kp + kk]; }
    }
    __syncthreads();
    int nk = (p < 3) ? 64 : 8;
    for (int k4 = 0; k4 < nk; k4 += 4) {
      float qv[4];
#pragma unroll
      for (int kk = 0; kk < 4; kk++) qv[kk] = qsh[(k4+kk)*201 + jr];
#pragma unroll
      for (int ii = 0; ii < 8; ii++)
#pragma unroll
        for (int kk = 0; kk < 4; kk++)
          acc[ii] = fmaf(db[ii*200 + kp + k4 + kk], qv[kk], acc[ii]);
    }
  }

  float iqn = invqn[b*200 + jr];
  float qm  = qMask[b*200 + jr];
  int w = tid >> 6, l = tid & 63;
  float rv[8];
#pragma unroll
  for (int ii = 0; ii < 8; ii++) {
    float idn = invdn[b*200 + i0 + ii];
    float dm  = dMask[b*200 + i0 + ii];
    float r = acc[ii]*iqn*idn*qm*dm;
    rv[ii] = r;
    if (jv) rel[(b*200 + i0 + ii)*200 + j] = r;   // coalesced
  }
#pragma unroll
  for (int ii = 0; ii < 8; ii++) {
    float vm = jv ? rv[ii] : NEG_HUGE;
    float vs = jv ? rv[ii] : 0.f;
    int bj = jr;
#pragma unroll
    for (int m = 32; m; m >>= 1) {
      float ov = __shfl_xor(vm, m);
      int   oj = __shfl_xor(bj, m);
      vs += __shfl_xor(vs, m);
      if (ov > vm || (ov == vm && oj < bj)) { vm = ov; bj = oj; }  // first-max wins
    }
    if (l == 0) { redv[w][ii][0] = vm; redv[w][ii][1] = vs; redi[w][ii] = bj; }
  }
  __syncthreads();
  if (tid < 8) {
    float bv = redv[0][tid][0], ss = redv[0][tid][1]; int bj = redi[0][tid];
    for (int w2 = 1; w2 < 4; w2++) {
      ss += redv[w2][tid][1];
      float wv = redv[w2][tid][0]; int wj = redi[w2][tid];
      if (wv > bv || (wv == bv && wj < bj)) { bv = wv; bj = wj; }
    }
    invrs[b*200 + i0 + tid] = 1.f/(ss + EPS);
    idxout[b*200 + i0 + tid] = bj;
  }
}

// block = (b, 8 i's); lane=k. rel operands wave-uniform -> s_load.
__global__ __launch_bounds__(256) void k_wq(
    const float* __restrict__ qR, const float* __restrict__ rel,
    const float* __restrict__ invrs, float* __restrict__ wq)
{
  int tid = threadIdx.x;
  int b = blockIdx.x / 25; int i0 = (blockIdx.x % 25) * 8;
  int kl = min(tid, 199); bool kv = tid < 200;
  const float* qb = qR + b*40000;
  const float* rb = rel + (b*200 + i0)*200;
  float acc[8];
#pragma unroll
  for (int ii = 0; ii < 8; ii++) acc[ii] = 0.f;
  for (int j0 = 0; j0 < 200; j0 += 8) {
    float qv[8];
#pragma unroll
    for (int jj = 0; jj < 8; jj++) qv[jj] = qb[(j0+jj)*200 + kl];
#pragma unroll
    for (int ii = 0; ii < 8; ii++)
#pragma unroll
      for (int jj = 0; jj < 8; jj++)
        acc[ii] = fmaf(rb[ii*200 + j0 + jj], qv[jj], acc[ii]);
  }
#pragma unroll
  for (int ii = 0; ii < 8; ii++) {
    float v = acc[ii]*invrs[b*200 + i0 + ii];
    if (kv) wq[(b*200 + i0 + ii)*200 + tid] = v;
  }
}

// 4 row-groups (m'): A rows built on the fly; N=50 GEMM vs selected M2.
__global__ __launch_bounds__(256) void k_gemm2(
    const float* __restrict__ dR, const float* __restrict__ qR,
    const float* __restrict__ qL, const float* __restrict__ wq,
    const int* __restrict__ idx, const float* __restrict__ m2all,
    float* __restrict__ G)
{
  __shared__ float ash[16*257];
  int tid = threadIdx.x;
  int mp = blockIdx.x / 25;                 // 0..3
  int r0 = (blockIdx.x % 25) * 256;
  int msel = (mp == 0) ? 0 : (mp == 3) ? 3 : 2;
  const float* Bm = m2all + msel*10000;
  float acc[50];
#pragma unroll
  for (int c = 0; c < 50; c++) acc[c] = 0.f;

  for (int p = 0; p < 13; p++) {
    int kp = p*16; int nk = (p < 12) ? 16 : 8;
    __syncthreads();
    for (int s = tid; s < 256*nk; s += 256) {
      int kk, mi;
      if (nk == 16) { kk = s & 15; mi = s >> 4; } else { kk = s & 7; mi = s >> 3; }
      int row = r0 + mi; int k = kp + kk;
      int bb = row / 200;
      float v;
      if (mp == 0)      v = dR[row*200 + k]*qL[bb*200 + k];
      else if (mp == 1) v = dR[row*200 + k]*wq[row*200 + k];
      else if (mp == 2) { float t = wq[row*200 + k]; v = t*t; }
      else { int jid = idx[row]; v = dR[row*200 + k]*qR[(bb*200 + jid)*200 + k]; }
      ash[kk*257 + mi] = v;
    }
    __syncthreads();
    for (int k4 = 0; k4 < nk; k4 += 4) {
      float av[4];
#pragma unroll
      for (int kk = 0; kk < 4; kk++) av[kk] = ash[(k4+kk)*257 + tid];
#pragma unroll
      for (int c = 0; c < 50; c++)
#pragma unroll
        for (int kk = 0; kk < 4; kk++)
          acc[c] = fmaf(av[kk], Bm[c*200 + kp + k4 + kk], acc[c]);
    }
  }
  int row = r0 + tid;
  float* g = G + ((size_t)mp*6400 + row)*50;
#pragma unroll
  for (int c = 0; c < 50; c++) g[c] = acc[c];
}

__global__ void k_epi(
    const float* __restrict__ G, const float* __restrict__ invfpn,
    const float* __restrict__ invapn, const float* __restrict__ invxpn,
    const float* __restrict__ invfqn, const float* __restrict__ invxqn,
    const int* __restrict__ idx, float* __restrict__ out)
{
  int row = blockIdx.x; int c = threadIdx.x;
  if (c >= 50) return;
  int b = row / 200;
  float g0 = G[(0*6400 + row)*50 + c];
  float g1 = G[(1*6400 + row)*50 + c];
  float g2 = G[(2*6400 + row)*50 + c];
  float g3 = G[(3*6400 + row)*50 + c];
  float o0 = g0*invfpn[row*50 + c]*invfqn[b*50 + c];
  float o3 = g1*invapn[row*50 + c]*rsqrtf(fmaxf(g2, EPS));
  int jid = idx[row];
  float o4 = g3*invxpn[row*50 + c]*invxqn[(b*200 + jid)*50 + c];
  out[row*250 + c]       = o0;
  out[row*250 + 150 + c] = o3;
  out[row*250 + 200 + c] = o4;
}

// maxpool via bf16 MFMA. block = (b, c, jh); 4 waves.
// Per block: GEMM tile i[0:256) x j[jh*128,+128) x k[0:208), A = d .* M2_c
// built in registers (2 i-tiles/wave, held across j-tiles), B = q^T bf16
// staged in LDS (128 rows x 216 stride = 55.3 KB -> 2 blocks/CU).
// A-frag (32x32x16): lane holds A[m=lane&31][ks*16 + (lane>>5)*8 + 0..7].
// B-frag: lane holds B[k-octet][n=lane&31] = q[j=n][k-octet].
// C/D: col=lane&31 (j), row=(reg&3)+8*(reg>>2)+4*(lane>>5) (i).
// Emits per-(i,c) partial max/sum over this jh half -> k_comb merges.
__global__ __launch_bounds__(256,2) void k_maxpool_mfma(
    const float* __restrict__ dR, const unsigned short* __restrict__ qb16,
    const float* __restrict__ m2all, const float* __restrict__ invmqn,
    float* __restrict__ pmax, float* __restrict__ psum)
{
  __shared__ __align__(16) unsigned short qsh[128*216];
  int tid = threadIdx.x;
  int blk = blockIdx.x;            // (b*50 + c)*2 + jh
  int jh = blk & 1;
  int bc = blk >> 1;
  int b = bc / 50, c = bc % 50;

  // stage q_bf16 rows jh*128..+127 into LDS (stride 216 kills b128 conflicts)
  {
    const unsigned short* src = qb16 + (size_t)(b*256 + jh*128)*208;
    for (int s = tid; s < 128*26; s += 256) {
      int r = s / 26, ch = s - r*26;
      uint4 v = *(const uint4*)(src + r*208 + ch*8);
      *(uint4*)(qsh + r*216 + ch*8) = v;
    }
  }

  int w = tid >> 6, lane = tid & 63;
  int n = lane & 31, h = lane >> 5;

  // Build A fragments for i-tiles 2w and 2w+1 (fused d*M2 scale + bf16 cvt)
  bf16x8 afrag[2][13];
  const float* M2 = m2all + 10000 + c*200;
#pragma unroll
  for (int t = 0; t < 2; t++) {
    int i = (2*w + t)*32 + n;
    int ir = min(i, 199);                    // pad rows clamp; never written out
    const float* drow = dR + (size_t)(b*200 + ir)*200;
    for (int ks = 0; ks < 13; ks++) {
      int ko = ks*16 + h*8;
      bf16x8 af;
      if (ko < 200) {
        float4 d0 = *(const float4*)(drow + ko);
        float4 d1 = *(const float4*)(drow + ko + 4);
        float4 m0 = *(const float4*)(M2 + ko);
        float4 m1 = *(const float4*)(M2 + ko + 4);
        af[0] = (__bf16)(d0.x*m0.x); af[1] = (__bf16)(d0.y*m0.y);
        af[2] = (__bf16)(d0.z*m0.z); af[3] = (__bf16)(d0.w*m0.w);
        af[4] = (__bf16)(d1.x*m1.x); af[5] = (__bf16)(d1.y*m1.y);
        af[6] = (__bf16)(d1.z*m1.z); af[7] = (__bf16)(d1.w*m1.w);
      } else {
#pragma unroll
        for (int z = 0; z < 8; z++) af[z] = (__bf16)0.0f;
      }
      afrag[t][ks] = af;
    }
  }

  float vm[2][16], vs[2][16];
#pragma unroll
  for (int t = 0; t < 2; t++)
#pragma unroll
    for (int r = 0; r < 16; r++) { vm[t][r] = NEG_HUGE; vs[t][r] = 0.f; }

  __syncthreads();

  for (int jt = 0; jt < 4; jt++) {
    f32x16 C0, C1;
#pragma unroll
    for (int z = 0; z < 16; z++) { C0[z] = 0.f; C1[z] = 0.f; }
    const unsigned short* bptr = qsh + (jt*32 + n)*216 + h*8;
#pragma unroll
    for (int ks = 0; ks < 13; ks++) {
      bf16x8 bf = *(const bf16x8*)(bptr + ks*16);
      C0 = __builtin_amdgcn_mfma_f32_32x32x16_bf16(afrag[0][ks], bf, C0, 0, 0, 0);
      C1 = __builtin_amdgcn_mfma_f32_32x32x16_bf16(afrag[1][ks], bf, C1, 0, 0, 0);
    }
    int j = jh*128 + jt*32 + n;
    bool jvalid = j < 200;
    float iq = jvalid ? invmqn[c*6400 + b*200 + j] : 0.f;
#pragma unroll
    for (int r = 0; r < 16; r++) {
      float v0 = C0[r]*iq, v1 = C1[r]*iq;
      vm[0][r] = fmaxf(vm[0][r], jvalid ? v0 : NEG_HUGE);
      vm[1][r] = fmaxf(vm[1][r], jvalid ? v1 : NEG_HUGE);
      vs[0][r] += v0;
      vs[1][r] += v1;
    }
  }

  // reduce across the 32 j-lanes (both half-waves hold disjoint i-rows)
#pragma unroll
  for (int t = 0; t < 2; t++)
#pragma unroll
    for (int r = 0; r < 16; r++) {
      float a = vm[t][r], s = vs[t][r];
#pragma unroll
      for (int m = 1; m <= 16; m <<= 1) {
        a = fmaxf(a, __shfl_xor(a, m));
        s += __shfl_xor(s, m);
      }
      vm[t][r] = a; vs[t][r] = s;
    }

  if (n == 0) {
#pragma unroll
    for (int t = 0; t < 2; t++) {
      int i0 = (2*w + t)*32;
#pragma unroll
      for (int r = 0; r < 16; r++) {
        int row = (r & 3) + 8*(r >> 2) + 4*h;
        int i = i0 + row;
        if (i < 200) {
          size_t o = (size_t)(jh*6400 + b*200 + i)*50 + c;
          pmax[o] = vm[t][r];
          psum[o] = vs[t][r];
        }
      }
    }
  }
}

__global__ void k_comb(const float* __restrict__ pmax, const float* __restrict__ psum,
                       const float* __restrict__ invmpn, float* __restrict__ out)
{
  int row = blockIdx.x; int c = threadIdx.x;
  if (c >= 50) return;
  float m = fmaxf(pmax[(size_t)row*50 + c], pmax[(size_t)(6400 + row)*50 + c]);
  float s = psum[(size_t)row*50 + c] + psum[(size_t)(6400 + row)*50 + c];
  float ip = invmpn[row*50 + c];
  out[row*250 + 50 + c]  = m*ip;
  out[row*250 + 100 + c] = s*ip*(1.f/200.f);
}

extern "C" void kernel_launch(void* const* d_in, const int* in_sizes, int n_in,
                              void* d_out, int out_size, void* d_ws, size_t ws_size,
                              hipStream_t stream) {
  const float* qR = (const float*)d_in[0];
  const float* qL = (const float*)d_in[1];
  const float* qM = (const float*)d_in[2];
  const float* dR = (const float*)d_in[3];
  // d_in[4] = d_last: unused by the reference
  const float* dM = (const float*)d_in[5];
  const float* fullM = (const float*)d_in[6];
  const float* mpM   = (const float*)d_in[7];
  const float* attM  = (const float*)d_in[8];
  const float* xM    = (const float*)d_in[9];

  float* ws  = (float*)d_ws;
  float* out = (float*)d_out;

  float* m2all  = ws + OFF_M2ALL;
  float* nsqT   = ws + OFF_NSQT;
  unsigned short* qb16 = (unsigned short*)(ws + OFF_QB16);
  float* invfpn = ws + OFF_INVFPN;
  float* invmpn = ws + OFF_INVMPN;
  float* invapn = ws + OFF_INVAPN;
  float* invxpn = ws + OFF_INVXPN;
  float* invmqn = ws + OFF_INVMQN;
  float* invxqn = ws + OFF_INVXQN;
  float* invfqn = ws + OFF_INVFQN;
  float* invdn  = ws + OFF_INVDN;
  float* invqn  = ws + OFF_INVQN;
  float* rel    = ws + OFF_REL;
  float* invrs  = ws + OFF_INVRS;
  int*   idxp   = (int*)(ws + OFF_IDX);
  float* wqp    = ws + OFF_WQ;
  float* G      = ws + OFF_G;
  float* pmaxp  = ws + OFF_PMAX;
  float* psump  = ws + OFF_PSUM;

  k_m2<<<157, 256, 0, stream>>>(fullM, mpM, attM, xM, m2all);
  k_pnorm<<<12800, 64, 0, stream>>>(dR, qR, invdn, invqn);
  k_gemm1<<<201, 256, 0, stream>>>(dR, qR, qL, m2all, nsqT);
  k_inv<<<dim3(200, 51), 256, 0, stream>>>(nsqT, invfpn, invmpn, invapn, invxpn,
                                           invmqn, invxqn, invfqn);
  k_qbf16<<<1664, 256, 0, stream>>>(qR, qb16);        // after k_inv: reuses nsqT
  k_rel<<<800, 256, 0, stream>>>(dR, qR, qM, dM, invdn, invqn, rel, invrs, idxp);
  k_wq<<<800, 256, 0, stream>>>(qR, rel, invrs, wqp);
  k_gemm2<<<100, 256, 0, stream>>>(dR, qR, qL, wqp, idxp, m2all, G);
  k_epi<<<6400, 64, 0, stream>>>(G, invfpn, invapn, invxpn, invfqn, invxqn, idxp, out);
  // after k_epi: pmax/psum reuse G's storage
  k_maxpool_mfma<<<3200, 256, 0, stream>>>(dR, qb16, m2all, invmqn, pmaxp, psump);
  k_comb<<<6400, 64, 0, stream>>>(pmaxp, psump, invmpn, out);
}

// Round 4
// 443.205 us; speedup vs baseline: 3.5453x; 1.9461x over previous
//
#include <hip/hip_runtime.h>
#include <math.h>

// MultiPerspectiveMatch on MI355X — round 4.
// vs round 3:
//  - k_maxpool_mfma v2: one afrag live at a time (t outer, jh inner) => no
//    scratch spill (r3: 527 MB/dispatch scratch writes, VGPR_Count=128 vs
//    ~240 live). d pre-converted to bf16 (db16). Direct out write, k_comb gone.
//  - k_gemm1/k_gemm2 -> MFMA (r3: 288us latency-dead, acc[50] AGPR-bound).
//    B = bf16 M^2 [c'][k]; A rows built on the fly (x^2 / products) in bf16.
//  - norms in bf16^2: ~0.06% rel err on nsq -> ~3e-4 output err (threshold 1.7e-2).

#define EPS 1e-6f
#define NEG_HUGE -3.4e38f

typedef __bf16 bf16x8 __attribute__((ext_vector_type(8)));
typedef float f32x16 __attribute__((ext_vector_type(16)));

// ---- ws offsets (floats) ----
constexpr size_t OFF_M2ALL = 0;            // f32 [4][50][200] = 40,000
constexpr size_t OFF_M2B16 = 40000;        // bf16 [224][208] = 23,296 fl
constexpr size_t OFF_NSQT  = 63296;        // f32 [12928][224] = 2,895,872 (dead after k_inv)
constexpr size_t OFF_QB16  = 63296;        // bf16 [32][256][208] (reuses NSQT after k_inv)
constexpr size_t OFF_DB16  = 915264;       // bf16 [32][256][208]
constexpr size_t OFF_INVFPN= 2959168;      // [6400][50]
constexpr size_t OFF_INVMPN= 3279168;
constexpr size_t OFF_INVAPN= 3599168;
constexpr size_t OFF_INVXPN= 3919168;
constexpr size_t OFF_INVMQN= 4239168;      // [c(50)][6400]
constexpr size_t OFF_INVXQN= 4559168;      // [6400][50]
constexpr size_t OFF_INVFQN= 4879168;      // [32][50]
constexpr size_t OFF_INVDN = 4880768;      // [6400]
constexpr size_t OFF_INVQN = 4887168;      // [6400]
constexpr size_t OFF_REL   = 4893568;      // [32][200][200]  (dead after k_wq)
constexpr size_t OFF_G     = 4893568;      //   [4][6400][50] reuses REL
constexpr size_t OFF_INVRS = 6173568;
constexpr size_t OFF_IDX   = 6179968;      // int
constexpr size_t OFF_WQ    = 6186368;      // [32][200][200]
// end = 7,466,368 floats = 29.9 MB

// m2all f32 + m2b16 (rows c'=m*50+c in [0,200), zero-padded to 224x208)
__global__ void k_m2(const float* __restrict__ fM, const float* __restrict__ mM,
                     const float* __restrict__ aM, const float* __restrict__ xM,
                     float* __restrict__ m2all, unsigned short* __restrict__ m2b16)
{
  int i = blockIdx.x*256 + threadIdx.x;
  if (i < 40000) {
    int m = i / 10000, r = i % 10000;
    const float* s = (m==0)?fM:(m==1)?mM:(m==2)?aM:xM;
    float v = s[r];
    m2all[i] = v*v;
  }
  if (i < 224*208) {
    int row = i / 208, k = i % 208;
    unsigned short o = 0;
    if (row < 200 && k < 200) {
      int m = row / 50, c = row % 50;
      const float* s = (m==0)?fM:(m==1)?mM:(m==2)?aM:xM;
      float v = s[c*200 + k];
      __bf16 h = (__bf16)(v*v);
      o = *(unsigned short*)&h;
    }
    m2b16[i] = o;
  }
}

__global__ void k_pnorm(const float* __restrict__ dR, const float* __restrict__ qR,
                        float* __restrict__ invdn, float* __restrict__ invqn)
{
  int row = blockIdx.x; int l = threadIdx.x;
  const float* src = (row < 6400) ? dR + row*200 : qR + (row-6400)*200;
  float s = 0.f;
  for (int k = l; k < 200; k += 64) { float v = src[k]; s = fmaf(v, v, s); }
#pragma unroll
  for (int m = 32; m; m >>= 1) s += __shfl_xor(s, m);
  if (l == 0) {
    float r = rsqrtf(fmaxf(s, EPS));
    if (row < 6400) invdn[row] = r; else invqn[row-6400] = r;
  }
}

// nsq GEMM via MFMA: rows = [d|q|q_last] squared (bf16), B = m2b16 (N=224).
// A-frag 32x32x16: lane holds A[m=lane&31][ks*16+(lane>>5)*8+z].
// C/D: col=lane&31 (c'), row=(r&3)+8*(r>>2)+4*(lane>>5).
__global__ __launch_bounds__(256,4) void k_gemm1_mfma(
    const float* __restrict__ dR, const float* __restrict__ qR,
    const float* __restrict__ qL, const unsigned short* __restrict__ m2b16,
    float* __restrict__ nsqT)
{
  int tid = threadIdx.x;
  int w = tid >> 6, lane = tid & 63;
  int n = lane & 31, h = lane >> 5;
  int r0 = blockIdx.x * 128;
  int row = r0 + w*32 + n;

  const float* src = dR; bool valid = true;
  if (row < 6400)        src = dR + (size_t)row*200;
  else if (row < 12800)  src = qR + (size_t)(row-6400)*200;
  else if (row < 12832)  src = qL + (size_t)(row-12800)*200;
  else valid = false;

  bf16x8 afrag[13];
#pragma unroll
  for (int ks = 0; ks < 13; ks++) {
    int ko = ks*16 + h*8;
    bf16x8 af;
    if (valid && ko < 200) {
      float4 a0 = *(const float4*)(src + ko);
      float4 a1 = *(const float4*)(src + ko + 4);
      af[0] = (__bf16)(a0.x*a0.x); af[1] = (__bf16)(a0.y*a0.y);
      af[2] = (__bf16)(a0.z*a0.z); af[3] = (__bf16)(a0.w*a0.w);
      af[4] = (__bf16)(a1.x*a1.x); af[5] = (__bf16)(a1.y*a1.y);
      af[6] = (__bf16)(a1.z*a1.z); af[7] = (__bf16)(a1.w*a1.w);
    } else {
#pragma unroll
      for (int z = 0; z < 8; z++) af[z] = (__bf16)0.0f;
    }
    afrag[ks] = af;
  }

  for (int nt = 0; nt < 7; nt++) {
    f32x16 C;
#pragma unroll
    for (int z = 0; z < 16; z++) C[z] = 0.f;
    const unsigned short* bp = m2b16 + (size_t)(nt*32 + n)*208 + h*8;
#pragma unroll
    for (int ks = 0; ks < 13; ks++) {
      bf16x8 bf = *(const bf16x8*)(bp + ks*16);
      C = __builtin_amdgcn_mfma_f32_32x32x16_bf16(afrag[ks], bf, C, 0, 0, 0);
    }
#pragma unroll
    for (int r = 0; r < 16; r++) {
      int mrow = (r & 3) + 8*(r >> 2) + 4*h;
      nsqT[(size_t)(r0 + w*32 + mrow)*224 + nt*32 + n] = C[r];  // coalesced per r
    }
  }
}

__global__ void k_inv(const float* __restrict__ nsqT,
    float* __restrict__ invfpn, float* __restrict__ invmpn,
    float* __restrict__ invapn, float* __restrict__ invxpn,
    float* __restrict__ invmqn, float* __restrict__ invxqn,
    float* __restrict__ invfqn)
{
  int nIdx = blockIdx.x;                    // 0..199 = m*50+c
  int row = blockIdx.y*256 + threadIdx.x;
  if (row >= 12832) return;
  int m = nIdx / 50, c = nIdx % 50;
  float v = rsqrtf(fmaxf(nsqT[(size_t)row*224 + nIdx], EPS));
  if (row < 6400) {
    if (m == 0)      invfpn[row*50 + c] = v;
    else if (m == 1) invmpn[row*50 + c] = v;
    else if (m == 2) invapn[row*50 + c] = v;
    else             invxpn[row*50 + c] = v;
  } else if (row < 12800) {
    int r2 = row - 6400;
    if (m == 1)      invmqn[c*6400 + r2] = v;
    else if (m == 3) invxqn[r2*50 + c] = v;
  } else {
    if (m == 0)      invfqn[(row-12800)*50 + c] = v;
  }
}

// q and d -> padded bf16 [32][256][208]. MUST run after k_inv (qb16 aliases nsqT).
__global__ void k_cvt16(const float* __restrict__ qR, const float* __restrict__ dR,
                        unsigned short* __restrict__ qb16, unsigned short* __restrict__ db16)
{
  int idx = blockIdx.x*256 + threadIdx.x;   // 2 * 32*256*52
  const int half = 32*256*52;
  if (idx >= 2*half) return;
  int sel = idx >= half;
  int id = sel ? idx - half : idx;
  int k4 = (id % 52)*4;
  int j  = (id / 52) % 256;
  int b  = id / (52*256);
  const float* src = sel ? dR : qR;
  unsigned short* dst = sel ? db16 : qb16;
  ushort4 o = {0,0,0,0};
  if (j < 200 && k4 < 200) {
    float4 v = *(const float4*)(src + (size_t)(b*200 + j)*200 + k4);
    __bf16 h0=(__bf16)v.x, h1=(__bf16)v.y, h2=(__bf16)v.z, h3=(__bf16)v.w;
    o.x = *(unsigned short*)&h0; o.y = *(unsigned short*)&h1;
    o.z = *(unsigned short*)&h2; o.w = *(unsigned short*)&h3;
  }
  *(ushort4*)(dst + (size_t)(b*256 + j)*208 + k4) = o;
}

// block = (b, 8 i's); lane=j. d operands wave-uniform -> s_load. fp32 exact
// (rel feeds argmax + attentive weighting; keep full precision).
__global__ __launch_bounds__(256) void k_rel(
    const float* __restrict__ dR, const float* __restrict__ qR,
    const float* __restrict__ qMask, const float* __restrict__ dMask,
    const float* __restrict__ invdn, const float* __restrict__ invqn,
    float* __restrict__ rel, float* __restrict__ invrs, int* __restrict__ idxout)
{
  __shared__ float qsh[64*201];
  __shared__ float redv[4][8][2];
  __shared__ int   redi[4][8];
  int tid = threadIdx.x;
  int b  = blockIdx.x / 25;
  int i0 = (blockIdx.x % 25) * 8;
  int j = tid, jr = min(j, 199);
  bool jv = j < 200;
  const float* qb = qR + b*40000;
  const float* db = dR + (b*200 + i0)*200;
  float acc[8];
#pragma unroll
  for (int ii = 0; ii < 8; ii++) acc[ii] = 0.f;

  for (int p = 0; p < 4; p++) {
    int kp = p*64;
    __syncthreads();
    if (p < 3) {
      for (int s = tid; s < 200*64; s += 256) { int kk = s & 63, jj = s >> 6; qsh[kk*201 + jj] = qb[jj*200 + kp + kk]; }
    } else {
      for (int s = tid; s < 200*8; s += 256) { int kk = s & 7, jj = s >> 3; qsh[kk*201 + jj] = qb[jj*200 + kp + kk]; }
    }
    __syncthreads();
    int nk = (p < 3) ? 64 : 8;
    for (int k4 = 0; k4 < nk; k4 += 4) {
      float qv[4];
#pragma unroll
      for (int kk = 0; kk < 4; kk++) qv[kk] = qsh[(k4+kk)*201 + jr];
#pragma unroll
      for (int ii = 0; ii < 8; ii++)
#pragma unroll
        for (int kk = 0; kk < 4; kk++)
          acc[ii] = fmaf(db[ii*200 + kp + k4 + kk], qv[kk], acc[ii]);
    }
  }

  float iqn = invqn[b*200 + jr];
  float qm  = qMask[b*200 + jr];
  int w = tid >> 6, l = tid & 63;
  float rv[8];
#pragma unroll
  for (int ii = 0; ii < 8; ii++) {
    float idn = invdn[b*200 + i0 + ii];
    float dm  = dMask[b*200 + i0 + ii];
    float r = acc[ii]*iqn*idn*qm*dm;
    rv[ii] = r;
    if (jv) rel[(b*200 + i0 + ii)*200 + j] = r;   // coalesced
  }
#pragma unroll
  for (int ii = 0; ii < 8; ii++) {
    float vm = jv ? rv[ii] : NEG_HUGE;
    float vs = jv ? rv[ii] : 0.f;
    int bj = jr;
#pragma unroll
    for (int m = 32; m; m >>= 1) {
      float ov = __shfl_xor(vm, m);
      int   oj = __shfl_xor(bj, m);
      vs += __shfl_xor(vs, m);
      if (ov > vm || (ov == vm && oj < bj)) { vm = ov; bj = oj; }  // first-max wins
    }
    if (l == 0) { redv[w][ii][0] = vm; redv[w][ii][1] = vs; redi[w][ii] = bj; }
  }
  __syncthreads();
  if (tid < 8) {
    float bv = redv[0][tid][0], ss = redv[0][tid][1]; int bj = redi[0][tid];
    for (int w2 = 1; w2 < 4; w2++) {
      ss += redv[w2][tid][1];
      float wv = redv[w2][tid][0]; int wj = redi[w2][tid];
      if (wv > bv || (wv == bv && wj < bj)) { bv = wv; bj = wj; }
    }
    invrs[b*200 + i0 + tid] = 1.f/(ss + EPS);
    idxout[b*200 + i0 + tid] = bj;
  }
}

// block = (b, 8 i's); lane=k. rel operands wave-uniform -> s_load.
__global__ __launch_bounds__(256) void k_wq(
    const float* __restrict__ qR, const float* __restrict__ rel,
    const float* __restrict__ invrs, float* __restrict__ wq)
{
  int tid = threadIdx.x;
  int b = blockIdx.x / 25; int i0 = (blockIdx.x % 25) * 8;
  int kl = min(tid, 199); bool kv = tid < 200;
  const float* qb = qR + b*40000;
  const float* rb = rel + (b*200 + i0)*200;
  float acc[8];
#pragma unroll
  for (int ii = 0; ii < 8; ii++) acc[ii] = 0.f;
  for (int j0 = 0; j0 < 200; j0 += 8) {
    float qv[8];
#pragma unroll
    for (int jj = 0; jj < 8; jj++) qv[jj] = qb[(j0+jj)*200 + kl];
#pragma unroll
    for (int ii = 0; ii < 8; ii++)
#pragma unroll
      for (int jj = 0; jj < 8; jj++)
        acc[ii] = fmaf(rb[ii*200 + j0 + jj], qv[jj], acc[ii]);
  }
#pragma unroll
  for (int ii = 0; ii < 8; ii++) {
    float v = acc[ii]*invrs[b*200 + i0 + ii];
    if (kv) wq[(b*200 + i0 + ii)*200 + tid] = v;
  }
}

// Numerator GEMMs via MFMA: mp in {0:d*qL, 1:d*wq, 2:wq^2, 3:d*q[argmax]};
// B = m2b16 rows [msel*50, +64) (rows>=200 are zeros).
__global__ __launch_bounds__(256,4) void k_gemm2_mfma(
    const float* __restrict__ dR, const float* __restrict__ qR,
    const float* __restrict__ qL, const float* __restrict__ wq,
    const int* __restrict__ idx, const unsigned short* __restrict__ m2b16,
    float* __restrict__ G)
{
  int tid = threadIdx.x;
  int w = tid >> 6, lane = tid & 63;
  int n = lane & 31, h = lane >> 5;
  int mp = blockIdx.x / 50;
  int r0 = (blockIdx.x % 50) * 128;
  int row = r0 + w*32 + n;
  int bb = row / 200;
  int msel = (mp == 0) ? 0 : (mp == 3) ? 3 : 2;

  const float* s0 = dR + (size_t)row*200;
  const float* s1;
  if (mp == 0)      s1 = qL + (size_t)bb*200;
  else if (mp == 1) s1 = wq + (size_t)row*200;
  else if (mp == 2) { s0 = wq + (size_t)row*200; s1 = s0; }
  else              s1 = qR + (size_t)(bb*200 + idx[row])*200;

  bf16x8 afrag[13];
#pragma unroll
  for (int ks = 0; ks < 13; ks++) {
    int ko = ks*16 + h*8;
    bf16x8 af;
    if (ko < 200) {
      float4 a0 = *(const float4*)(s0 + ko);
      float4 a1 = *(const float4*)(s0 + ko + 4);
      float4 b0 = *(const float4*)(s1 + ko);
      float4 b1 = *(const float4*)(s1 + ko + 4);
      af[0] = (__bf16)(a0.x*b0.x); af[1] = (__bf16)(a0.y*b0.y);
      af[2] = (__bf16)(a0.z*b0.z); af[3] = (__bf16)(a0.w*b0.w);
      af[4] = (__bf16)(a1.x*b1.x); af[5] = (__bf16)(a1.y*b1.y);
      af[6] = (__bf16)(a1.z*b1.z); af[7] = (__bf16)(a1.w*b1.w);
    } else {
#pragma unroll
      for (int z = 0; z < 8; z++) af[z] = (__bf16)0.0f;
    }
    afrag[ks] = af;
  }

  for (int nt = 0; nt < 2; nt++) {
    f32x16 C;
#pragma unroll
    for (int z = 0; z < 16; z++) C[z] = 0.f;
    const unsigned short* bp = m2b16 + (size_t)(msel*50 + nt*32 + n)*208 + h*8;
#pragma unroll
    for (int ks = 0; ks < 13; ks++) {
      bf16x8 bf = *(const bf16x8*)(bp + ks*16);
      C = __builtin_amdgcn_mfma_f32_32x32x16_bf16(afrag[ks], bf, C, 0, 0, 0);
    }
    int cc = nt*32 + n;
    if (cc < 50) {
#pragma unroll
      for (int r = 0; r < 16; r++) {
        int mrow = (r & 3) + 8*(r >> 2) + 4*h;
        G[(size_t)(mp*6400 + r0 + w*32 + mrow)*50 + cc] = C[r];
      }
    }
  }
}

__global__ void k_epi(
    const float* __restrict__ G, const float* __restrict__ invfpn,
    const float* __restrict__ invapn, const float* __restrict__ invxpn,
    const float* __restrict__ invfqn, const float* __restrict__ invxqn,
    const int* __restrict__ idx, float* __restrict__ out)
{
  int row = blockIdx.x; int c = threadIdx.x;
  if (c >= 50) return;
  int b = row / 200;
  float g0 = G[(0*6400 + row)*50 + c];
  float g1 = G[(1*6400 + row)*50 + c];
  float g2 = G[(2*6400 + row)*50 + c];
  float g3 = G[(3*6400 + row)*50 + c];
  float o0 = g0*invfpn[row*50 + c]*invfqn[b*50 + c];
  float o3 = g1*invapn[row*50 + c]*rsqrtf(fmaxf(g2, EPS));
  int jid = idx[row];
  float o4 = g3*invxpn[row*50 + c]*invxqn[(b*200 + jid)*50 + c];
  out[row*250 + c]       = o0;
  out[row*250 + 150 + c] = o3;
  out[row*250 + 200 + c] = o4;
}

// maxpool via MFMA, v2 (no spill): block=(b,c), grid 1600, 4 waves.
// t outer (one afrag[13] live), jh inner (B restaged per t — cheap vs MFMA).
// A = db16 .* M2_c (bf16 in / f32 scale / bf16 out), B = qb16 via LDS.
// C/D: col=lane&31 (j), row=(r&3)+8*(r>>2)+4*(lane>>5) (i).
// Folds max/mean over j in-register, writes out cols 50:150 directly.
__global__ __launch_bounds__(256,2) void k_maxpool_mfma(
    const unsigned short* __restrict__ db16, const unsigned short* __restrict__ qb16,
    const float* __restrict__ m2all, const float* __restrict__ invmqn,
    const float* __restrict__ invmpn, float* __restrict__ out)
{
  __shared__ __align__(16) unsigned short qsh[128*216];  // 55296 B -> 2 blocks/CU
  int tid = threadIdx.x;
  int b = blockIdx.x / 50, c = blockIdx.x % 50;
  int w = tid >> 6, lane = tid & 63;
  int n = lane & 31, h = lane >> 5;
  const float* M2 = m2all + 10000 + c*200;  // maxpool_M^2, f32

  for (int t = 0; t < 2; t++) {
    int tt = w*2 + t;                        // i-tile 0..7
    // A-frag for rows tt*32+n (db16 rows >=200 and k>=200 are zeros)
    bf16x8 afrag[13];
    const unsigned short* dbp = db16 + (size_t)(b*256 + tt*32 + n)*208;
#pragma unroll
    for (int ks = 0; ks < 13; ks++) {
      int ko = ks*16 + h*8;
      bf16x8 af;
      if (ko < 200) {
        bf16x8 d8 = *(const bf16x8*)(dbp + ko);
        float4 m0 = *(const float4*)(M2 + ko);
        float4 m1 = *(const float4*)(M2 + ko + 4);
        af[0] = (__bf16)((float)d8[0]*m0.x); af[1] = (__bf16)((float)d8[1]*m0.y);
        af[2] = (__bf16)((float)d8[2]*m0.z); af[3] = (__bf16)((float)d8[3]*m0.w);
        af[4] = (__bf16)((float)d8[4]*m1.x); af[5] = (__bf16)((float)d8[5]*m1.y);
        af[6] = (__bf16)((float)d8[6]*m1.z); af[7] = (__bf16)((float)d8[7]*m1.w);
      } else {
#pragma unroll
        for (int z = 0; z < 8; z++) af[z] = (__bf16)0.0f;
      }
      afrag[ks] = af;
    }

    float vm[16], vs[16];
#pragma unroll
    for (int r = 0; r < 16; r++) { vm[r] = NEG_HUGE; vs[r] = 0.f; }

    for (int jh = 0; jh < 2; jh++) {
      __syncthreads();
      {
        const unsigned short* src = qb16 + (size_t)(b*256 + jh*128)*208;
        for (int s = tid; s < 128*26; s += 256) {
          int r = s / 26, ch = s - r*26;
          *(uint4*)(qsh + r*216 + ch*8) = *(const uint4*)(src + r*208 + ch*8);
        }
      }
      __syncthreads();
      for (int jt = 0; jt < 4; jt++) {
        f32x16 C;
#pragma unroll
        for (int z = 0; z < 16; z++) C[z] = 0.f;
        const unsigned short* bptr = qsh + (jt*32 + n)*216 + h*8;
#pragma unroll
        for (int ks = 0; ks < 13; ks++) {
          bf16x8 bf = *(const bf16x8*)(bptr + ks*16);
          C = __builtin_amdgcn_mfma_f32_32x32x16_bf16(afrag[ks], bf, C, 0, 0, 0);
        }
        int j = jh*128 + jt*32 + n;
        bool jvalid = j < 200;
        float iq = jvalid ? invmqn[c*6400 + b*200 + j] : 0.f;
#pragma unroll
        for (int r = 0; r < 16; r++) {
          float v = C[r]*iq;
          vm[r] = fmaxf(vm[r], jvalid ? v : NEG_HUGE);
          vs[r] += v;
        }
      }
    }

    // reduce across 32 j-lanes (h halves hold disjoint i-rows — keep separate)
#pragma unroll
    for (int r = 0; r < 16; r++) {
      float a = vm[r], s = vs[r];
#pragma unroll
      for (int m = 1; m <= 16; m <<= 1) {
        a = fmaxf(a, __shfl_xor(a, m));
        s += __shfl_xor(s, m);
      }
      vm[r] = a; vs[r] = s;
    }
    if (n == 0) {
#pragma unroll
      for (int r = 0; r < 16; r++) {
        int i = tt*32 + (r & 3) + 8*(r >> 2) + 4*h;
        if (i < 200) {
          float ip = invmpn[(b*200 + i)*50 + c];
          int ob = (b*200 + i)*250 + c;
          out[ob + 50]  = vm[r]*ip;
          out[ob + 100] = vs[r]*ip*(1.f/200.f);
        }
      }
    }
  }
}

extern "C" void kernel_launch(void* const* d_in, const int* in_sizes, int n_in,
                              void* d_out, int out_size, void* d_ws, size_t ws_size,
                              hipStream_t stream) {
  const float* qR = (const float*)d_in[0];
  const float* qL = (const float*)d_in[1];
  const float* qM = (const float*)d_in[2];
  const float* dR = (const float*)d_in[3];
  // d_in[4] = d_last: unused by the reference
  const float* dM = (const float*)d_in[5];
  const float* fullM = (const float*)d_in[6];
  const float* mpM   = (const float*)d_in[7];
  const float* attM  = (const float*)d_in[8];
  const float* xM    = (const float*)d_in[9];

  float* ws  = (float*)d_ws;
  float* out = (float*)d_out;

  float* m2all  = ws + OFF_M2ALL;
  unsigned short* m2b16 = (unsigned short*)(ws + OFF_M2B16);
  float* nsqT   = ws + OFF_NSQT;
  unsigned short* qb16 = (unsigned short*)(ws + OFF_QB16);
  unsigned short* db16 = (unsigned short*)(ws + OFF_DB16);
  float* invfpn = ws + OFF_INVFPN;
  float* invmpn = ws + OFF_INVMPN;
  float* invapn = ws + OFF_INVAPN;
  float* invxpn = ws + OFF_INVXPN;
  float* invmqn = ws + OFF_INVMQN;
  float* invxqn = ws + OFF_INVXQN;
  float* invfqn = ws + OFF_INVFQN;
  float* invdn  = ws + OFF_INVDN;
  float* invqn  = ws + OFF_INVQN;
  float* rel    = ws + OFF_REL;
  float* G      = ws + OFF_G;        // aliases rel (rel dead after k_wq)
  float* invrs  = ws + OFF_INVRS;
  int*   idxp   = (int*)(ws + OFF_IDX);
  float* wqp    = ws + OFF_WQ;

  k_m2<<<182, 256, 0, stream>>>(fullM, mpM, attM, xM, m2all, m2b16);
  k_pnorm<<<12800, 64, 0, stream>>>(dR, qR, invdn, invqn);
  k_gemm1_mfma<<<101, 256, 0, stream>>>(dR, qR, qL, m2b16, nsqT);
  k_inv<<<dim3(200, 51), 256, 0, stream>>>(nsqT, invfpn, invmpn, invapn, invxpn,
                                           invmqn, invxqn, invfqn);
  k_cvt16<<<6656, 256, 0, stream>>>(qR, dR, qb16, db16);   // after k_inv (aliases nsqT)
  k_rel<<<800, 256, 0, stream>>>(dR, qR, qM, dM, invdn, invqn, rel, invrs, idxp);
  k_wq<<<800, 256, 0, stream>>>(qR, rel, invrs, wqp);
  k_gemm2_mfma<<<200, 256, 0, stream>>>(dR, qR, qL, wqp, idxp, m2b16, G);
  k_epi<<<6400, 64, 0, stream>>>(G, invfpn, invapn, invxpn, invfqn, invxqn, idxp, out);
  k_maxpool_mfma<<<1600, 256, 0, stream>>>(db16, qb16, m2all, invmqn, invmpn, out);
}

// Round 5
// 376.497 us; speedup vs baseline: 4.1734x; 1.1772x over previous
//
#include <hip/hip_runtime.h>
#include <math.h>

// MultiPerspectiveMatch on MI355X — round 5.
// vs round 4 (k_maxpool 200us with MfmaUtil 9%, WRITE_SIZE 103MB vs 2.6MB real):
//  - k_maxpool_mfma v3:
//      * invmqn folded into staged B (qsh = bf16(q * iq)); padded j contribute 0
//      * jh outer / t inner: 2 stagings per block; vm/vs live only within one
//        jh's jt loop, flushed to a 2KB LDS accumulator -> no reg state across
//        staging barriers (r4 spill cause)
//      * skip fully-padded j-tile; stage 96 rows for jh=1
//      * compact coalesced output pmax2/psum2[(b*50+c)][256] (r4: single-lane
//        4B scatter at 1KB stride across 8 XCDs -> 16x write-allocate amp)
//  - k_out: assembles out[row][0:250] lane-coalesced (replaces k_epi scatter
//    for maxpool cols + k_comb)
//  - k_pnorm: 4 rows/block (grid 3200, was 12800 x 64thr)

#define EPS 1e-6f
#define NEG_HUGE -3.4e38f

typedef __bf16 bf16x8 __attribute__((ext_vector_type(8)));
typedef float f32x16 __attribute__((ext_vector_type(16)));

// ---- ws offsets (floats) ----
constexpr size_t OFF_M2ALL = 0;            // f32 [4][50][200] = 40,000
constexpr size_t OFF_M2B16 = 40000;        // bf16 [224][208] = 23,296 fl
constexpr size_t OFF_NSQT  = 63296;        // f32 [12928][224] (dead after k_inv)
constexpr size_t OFF_QB16  = 63296;        // bf16 [32][256][208] (reuses NSQT)
constexpr size_t OFF_DB16  = 915264;       // bf16 [32][256][208]
constexpr size_t OFF_INVFPN= 2959168;      // [6400][50]
constexpr size_t OFF_INVMPN= 3279168;
constexpr size_t OFF_INVAPN= 3599168;
constexpr size_t OFF_INVXPN= 3919168;
constexpr size_t OFF_INVMQN= 4239168;      // [c(50)][6400]
constexpr size_t OFF_INVXQN= 4559168;      // [6400][50]
constexpr size_t OFF_INVFQN= 4879168;      // [32][50]
constexpr size_t OFF_INVDN = 4880768;      // [6400]
constexpr size_t OFF_INVQN = 4887168;      // [6400]
constexpr size_t OFF_REL   = 4893568;      // [32][200][200]  (dead after k_wq)
constexpr size_t OFF_G     = 4893568;      //   [4][6400][50] reuses REL
constexpr size_t OFF_INVRS = 6173568;
constexpr size_t OFF_IDX   = 6179968;      // int
constexpr size_t OFF_WQ    = 6186368;      // [32][200][200]
constexpr size_t OFF_PMAX2 = 7466368;      // [1600][256]
constexpr size_t OFF_PSUM2 = 7875968;      // [1600][256]
// end = 8,285,568 floats = 33.1 MB

__global__ void k_m2(const float* __restrict__ fM, const float* __restrict__ mM,
                     const float* __restrict__ aM, const float* __restrict__ xM,
                     float* __restrict__ m2all, unsigned short* __restrict__ m2b16)
{
  int i = blockIdx.x*256 + threadIdx.x;
  if (i < 40000) {
    int m = i / 10000, r = i % 10000;
    const float* s = (m==0)?fM:(m==1)?mM:(m==2)?aM:xM;
    float v = s[r];
    m2all[i] = v*v;
  }
  if (i < 224*208) {
    int row = i / 208, k = i % 208;
    unsigned short o = 0;
    if (row < 200 && k < 200) {
      int m = row / 50, c = row % 50;
      const float* s = (m==0)?fM:(m==1)?mM:(m==2)?aM:xM;
      float v = s[c*200 + k];
      __bf16 h = (__bf16)(v*v);
      o = *(unsigned short*)&h;
    }
    m2b16[i] = o;
  }
}

// 4 rows per block (one per wave)
__global__ __launch_bounds__(256) void k_pnorm(
    const float* __restrict__ dR, const float* __restrict__ qR,
    float* __restrict__ invdn, float* __restrict__ invqn)
{
  int row = blockIdx.x*4 + (threadIdx.x >> 6);
  int l = threadIdx.x & 63;
  const float* src = (row < 6400) ? dR + (size_t)row*200 : qR + (size_t)(row-6400)*200;
  float s = 0.f;
  for (int k = l; k < 200; k += 64) { float v = src[k]; s = fmaf(v, v, s); }
#pragma unroll
  for (int m = 32; m; m >>= 1) s += __shfl_xor(s, m);
  if (l == 0) {
    float r = rsqrtf(fmaxf(s, EPS));
    if (row < 6400) invdn[row] = r; else invqn[row-6400] = r;
  }
}

// nsq GEMM via MFMA: rows = [d|q|q_last] squared (bf16), B = m2b16 (N=224).
__global__ __launch_bounds__(256,4) void k_gemm1_mfma(
    const float* __restrict__ dR, const float* __restrict__ qR,
    const float* __restrict__ qL, const unsigned short* __restrict__ m2b16,
    float* __restrict__ nsqT)
{
  int tid = threadIdx.x;
  int w = tid >> 6, lane = tid & 63;
  int n = lane & 31, h = lane >> 5;
  int r0 = blockIdx.x * 128;
  int row = r0 + w*32 + n;

  const float* src = dR; bool valid = true;
  if (row < 6400)        src = dR + (size_t)row*200;
  else if (row < 12800)  src = qR + (size_t)(row-6400)*200;
  else if (row < 12832)  src = qL + (size_t)(row-12800)*200;
  else valid = false;

  bf16x8 afrag[13];
#pragma unroll
  for (int ks = 0; ks < 13; ks++) {
    int ko = ks*16 + h*8;
    bf16x8 af;
    if (valid && ko < 200) {
      float4 a0 = *(const float4*)(src + ko);
      float4 a1 = *(const float4*)(src + ko + 4);
      af[0] = (__bf16)(a0.x*a0.x); af[1] = (__bf16)(a0.y*a0.y);
      af[2] = (__bf16)(a0.z*a0.z); af[3] = (__bf16)(a0.w*a0.w);
      af[4] = (__bf16)(a1.x*a1.x); af[5] = (__bf16)(a1.y*a1.y);
      af[6] = (__bf16)(a1.z*a1.z); af[7] = (__bf16)(a1.w*a1.w);
    } else {
#pragma unroll
      for (int z = 0; z < 8; z++) af[z] = (__bf16)0.0f;
    }
    afrag[ks] = af;
  }

  for (int nt = 0; nt < 7; nt++) {
    f32x16 C;
#pragma unroll
    for (int z = 0; z < 16; z++) C[z] = 0.f;
    const unsigned short* bp = m2b16 + (size_t)(nt*32 + n)*208 + h*8;
#pragma unroll
    for (int ks = 0; ks < 13; ks++) {
      bf16x8 bf = *(const bf16x8*)(bp + ks*16);
      C = __builtin_amdgcn_mfma_f32_32x32x16_bf16(afrag[ks], bf, C, 0, 0, 0);
    }
#pragma unroll
    for (int r = 0; r < 16; r++) {
      int mrow = (r & 3) + 8*(r >> 2) + 4*h;
      nsqT[(size_t)(r0 + w*32 + mrow)*224 + nt*32 + n] = C[r];
    }
  }
}

__global__ void k_inv(const float* __restrict__ nsqT,
    float* __restrict__ invfpn, float* __restrict__ invmpn,
    float* __restrict__ invapn, float* __restrict__ invxpn,
    float* __restrict__ invmqn, float* __restrict__ invxqn,
    float* __restrict__ invfqn)
{
  int nIdx = blockIdx.x;                    // 0..199 = m*50+c
  int row = blockIdx.y*256 + threadIdx.x;
  if (row >= 12832) return;
  int m = nIdx / 50, c = nIdx % 50;
  float v = rsqrtf(fmaxf(nsqT[(size_t)row*224 + nIdx], EPS));
  if (row < 6400) {
    if (m == 0)      invfpn[row*50 + c] = v;
    else if (m == 1) invmpn[row*50 + c] = v;
    else if (m == 2) invapn[row*50 + c] = v;
    else             invxpn[row*50 + c] = v;
  } else if (row < 12800) {
    int r2 = row - 6400;
    if (m == 1)      invmqn[c*6400 + r2] = v;
    else if (m == 3) invxqn[r2*50 + c] = v;
  } else {
    if (m == 0)      invfqn[(row-12800)*50 + c] = v;
  }
}

// q and d -> padded bf16 [32][256][208]. MUST run after k_inv (qb16 aliases nsqT).
__global__ void k_cvt16(const float* __restrict__ qR, const float* __restrict__ dR,
                        unsigned short* __restrict__ qb16, unsigned short* __restrict__ db16)
{
  int idx = blockIdx.x*256 + threadIdx.x;   // 2 * 32*256*52
  const int half = 32*256*52;
  if (idx >= 2*half) return;
  int sel = idx >= half;
  int id = sel ? idx - half : idx;
  int k4 = (id % 52)*4;
  int j  = (id / 52) % 256;
  int b  = id / (52*256);
  const float* src = sel ? dR : qR;
  unsigned short* dst = sel ? db16 : qb16;
  ushort4 o = {0,0,0,0};
  if (j < 200 && k4 < 200) {
    float4 v = *(const float4*)(src + (size_t)(b*200 + j)*200 + k4);
    __bf16 h0=(__bf16)v.x, h1=(__bf16)v.y, h2=(__bf16)v.z, h3=(__bf16)v.w;
    o.x = *(unsigned short*)&h0; o.y = *(unsigned short*)&h1;
    o.z = *(unsigned short*)&h2; o.w = *(unsigned short*)&h3;
  }
  *(ushort4*)(dst + (size_t)(b*256 + j)*208 + k4) = o;
}

// block = (b, 8 i's); lane=j. d operands wave-uniform -> s_load. fp32 exact
// (rel feeds argmax — bf16 would flip near-tied argmaxes; keep full precision).
__global__ __launch_bounds__(256) void k_rel(
    const float* __restrict__ dR, const float* __restrict__ qR,
    const float* __restrict__ qMask, const float* __restrict__ dMask,
    const float* __restrict__ invdn, const float* __restrict__ invqn,
    float* __restrict__ rel, float* __restrict__ invrs, int* __restrict__ idxout)
{
  __shared__ float qsh[64*201];
  __shared__ float redv[4][8][2];
  __shared__ int   redi[4][8];
  int tid = threadIdx.x;
  int b  = blockIdx.x / 25;
  int i0 = (blockIdx.x % 25) * 8;
  int j = tid, jr = min(j, 199);
  bool jv = j < 200;
  const float* qb = qR + b*40000;
  const float* db = dR + (b*200 + i0)*200;
  float acc[8];
#pragma unroll
  for (int ii = 0; ii < 8; ii++) acc[ii] = 0.f;

  for (int p = 0; p < 4; p++) {
    int kp = p*64;
    __syncthreads();
    if (p < 3) {
      for (int s = tid; s < 200*64; s += 256) { int kk = s & 63, jj = s >> 6; qsh[kk*201 + jj] = qb[jj*200 + kp + kk]; }
    } else {
      for (int s = tid; s < 200*8; s += 256) { int kk = s & 7, jj = s >> 3; qsh[kk*201 + jj] = qb[jj*200 + kp + kk]; }
    }
    __syncthreads();
    int nk = (p < 3) ? 64 : 8;
    for (int k4 = 0; k4 < nk; k4 += 4) {
      float qv[4];
#pragma unroll
      for (int kk = 0; kk < 4; kk++) qv[kk] = qsh[(k4+kk)*201 + jr];
#pragma unroll
      for (int ii = 0; ii < 8; ii++)
#pragma unroll
        for (int kk = 0; kk < 4; kk++)
          acc[ii] = fmaf(db[ii*200 + kp + k4 + kk], qv[kk], acc[ii]);
    }
  }

  float iqn = invqn[b*200 + jr];
  float qm  = qMask[b*200 + jr];
  int w = tid >> 6, l = tid & 63;
  float rv[8];
#pragma unroll
  for (int ii = 0; ii < 8; ii++) {
    float idn = invdn[b*200 + i0 + ii];
    float dm  = dMask[b*200 + i0 + ii];
    float r = acc[ii]*iqn*idn*qm*dm;
    rv[ii] = r;
    if (jv) rel[(b*200 + i0 + ii)*200 + j] = r;   // coalesced
  }
#pragma unroll
  for (int ii = 0; ii < 8; ii++) {
    float vm = jv ? rv[ii] : NEG_HUGE;
    float vs = jv ? rv[ii] : 0.f;
    int bj = jr;
#pragma unroll
    for (int m = 32; m; m >>= 1) {
      float ov = __shfl_xor(vm, m);
      int   oj = __shfl_xor(bj, m);
      vs += __shfl_xor(vs, m);
      if (ov > vm || (ov == vm && oj < bj)) { vm = ov; bj = oj; }  // first-max wins
    }
    if (l == 0) { redv[w][ii][0] = vm; redv[w][ii][1] = vs; redi[w][ii] = bj; }
  }
  __syncthreads();
  if (tid < 8) {
    float bv = redv[0][tid][0], ss = redv[0][tid][1]; int bj = redi[0][tid];
    for (int w2 = 1; w2 < 4; w2++) {
      ss += redv[w2][tid][1];
      float wv = redv[w2][tid][0]; int wj = redi[w2][tid];
      if (wv > bv || (wv == bv && wj < bj)) { bv = wv; bj = wj; }
    }
    invrs[b*200 + i0 + tid] = 1.f/(ss + EPS);
    idxout[b*200 + i0 + tid] = bj;
  }
}

// block = (b, 8 i's); lane=k. rel operands wave-uniform -> s_load.
__global__ __launch_bounds__(256) void k_wq(
    const float* __restrict__ qR, const float* __restrict__ rel,
    const float* __restrict__ invrs, float* __restrict__ wq)
{
  int tid = threadIdx.x;
  int b = blockIdx.x / 25; int i0 = (blockIdx.x % 25) * 8;
  int kl = min(tid, 199); bool kv = tid < 200;
  const float* qb = qR + b*40000;
  const float* rb = rel + (b*200 + i0)*200;
  float acc[8];
#pragma unroll
  for (int ii = 0; ii < 8; ii++) acc[ii] = 0.f;
  for (int j0 = 0; j0 < 200; j0 += 8) {
    float qv[8];
#pragma unroll
    for (int jj = 0; jj < 8; jj++) qv[jj] = qb[(j0+jj)*200 + kl];
#pragma unroll
    for (int ii = 0; ii < 8; ii++)
#pragma unroll
      for (int jj = 0; jj < 8; jj++)
        acc[ii] = fmaf(rb[ii*200 + j0 + jj], qv[jj], acc[ii]);
  }
#pragma unroll
  for (int ii = 0; ii < 8; ii++) {
    float v = acc[ii]*invrs[b*200 + i0 + ii];
    if (kv) wq[(b*200 + i0 + ii)*200 + tid] = v;
  }
}

// Numerator GEMMs via MFMA: mp in {0:d*qL, 1:d*wq, 2:wq^2, 3:d*q[argmax]};
// B = m2b16 rows [msel*50, +64). G stores are 32-lane contiguous (coalesced).
__global__ __launch_bounds__(256,4) void k_gemm2_mfma(
    const float* __restrict__ dR, const float* __restrict__ qR,
    const float* __restrict__ qL, const float* __restrict__ wq,
    const int* __restrict__ idx, const unsigned short* __restrict__ m2b16,
    float* __restrict__ G)
{
  int tid = threadIdx.x;
  int w = tid >> 6, lane = tid & 63;
  int n = lane & 31, h = lane >> 5;
  int mp = blockIdx.x / 50;
  int r0 = (blockIdx.x % 50) * 128;
  int row = r0 + w*32 + n;
  int bb = row / 200;
  int msel = (mp == 0) ? 0 : (mp == 3) ? 3 : 2;

  const float* s0 = dR + (size_t)row*200;
  const float* s1;
  if (mp == 0)      s1 = qL + (size_t)bb*200;
  else if (mp == 1) s1 = wq + (size_t)row*200;
  else if (mp == 2) { s0 = wq + (size_t)row*200; s1 = s0; }
  else              s1 = qR + (size_t)(bb*200 + idx[row])*200;

  bf16x8 afrag[13];
#pragma unroll
  for (int ks = 0; ks < 13; ks++) {
    int ko = ks*16 + h*8;
    bf16x8 af;
    if (ko < 200) {
      float4 a0 = *(const float4*)(s0 + ko);
      float4 a1 = *(const float4*)(s0 + ko + 4);
      float4 b0 = *(const float4*)(s1 + ko);
      float4 b1 = *(const float4*)(s1 + ko + 4);
      af[0] = (__bf16)(a0.x*b0.x); af[1] = (__bf16)(a0.y*b0.y);
      af[2] = (__bf16)(a0.z*b0.z); af[3] = (__bf16)(a0.w*b0.w);
      af[4] = (__bf16)(a1.x*b1.x); af[5] = (__bf16)(a1.y*b1.y);
      af[6] = (__bf16)(a1.z*b1.z); af[7] = (__bf16)(a1.w*b1.w);
    } else {
#pragma unroll
      for (int z = 0; z < 8; z++) af[z] = (__bf16)0.0f;
    }
    afrag[ks] = af;
  }

  for (int nt = 0; nt < 2; nt++) {
    f32x16 C;
#pragma unroll
    for (int z = 0; z < 16; z++) C[z] = 0.f;
    const unsigned short* bp = m2b16 + (size_t)(msel*50 + nt*32 + n)*208 + h*8;
#pragma unroll
    for (int ks = 0; ks < 13; ks++) {
      bf16x8 bf = *(const bf16x8*)(bp + ks*16);
      C = __builtin_amdgcn_mfma_f32_32x32x16_bf16(afrag[ks], bf, C, 0, 0, 0);
    }
    int cc = nt*32 + n;
    if (cc < 50) {
#pragma unroll
      for (int r = 0; r < 16; r++) {
        int mrow = (r & 3) + 8*(r >> 2) + 4*h;
        G[(size_t)(mp*6400 + r0 + w*32 + mrow)*50 + cc] = C[r];
      }
    }
  }
}

// maxpool via MFMA v3. block=(b,c), 4 waves, grid 1600.
// jh outer (2 q-stagings/block, iq pre-folded into B), t inner (2 i-tiles/wave,
// one afrag[13] live). Per (jh,t): 4 (resp. 3) j-tiles, 13-MFMA chains; vm/vs
// folded in-reg across jt, shfl-reduced over 32 j-lanes, flushed to LDS accum.
// C/D: col=lane&31 (j), row=(r&3)+8*(r>>2)+4*(lane>>5) (i).
// Output: compact pmax2/psum2[blockIdx][i] — fully coalesced block stores.
__global__ __launch_bounds__(256,2) void k_maxpool_mfma(
    const unsigned short* __restrict__ db16, const unsigned short* __restrict__ qb16,
    const float* __restrict__ m2all, const float* __restrict__ invmqn,
    float* __restrict__ pmax2, float* __restrict__ psum2)
{
  __shared__ __align__(16) unsigned short qsh[128*216];  // 55296 B
  __shared__ float accm[256], accs[256];                 // 2 KB
  int tid = threadIdx.x;
  int b = blockIdx.x / 50, c = blockIdx.x % 50;
  int w = tid >> 6, lane = tid & 63;
  int n = lane & 31, h = lane >> 5;
  const float* M2 = m2all + 10000 + c*200;   // maxpool_M^2, f32

  accm[tid] = NEG_HUGE;
  accs[tid] = 0.f;

  for (int jh = 0; jh < 2; jh++) {
    int nrows = jh ? 96 : 128;               // j 0-127, 128-223 (224+ skipped)
    int njt   = jh ? 3 : 4;
    __syncthreads();                         // accum-init / prior-jh reads done
    {
      const unsigned short* src = qb16 + (size_t)(b*256 + jh*128)*208;
      const float* iqb = invmqn + c*6400 + b*200;
      for (int s = tid; s < nrows*26; s += 256) {
        int r = s / 26, ch = s - r*26;
        int j = jh*128 + r;
        float iq = (j < 200) ? iqb[j] : 0.f;
        bf16x8 v = *(const bf16x8*)(src + (size_t)r*208 + ch*8);
        bf16x8 o;
#pragma unroll
        for (int z = 0; z < 8; z++) o[z] = (__bf16)((float)v[z] * iq);
        *(bf16x8*)(qsh + r*216 + ch*8) = o;
      }
    }
    __syncthreads();

    for (int t = 0; t < 2; t++) {
      int tt = w*2 + t;                      // i-tile 0..7
      bf16x8 afrag[13];
      const unsigned short* dbp = db16 + (size_t)(b*256 + tt*32 + n)*208;
#pragma unroll
      for (int ks = 0; ks < 13; ks++) {
        int ko = ks*16 + h*8;
        bf16x8 af;
        if (ko < 200) {
          bf16x8 d8 = *(const bf16x8*)(dbp + ko);
          float4 m0 = *(const float4*)(M2 + ko);
          float4 m1 = *(const float4*)(M2 + ko + 4);
          af[0] = (__bf16)((float)d8[0]*m0.x); af[1] = (__bf16)((float)d8[1]*m0.y);
          af[2] = (__bf16)((float)d8[2]*m0.z); af[3] = (__bf16)((float)d8[3]*m0.w);
          af[4] = (__bf16)((float)d8[4]*m1.x); af[5] = (__bf16)((float)d8[5]*m1.y);
          af[6] = (__bf16)((float)d8[6]*m1.z); af[7] = (__bf16)((float)d8[7]*m1.w);
        } else {
#pragma unroll
          for (int z = 0; z < 8; z++) af[z] = (__bf16)0.0f;
        }
        afrag[ks] = af;
      }

      float vm[16], vs[16];
#pragma unroll
      for (int r = 0; r < 16; r++) { vm[r] = NEG_HUGE; vs[r] = 0.f; }

      for (int jt = 0; jt < njt; jt++) {
        f32x16 C;
#pragma unroll
        for (int z = 0; z < 16; z++) C[z] = 0.f;
        const unsigned short* bptr = qsh + (jt*32 + n)*216 + h*8;
#pragma unroll
        for (int ks = 0; ks < 13; ks++) {
          bf16x8 bf = *(const bf16x8*)(bptr + ks*16);
          C = __builtin_amdgcn_mfma_f32_32x32x16_bf16(afrag[ks], bf, C, 0, 0, 0);
        }
        bool jv = (jh*128 + jt*32 + n) < 200;  // padded B' is 0 -> vs safe
#pragma unroll
        for (int r = 0; r < 16; r++) {
          vm[r] = fmaxf(vm[r], jv ? C[r] : NEG_HUGE);
          vs[r] += C[r];
        }
      }

      // reduce over 32 j-lanes, flush to LDS accum (disjoint i per (w,t,h))
#pragma unroll
      for (int r = 0; r < 16; r++) {
        float a = vm[r], s = vs[r];
#pragma unroll
        for (int m = 1; m <= 16; m <<= 1) {
          a = fmaxf(a, __shfl_xor(a, m));
          s += __shfl_xor(s, m);
        }
        vm[r] = a; vs[r] = s;
      }
      if (n == 0) {
#pragma unroll
        for (int r = 0; r < 16; r++) {
          int i = tt*32 + (r & 3) + 8*(r >> 2) + 4*h;
          accm[i] = fmaxf(accm[i], vm[r]);
          accs[i] += vs[r];
        }
      }
    }
  }
  __syncthreads();
  pmax2[(size_t)blockIdx.x*256 + tid] = accm[tid];
  psum2[(size_t)blockIdx.x*256 + tid] = accs[tid];
}

// Final assembly: out[row][0:250] written lane-coalesced.
__global__ void k_out(
    const float* __restrict__ G, const float* __restrict__ pmax2,
    const float* __restrict__ psum2, const float* __restrict__ invfpn,
    const float* __restrict__ invmpn, const float* __restrict__ invapn,
    const float* __restrict__ invxpn, const float* __restrict__ invfqn,
    const float* __restrict__ invxqn, const int* __restrict__ idx,
    float* __restrict__ out)
{
  int row = blockIdx.x;
  int l = threadIdx.x;
  if (l >= 250) return;
  int b = row / 200, i = row % 200;
  int seg = l / 50, c = l % 50;
  float o;
  if (seg == 0) {
    o = G[(size_t)(0*6400 + row)*50 + c] * invfpn[row*50 + c] * invfqn[b*50 + c];
  } else if (seg == 1) {
    o = pmax2[(size_t)(b*50 + c)*256 + i] * invmpn[row*50 + c];
  } else if (seg == 2) {
    o = psum2[(size_t)(b*50 + c)*256 + i] * invmpn[row*50 + c] * (1.f/200.f);
  } else if (seg == 3) {
    o = G[(size_t)(1*6400 + row)*50 + c] * invapn[row*50 + c]
        * rsqrtf(fmaxf(G[(size_t)(2*6400 + row)*50 + c], EPS));
  } else {
    int jid = idx[row];
    o = G[(size_t)(3*6400 + row)*50 + c] * invxpn[row*50 + c]
        * invxqn[(b*200 + jid)*50 + c];
  }
  out[(size_t)row*250 + l] = o;
}

extern "C" void kernel_launch(void* const* d_in, const int* in_sizes, int n_in,
                              void* d_out, int out_size, void* d_ws, size_t ws_size,
                              hipStream_t stream) {
  const float* qR = (const float*)d_in[0];
  const float* qL = (const float*)d_in[1];
  const float* qM = (const float*)d_in[2];
  const float* dR = (const float*)d_in[3];
  // d_in[4] = d_last: unused by the reference
  const float* dM = (const float*)d_in[5];
  const float* fullM = (const float*)d_in[6];
  const float* mpM   = (const float*)d_in[7];
  const float* attM  = (const float*)d_in[8];
  const float* xM    = (const float*)d_in[9];

  float* ws  = (float*)d_ws;
  float* out = (float*)d_out;

  float* m2all  = ws + OFF_M2ALL;
  unsigned short* m2b16 = (unsigned short*)(ws + OFF_M2B16);
  float* nsqT   = ws + OFF_NSQT;
  unsigned short* qb16 = (unsigned short*)(ws + OFF_QB16);
  unsigned short* db16 = (unsigned short*)(ws + OFF_DB16);
  float* invfpn = ws + OFF_INVFPN;
  float* invmpn = ws + OFF_INVMPN;
  float* invapn = ws + OFF_INVAPN;
  float* invxpn = ws + OFF_INVXPN;
  float* invmqn = ws + OFF_INVMQN;
  float* invxqn = ws + OFF_INVXQN;
  float* invfqn = ws + OFF_INVFQN;
  float* invdn  = ws + OFF_INVDN;
  float* invqn  = ws + OFF_INVQN;
  float* rel    = ws + OFF_REL;
  float* G      = ws + OFF_G;        // aliases rel (rel dead after k_wq)
  float* invrs  = ws + OFF_INVRS;
  int*   idxp   = (int*)(ws + OFF_IDX);
  float* wqp    = ws + OFF_WQ;
  float* pmax2  = ws + OFF_PMAX2;
  float* psum2  = ws + OFF_PSUM2;

  k_m2<<<182, 256, 0, stream>>>(fullM, mpM, attM, xM, m2all, m2b16);
  k_pnorm<<<3200, 256, 0, stream>>>(dR, qR, invdn, invqn);
  k_gemm1_mfma<<<101, 256, 0, stream>>>(dR, qR, qL, m2b16, nsqT);
  k_inv<<<dim3(200, 51), 256, 0, stream>>>(nsqT, invfpn, invmpn, invapn, invxpn,
                                           invmqn, invxqn, invfqn);
  k_cvt16<<<6656, 256, 0, stream>>>(qR, dR, qb16, db16);   // after k_inv (aliases nsqT)
  k_rel<<<800, 256, 0, stream>>>(dR, qR, qM, dM, invdn, invqn, rel, invrs, idxp);
  k_wq<<<800, 256, 0, stream>>>(qR, rel, invrs, wqp);
  k_gemm2_mfma<<<200, 256, 0, stream>>>(dR, qR, qL, wqp, idxp, m2b16, G);
  k_maxpool_mfma<<<1600, 256, 0, stream>>>(db16, qb16, m2all, invmqn, pmax2, psum2);
  k_out<<<6400, 256, 0, stream>>>(G, pmax2, psum2, invfpn, invmpn, invapn,
                                  invxpn, invfqn, invxqn, idxp, out);
}

// Round 6
// 324.480 us; speedup vs baseline: 4.8425x; 1.1603x over previous
//
#include <hip/hip_runtime.h>
#include <math.h>

// MultiPerspectiveMatch on MI355X — round 6.
// vs round 5 (k_maxpool 134us, MfmaUtil 11% = pure-MFMA floor ~15us + 89% idle):
//  - k_maxpool_mfma v4:
//      * A = RAW db16 fragments, direct global loads — the r5 afrag build
//        (2jh x 2t x 13ks x ~24 VALU = ~1250 instr/thread) is gone.
//      * M2_c moved into B staging (qsh = bf16(q * iq * M2_c)); padded j/k
//        contribute exact zeros.
//      * 512-thread blocks, one i-tile per wave (8 waves) -> 4 waves/SIMD
//        (was 2): hides the serially-dependent 13-MFMA chain latency.
//      * vm/vs in regs across both jh stagings; lane n==0 writes pmax2/psum2
//        directly (LDS accum gone).
// Everything else unchanged from round 5.

#define EPS 1e-6f
#define NEG_HUGE -3.4e38f

typedef __bf16 bf16x8 __attribute__((ext_vector_type(8)));
typedef float f32x16 __attribute__((ext_vector_type(16)));

// ---- ws offsets (floats) ----
constexpr size_t OFF_M2ALL = 0;            // f32 [4][50][200] = 40,000
constexpr size_t OFF_M2B16 = 40000;        // bf16 [224][208] = 23,296 fl
constexpr size_t OFF_NSQT  = 63296;        // f32 [12928][224] (dead after k_inv)
constexpr size_t OFF_QB16  = 63296;        // bf16 [32][256][208] (reuses NSQT)
constexpr size_t OFF_DB16  = 915264;       // bf16 [32][256][208]
constexpr size_t OFF_INVFPN= 2959168;      // [6400][50]
constexpr size_t OFF_INVMPN= 3279168;
constexpr size_t OFF_INVAPN= 3599168;
constexpr size_t OFF_INVXPN= 3919168;
constexpr size_t OFF_INVMQN= 4239168;      // [c(50)][6400]
constexpr size_t OFF_INVXQN= 4559168;      // [6400][50]
constexpr size_t OFF_INVFQN= 4879168;      // [32][50]
constexpr size_t OFF_INVDN = 4880768;      // [6400]
constexpr size_t OFF_INVQN = 4887168;      // [6400]
constexpr size_t OFF_REL   = 4893568;      // [32][200][200]  (dead after k_wq)
constexpr size_t OFF_G     = 4893568;      //   [4][6400][50] reuses REL
constexpr size_t OFF_INVRS = 6173568;
constexpr size_t OFF_IDX   = 6179968;      // int
constexpr size_t OFF_WQ    = 6186368;      // [32][200][200]
constexpr size_t OFF_PMAX2 = 7466368;      // [1600][256]
constexpr size_t OFF_PSUM2 = 7875968;      // [1600][256]
// end = 8,285,568 floats = 33.1 MB

__global__ void k_m2(const float* __restrict__ fM, const float* __restrict__ mM,
                     const float* __restrict__ aM, const float* __restrict__ xM,
                     float* __restrict__ m2all, unsigned short* __restrict__ m2b16)
{
  int i = blockIdx.x*256 + threadIdx.x;
  if (i < 40000) {
    int m = i / 10000, r = i % 10000;
    const float* s = (m==0)?fM:(m==1)?mM:(m==2)?aM:xM;
    float v = s[r];
    m2all[i] = v*v;
  }
  if (i < 224*208) {
    int row = i / 208, k = i % 208;
    unsigned short o = 0;
    if (row < 200 && k < 200) {
      int m = row / 50, c = row % 50;
      const float* s = (m==0)?fM:(m==1)?mM:(m==2)?aM:xM;
      float v = s[c*200 + k];
      __bf16 h = (__bf16)(v*v);
      o = *(unsigned short*)&h;
    }
    m2b16[i] = o;
  }
}

// 4 rows per block (one per wave)
__global__ __launch_bounds__(256) void k_pnorm(
    const float* __restrict__ dR, const float* __restrict__ qR,
    float* __restrict__ invdn, float* __restrict__ invqn)
{
  int row = blockIdx.x*4 + (threadIdx.x >> 6);
  int l = threadIdx.x & 63;
  const float* src = (row < 6400) ? dR + (size_t)row*200 : qR + (size_t)(row-6400)*200;
  float s = 0.f;
  for (int k = l; k < 200; k += 64) { float v = src[k]; s = fmaf(v, v, s); }
#pragma unroll
  for (int m = 32; m; m >>= 1) s += __shfl_xor(s, m);
  if (l == 0) {
    float r = rsqrtf(fmaxf(s, EPS));
    if (row < 6400) invdn[row] = r; else invqn[row-6400] = r;
  }
}

// nsq GEMM via MFMA: rows = [d|q|q_last] squared (bf16), B = m2b16 (N=224).
__global__ __launch_bounds__(256,4) void k_gemm1_mfma(
    const float* __restrict__ dR, const float* __restrict__ qR,
    const float* __restrict__ qL, const unsigned short* __restrict__ m2b16,
    float* __restrict__ nsqT)
{
  int tid = threadIdx.x;
  int w = tid >> 6, lane = tid & 63;
  int n = lane & 31, h = lane >> 5;
  int r0 = blockIdx.x * 128;
  int row = r0 + w*32 + n;

  const float* src = dR; bool valid = true;
  if (row < 6400)        src = dR + (size_t)row*200;
  else if (row < 12800)  src = qR + (size_t)(row-6400)*200;
  else if (row < 12832)  src = qL + (size_t)(row-12800)*200;
  else valid = false;

  bf16x8 afrag[13];
#pragma unroll
  for (int ks = 0; ks < 13; ks++) {
    int ko = ks*16 + h*8;
    bf16x8 af;
    if (valid && ko < 200) {
      float4 a0 = *(const float4*)(src + ko);
      float4 a1 = *(const float4*)(src + ko + 4);
      af[0] = (__bf16)(a0.x*a0.x); af[1] = (__bf16)(a0.y*a0.y);
      af[2] = (__bf16)(a0.z*a0.z); af[3] = (__bf16)(a0.w*a0.w);
      af[4] = (__bf16)(a1.x*a1.x); af[5] = (__bf16)(a1.y*a1.y);
      af[6] = (__bf16)(a1.z*a1.z); af[7] = (__bf16)(a1.w*a1.w);
    } else {
#pragma unroll
      for (int z = 0; z < 8; z++) af[z] = (__bf16)0.0f;
    }
    afrag[ks] = af;
  }

  for (int nt = 0; nt < 7; nt++) {
    f32x16 C;
#pragma unroll
    for (int z = 0; z < 16; z++) C[z] = 0.f;
    const unsigned short* bp = m2b16 + (size_t)(nt*32 + n)*208 + h*8;
#pragma unroll
    for (int ks = 0; ks < 13; ks++) {
      bf16x8 bf = *(const bf16x8*)(bp + ks*16);
      C = __builtin_amdgcn_mfma_f32_32x32x16_bf16(afrag[ks], bf, C, 0, 0, 0);
    }
#pragma unroll
    for (int r = 0; r < 16; r++) {
      int mrow = (r & 3) + 8*(r >> 2) + 4*h;
      nsqT[(size_t)(r0 + w*32 + mrow)*224 + nt*32 + n] = C[r];
    }
  }
}

__global__ void k_inv(const float* __restrict__ nsqT,
    float* __restrict__ invfpn, float* __restrict__ invmpn,
    float* __restrict__ invapn, float* __restrict__ invxpn,
    float* __restrict__ invmqn, float* __restrict__ invxqn,
    float* __restrict__ invfqn)
{
  int nIdx = blockIdx.x;                    // 0..199 = m*50+c
  int row = blockIdx.y*256 + threadIdx.x;
  if (row >= 12832) return;
  int m = nIdx / 50, c = nIdx % 50;
  float v = rsqrtf(fmaxf(nsqT[(size_t)row*224 + nIdx], EPS));
  if (row < 6400) {
    if (m == 0)      invfpn[row*50 + c] = v;
    else if (m == 1) invmpn[row*50 + c] = v;
    else if (m == 2) invapn[row*50 + c] = v;
    else             invxpn[row*50 + c] = v;
  } else if (row < 12800) {
    int r2 = row - 6400;
    if (m == 1)      invmqn[c*6400 + r2] = v;
    else if (m == 3) invxqn[r2*50 + c] = v;
  } else {
    if (m == 0)      invfqn[(row-12800)*50 + c] = v;
  }
}

// q and d -> padded bf16 [32][256][208]. MUST run after k_inv (qb16 aliases nsqT).
__global__ void k_cvt16(const float* __restrict__ qR, const float* __restrict__ dR,
                        unsigned short* __restrict__ qb16, unsigned short* __restrict__ db16)
{
  int idx = blockIdx.x*256 + threadIdx.x;   // 2 * 32*256*52
  const int half = 32*256*52;
  if (idx >= 2*half) return;
  int sel = idx >= half;
  int id = sel ? idx - half : idx;
  int k4 = (id % 52)*4;
  int j  = (id / 52) % 256;
  int b  = id / (52*256);
  const float* src = sel ? dR : qR;
  unsigned short* dst = sel ? db16 : qb16;
  ushort4 o = {0,0,0,0};
  if (j < 200 && k4 < 200) {
    float4 v = *(const float4*)(src + (size_t)(b*200 + j)*200 + k4);
    __bf16 h0=(__bf16)v.x, h1=(__bf16)v.y, h2=(__bf16)v.z, h3=(__bf16)v.w;
    o.x = *(unsigned short*)&h0; o.y = *(unsigned short*)&h1;
    o.z = *(unsigned short*)&h2; o.w = *(unsigned short*)&h3;
  }
  *(ushort4*)(dst + (size_t)(b*256 + j)*208 + k4) = o;
}

// block = (b, 8 i's); lane=j. d operands wave-uniform -> s_load. fp32 exact
// (rel feeds argmax — bf16 would flip near-tied argmaxes; keep full precision).
__global__ __launch_bounds__(256) void k_rel(
    const float* __restrict__ dR, const float* __restrict__ qR,
    const float* __restrict__ qMask, const float* __restrict__ dMask,
    const float* __restrict__ invdn, const float* __restrict__ invqn,
    float* __restrict__ rel, float* __restrict__ invrs, int* __restrict__ idxout)
{
  __shared__ float qsh[64*201];
  __shared__ float redv[4][8][2];
  __shared__ int   redi[4][8];
  int tid = threadIdx.x;
  int b  = blockIdx.x / 25;
  int i0 = (blockIdx.x % 25) * 8;
  int j = tid, jr = min(j, 199);
  bool jv = j < 200;
  const float* qb = qR + b*40000;
  const float* db = dR + (b*200 + i0)*200;
  float acc[8];
#pragma unroll
  for (int ii = 0; ii < 8; ii++) acc[ii] = 0.f;

  for (int p = 0; p < 4; p++) {
    int kp = p*64;
    __syncthreads();
    if (p < 3) {
      for (int s = tid; s < 200*64; s += 256) { int kk = s & 63, jj = s >> 6; qsh[kk*201 + jj] = qb[jj*200 + kp + kk]; }
    } else {
      for (int s = tid; s < 200*8; s += 256) { int kk = s & 7, jj = s >> 3; qsh[kk*201 + jj] = qb[jj*200 + kp + kk]; }
    }
    __syncthreads();
    int nk = (p < 3) ? 64 : 8;
    for (int k4 = 0; k4 < nk; k4 += 4) {
      float qv[4];
#pragma unroll
      for (int kk = 0; kk < 4; kk++) qv[kk] = qsh[(k4+kk)*201 + jr];
#pragma unroll
      for (int ii = 0; ii < 8; ii++)
#pragma unroll
        for (int kk = 0; kk < 4; kk++)
          acc[ii] = fmaf(db[ii*200 + kp + k4 + kk], qv[kk], acc[ii]);
    }
  }

  float iqn = invqn[b*200 + jr];
  float qm  = qMask[b*200 + jr];
  int w = tid >> 6, l = tid & 63;
  float rv[8];
#pragma unroll
  for (int ii = 0; ii < 8; ii++) {
    float idn = invdn[b*200 + i0 + ii];
    float dm  = dMask[b*200 + i0 + ii];
    float r = acc[ii]*iqn*idn*qm*dm;
    rv[ii] = r;
    if (jv) rel[(b*200 + i0 + ii)*200 + j] = r;   // coalesced
  }
#pragma unroll
  for (int ii = 0; ii < 8; ii++) {
    float vm = jv ? rv[ii] : NEG_HUGE;
    float vs = jv ? rv[ii] : 0.f;
    int bj = jr;
#pragma unroll
    for (int m = 32; m; m >>= 1) {
      float ov = __shfl_xor(vm, m);
      int   oj = __shfl_xor(bj, m);
      vs += __shfl_xor(vs, m);
      if (ov > vm || (ov == vm && oj < bj)) { vm = ov; bj = oj; }  // first-max wins
    }
    if (l == 0) { redv[w][ii][0] = vm; redv[w][ii][1] = vs; redi[w][ii] = bj; }
  }
  __syncthreads();
  if (tid < 8) {
    float bv = redv[0][tid][0], ss = redv[0][tid][1]; int bj = redi[0][tid];
    for (int w2 = 1; w2 < 4; w2++) {
      ss += redv[w2][tid][1];
      float wv = redv[w2][tid][0]; int wj = redi[w2][tid];
      if (wv > bv || (wv == bv && wj < bj)) { bv = wv; bj = wj; }
    }
    invrs[b*200 + i0 + tid] = 1.f/(ss + EPS);
    idxout[b*200 + i0 + tid] = bj;
  }
}

// block = (b, 8 i's); lane=k. rel operands wave-uniform -> s_load.
__global__ __launch_bounds__(256) void k_wq(
    const float* __restrict__ qR, const float* __restrict__ rel,
    const float* __restrict__ invrs, float* __restrict__ wq)
{
  int tid = threadIdx.x;
  int b = blockIdx.x / 25; int i0 = (blockIdx.x % 25) * 8;
  int kl = min(tid, 199); bool kv = tid < 200;
  const float* qb = qR + b*40000;
  const float* rb = rel + (b*200 + i0)*200;
  float acc[8];
#pragma unroll
  for (int ii = 0; ii < 8; ii++) acc[ii] = 0.f;
  for (int j0 = 0; j0 < 200; j0 += 8) {
    float qv[8];
#pragma unroll
    for (int jj = 0; jj < 8; jj++) qv[jj] = qb[(j0+jj)*200 + kl];
#pragma unroll
    for (int ii = 0; ii < 8; ii++)
#pragma unroll
      for (int jj = 0; jj < 8; jj++)
        acc[ii] = fmaf(rb[ii*200 + j0 + jj], qv[jj], acc[ii]);
  }
#pragma unroll
  for (int ii = 0; ii < 8; ii++) {
    float v = acc[ii]*invrs[b*200 + i0 + ii];
    if (kv) wq[(b*200 + i0 + ii)*200 + tid] = v;
  }
}

// Numerator GEMMs via MFMA: mp in {0:d*qL, 1:d*wq, 2:wq^2, 3:d*q[argmax]};
// B = m2b16 rows [msel*50, +64). G stores are 32-lane contiguous (coalesced).
__global__ __launch_bounds__(256,4) void k_gemm2_mfma(
    const float* __restrict__ dR, const float* __restrict__ qR,
    const float* __restrict__ qL, const float* __restrict__ wq,
    const int* __restrict__ idx, const unsigned short* __restrict__ m2b16,
    float* __restrict__ G)
{
  int tid = threadIdx.x;
  int w = tid >> 6, lane = tid & 63;
  int n = lane & 31, h = lane >> 5;
  int mp = blockIdx.x / 50;
  int r0 = (blockIdx.x % 50) * 128;
  int row = r0 + w*32 + n;
  int bb = row / 200;
  int msel = (mp == 0) ? 0 : (mp == 3) ? 3 : 2;

  const float* s0 = dR + (size_t)row*200;
  const float* s1;
  if (mp == 0)      s1 = qL + (size_t)bb*200;
  else if (mp == 1) s1 = wq + (size_t)row*200;
  else if (mp == 2) { s0 = wq + (size_t)row*200; s1 = s0; }
  else              s1 = qR + (size_t)(bb*200 + idx[row])*200;

  bf16x8 afrag[13];
#pragma unroll
  for (int ks = 0; ks < 13; ks++) {
    int ko = ks*16 + h*8;
    bf16x8 af;
    if (ko < 200) {
      float4 a0 = *(const float4*)(s0 + ko);
      float4 a1 = *(const float4*)(s0 + ko + 4);
      float4 b0 = *(const float4*)(s1 + ko);
      float4 b1 = *(const float4*)(s1 + ko + 4);
      af[0] = (__bf16)(a0.x*b0.x); af[1] = (__bf16)(a0.y*b0.y);
      af[2] = (__bf16)(a0.z*b0.z); af[3] = (__bf16)(a0.w*b0.w);
      af[4] = (__bf16)(a1.x*b1.x); af[5] = (__bf16)(a1.y*b1.y);
      af[6] = (__bf16)(a1.z*b1.z); af[7] = (__bf16)(a1.w*b1.w);
    } else {
#pragma unroll
      for (int z = 0; z < 8; z++) af[z] = (__bf16)0.0f;
    }
    afrag[ks] = af;
  }

  for (int nt = 0; nt < 2; nt++) {
    f32x16 C;
#pragma unroll
    for (int z = 0; z < 16; z++) C[z] = 0.f;
    const unsigned short* bp = m2b16 + (size_t)(msel*50 + nt*32 + n)*208 + h*8;
#pragma unroll
    for (int ks = 0; ks < 13; ks++) {
      bf16x8 bf = *(const bf16x8*)(bp + ks*16);
      C = __builtin_amdgcn_mfma_f32_32x32x16_bf16(afrag[ks], bf, C, 0, 0, 0);
    }
    int cc = nt*32 + n;
    if (cc < 50) {
#pragma unroll
      for (int r = 0; r < 16; r++) {
        int mrow = (r & 3) + 8*(r >> 2) + 4*h;
        G[(size_t)(mp*6400 + r0 + w*32 + mrow)*50 + cc] = C[r];
      }
    }
  }
}

// maxpool via MFMA v4. block=(b,c), 8 waves (512 thr), grid 1600.
// Wave w owns i-tile w (rows w*32..+31). A = RAW db16 direct from global
// (d is ~106KB/batch -> L2-resident; no VALU build). B staged per jh with
// M2_c and invmqn folded in: qsh[j][k] = bf16(q[j,k]*iq[j]*M2[k]); padded
// j/k rows are exact zeros. vm/vs persist in regs across jh (32 VGPR only).
// C/D: col=lane&31 (j), row=(r&3)+8*(r>>2)+4*(lane>>5) (i).
__global__ __launch_bounds__(512,4) void k_maxpool_mfma(
    const unsigned short* __restrict__ db16, const unsigned short* __restrict__ qb16,
    const float* __restrict__ m2all, const float* __restrict__ invmqn,
    float* __restrict__ pmax2, float* __restrict__ psum2)
{
  __shared__ __align__(16) unsigned short qsh[128*216];  // 55296 B -> 2 blk/CU
  int tid = threadIdx.x;
  int b = blockIdx.x / 50, c = blockIdx.x % 50;
  int w = tid >> 6, lane = tid & 63;       // w = i-tile 0..7
  int n = lane & 31, h = lane >> 5;
  const float* M2 = m2all + 10000 + c*200; // maxpool_M^2, f32
  const unsigned short* dbp = db16 + (size_t)(b*256 + w*32 + n)*208 + h*8;

  float vm[16], vs[16];
#pragma unroll
  for (int r = 0; r < 16; r++) { vm[r] = NEG_HUGE; vs[r] = 0.f; }

  for (int jh = 0; jh < 2; jh++) {
    int nrows = jh ? 96 : 128;             // j 0-127, 128-223 (224+ skipped)
    int njt   = jh ? 3 : 4;
    __syncthreads();                       // prior-jh qsh reads done
    {
      const unsigned short* src = qb16 + (size_t)(b*256 + jh*128)*208;
      const float* iqb = invmqn + c*6400 + b*200;
      for (int s = tid; s < nrows*26; s += 512) {
        int r = s / 26, ch = s - r*26;
        int j = jh*128 + r;
        float iq = (j < 200) ? iqb[j] : 0.f;
        int k0 = ch*8;
        bf16x8 v = *(const bf16x8*)(src + (size_t)r*208 + k0);
        float4 m0 = *(const float4*)(M2 + k0);       // k0=200 reads next row's
        float4 m1 = *(const float4*)(M2 + k0 + 4);   // data: finite, x0 = 0. ok
        bf16x8 o;
        o[0] = (__bf16)((float)v[0]*iq*m0.x); o[1] = (__bf16)((float)v[1]*iq*m0.y);
        o[2] = (__bf16)((float)v[2]*iq*m0.z); o[3] = (__bf16)((float)v[3]*iq*m0.w);
        o[4] = (__bf16)((float)v[4]*iq*m1.x); o[5] = (__bf16)((float)v[5]*iq*m1.y);
        o[6] = (__bf16)((float)v[6]*iq*m1.z); o[7] = (__bf16)((float)v[7]*iq*m1.w);
        *(bf16x8*)(qsh + r*216 + k0) = o;
      }
    }
    __syncthreads();

    // raw A fragments (reloaded per jh — L2 hit, no regs across the barrier)
    bf16x8 afrag[13];
#pragma unroll
    for (int ks = 0; ks < 13; ks++) afrag[ks] = *(const bf16x8*)(dbp + ks*16);

    for (int jt = 0; jt < njt; jt++) {
      f32x16 C;
#pragma unroll
      for (int z = 0; z < 16; z++) C[z] = 0.f;
      const unsigned short* bptr = qsh + (jt*32 + n)*216 + h*8;
#pragma unroll
      for (int ks = 0; ks < 13; ks++) {
        bf16x8 bf = *(const bf16x8*)(bptr + ks*16);
        C = __builtin_amdgcn_mfma_f32_32x32x16_bf16(afrag[ks], bf, C, 0, 0, 0);
      }
      bool jv = (jh*128 + jt*32 + n) < 200;  // padded B cols are 0 -> vs safe
#pragma unroll
      for (int r = 0; r < 16; r++) {
        vm[r] = fmaxf(vm[r], jv ? C[r] : NEG_HUGE);
        vs[r] += C[r];
      }
    }
  }

  // reduce over the 32 j-lanes (xor masks 1..16 stay within n; h is disjoint i)
#pragma unroll
  for (int r = 0; r < 16; r++) {
    float a = vm[r], s = vs[r];
#pragma unroll
    for (int m = 1; m <= 16; m <<= 1) {
      a = fmaxf(a, __shfl_xor(a, m));
      s += __shfl_xor(s, m);
    }
    vm[r] = a; vs[r] = s;
  }
  if (n == 0) {
#pragma unroll
    for (int r = 0; r < 16; r++) {
      int i = w*32 + (r & 3) + 8*(r >> 2) + 4*h;
      pmax2[(size_t)blockIdx.x*256 + i] = vm[r];
      psum2[(size_t)blockIdx.x*256 + i] = vs[r];
    }
  }
}

// Final assembly: out[row][0:250] written lane-coalesced.
__global__ void k_out(
    const float* __restrict__ G, const float* __restrict__ pmax2,
    const float* __restrict__ psum2, const float* __restrict__ invfpn,
    const float* __restrict__ invmpn, const float* __restrict__ invapn,
    const float* __restrict__ invxpn, const float* __restrict__ invfqn,
    const float* __restrict__ invxqn, const int* __restrict__ idx,
    float* __restrict__ out)
{
  int row = blockIdx.x;
  int l = threadIdx.x;
  if (l >= 250) return;
  int b = row / 200, i = row % 200;
  int seg = l / 50, c = l % 50;
  float o;
  if (seg == 0) {
    o = G[(size_t)(0*6400 + row)*50 + c] * invfpn[row*50 + c] * invfqn[b*50 + c];
  } else if (seg == 1) {
    o = pmax2[(size_t)(b*50 + c)*256 + i] * invmpn[row*50 + c];
  } else if (seg == 2) {
    o = psum2[(size_t)(b*50 + c)*256 + i] * invmpn[row*50 + c] * (1.f/200.f);
  } else if (seg == 3) {
    o = G[(size_t)(1*6400 + row)*50 + c] * invapn[row*50 + c]
        * rsqrtf(fmaxf(G[(size_t)(2*6400 + row)*50 + c], EPS));
  } else {
    int jid = idx[row];
    o = G[(size_t)(3*6400 + row)*50 + c] * invxpn[row*50 + c]
        * invxqn[(b*200 + jid)*50 + c];
  }
  out[(size_t)row*250 + l] = o;
}

extern "C" void kernel_launch(void* const* d_in, const int* in_sizes, int n_in,
                              void* d_out, int out_size, void* d_ws, size_t ws_size,
                              hipStream_t stream) {
  const float* qR = (const float*)d_in[0];
  const float* qL = (const float*)d_in[1];
  const float* qM = (const float*)d_in[2];
  const float* dR = (const float*)d_in[3];
  // d_in[4] = d_last: unused by the reference
  const float* dM = (const float*)d_in[5];
  const float* fullM = (const float*)d_in[6];
  const float* mpM   = (const float*)d_in[7];
  const float* attM  = (const float*)d_in[8];
  const float* xM    = (const float*)d_in[9];

  float* ws  = (float*)d_ws;
  float* out = (float*)d_out;

  float* m2all  = ws + OFF_M2ALL;
  unsigned short* m2b16 = (unsigned short*)(ws + OFF_M2B16);
  float* nsqT   = ws + OFF_NSQT;
  unsigned short* qb16 = (unsigned short*)(ws + OFF_QB16);
  unsigned short* db16 = (unsigned short*)(ws + OFF_DB16);
  float* invfpn = ws + OFF_INVFPN;
  float* invmpn = ws + OFF_INVMPN;
  float* invapn = ws + OFF_INVAPN;
  float* invxpn = ws + OFF_INVXPN;
  float* invmqn = ws + OFF_INVMQN;
  float* invxqn = ws + OFF_INVXQN;
  float* invfqn = ws + OFF_INVFQN;
  float* invdn  = ws + OFF_INVDN;
  float* invqn  = ws + OFF_INVQN;
  float* rel    = ws + OFF_REL;
  float* G      = ws + OFF_G;        // aliases rel (rel dead after k_wq)
  float* invrs  = ws + OFF_INVRS;
  int*   idxp   = (int*)(ws + OFF_IDX);
  float* wqp    = ws + OFF_WQ;
  float* pmax2  = ws + OFF_PMAX2;
  float* psum2  = ws + OFF_PSUM2;

  k_m2<<<182, 256, 0, stream>>>(fullM, mpM, attM, xM, m2all, m2b16);
  k_pnorm<<<3200, 256, 0, stream>>>(dR, qR, invdn, invqn);
  k_gemm1_mfma<<<101, 256, 0, stream>>>(dR, qR, qL, m2b16, nsqT);
  k_inv<<<dim3(200, 51), 256, 0, stream>>>(nsqT, invfpn, invmpn, invapn, invxpn,
                                           invmqn, invxqn, invfqn);
  k_cvt16<<<6656, 256, 0, stream>>>(qR, dR, qb16, db16);   // after k_inv (aliases nsqT)
  k_rel<<<800, 256, 0, stream>>>(dR, qR, qM, dM, invdn, invqn, rel, invrs, idxp);
  k_wq<<<800, 256, 0, stream>>>(qR, rel, invrs, wqp);
  k_gemm2_mfma<<<200, 256, 0, stream>>>(dR, qR, qL, wqp, idxp, m2b16, G);
  k_maxpool_mfma<<<1600, 512, 0, stream>>>(db16, qb16, m2all, invmqn, pmax2, psum2);
  k_out<<<6400, 256, 0, stream>>>(G, pmax2, psum2, invfpn, invmpn, invapn,
                                  invxpn, invfqn, invxqn, idxp, out);
}

// Round 8
// 288.046 us; speedup vs baseline: 5.4550x; 1.1265x over previous
//
#include <hip/hip_runtime.h>
#include <math.h>

// MultiPerspectiveMatch on MI355X — round 8.
// = round 7 with the workspace layout bug fixed: qb16/db16 are 851,968 floats
// each (32*256*208 shorts / 2), not 425,984. r7 had db16 overlapping qb16's
// upper half AND invfpn/invmpn overlapping db16's tail -> corrupted A operands
// -> NaN. Design unchanged from r7:
//  - k_maxpool v5: qsh stride 232 shorts (116 words -> conflict-free b128),
//    dual interleaved C chains (2x MFMA ILP)
//  - 6 kernels: k_prep = m2+pnorm+cvt16; k_inv fused into k_gemm1 epilogue;
//    k_rel+k_wq fused (rel stays in LDS); gemm1 2807 waves; gemm2 1600 waves.

#define EPS 1e-6f
#define NEG_HUGE -3.4e38f

typedef __bf16 bf16x8 __attribute__((ext_vector_type(8)));
typedef float f32x16 __attribute__((ext_vector_type(16)));

// ---- ws offsets (floats) ----
constexpr size_t OFF_M2ALL = 0;            // f32 [4][50][200] = 40,000
constexpr size_t OFF_M2B16 = 40000;        // bf16 [224][208] = 23,296 fl
constexpr size_t OFF_QB16  = 63296;        // bf16 [32][256][208] = 851,968 fl
constexpr size_t OFF_DB16  = 915264;       // bf16 [32][256][208] = 851,968 fl
constexpr size_t OFF_INVFPN= 1767232;      // [6400][50]
constexpr size_t OFF_INVMPN= 2087232;
constexpr size_t OFF_INVAPN= 2407232;
constexpr size_t OFF_INVXPN= 2727232;
constexpr size_t OFF_INVMQN= 3047232;      // [c(50)][6400]
constexpr size_t OFF_INVXQN= 3367232;      // [6400][50]
constexpr size_t OFF_INVFQN= 3687232;      // [32][50]
constexpr size_t OFF_INVDN = 3688832;      // [6400]
constexpr size_t OFF_INVQN = 3695232;      // [6400]
constexpr size_t OFF_IDX   = 3701632;      // int [6400]
constexpr size_t OFF_WQ    = 3708032;      // [32][200][200] = 1,280,000
constexpr size_t OFF_G     = 4988032;      // [4][6400][50] = 1,280,000
constexpr size_t OFF_PMAX2 = 6268032;      // [1600][256]
constexpr size_t OFF_PSUM2 = 6677632;      // [1600][256]
// end = 7,087,232 floats = 28.3 MB

// Fused prep: blocks [0,4096): d/q rows -> bf16 padded [32][256][208] + plain
// norms (one row per wave). Blocks [4096, 4278): M^2 tables (f32 + bf16).
__global__ __launch_bounds__(256) void k_prep(
    const float* __restrict__ qR, const float* __restrict__ dR,
    const float* __restrict__ fM, const float* __restrict__ mM,
    const float* __restrict__ aM, const float* __restrict__ xM,
    unsigned short* __restrict__ qb16, unsigned short* __restrict__ db16,
    float* __restrict__ invdn, float* __restrict__ invqn,
    float* __restrict__ m2all, unsigned short* __restrict__ m2b16)
{
  int blk = blockIdx.x;
  int tid = threadIdx.x;
  if (blk < 4096) {
    int task = blk*4 + (tid >> 6);        // 0..16383
    int l = tid & 63;
    int isQ = task >= 8192;
    int r = isQ ? task - 8192 : task;     // b*256 + j
    int b = r >> 8, j = r & 255;
    unsigned short* dst = (isQ ? qb16 : db16) + (size_t)r*208;
    if (j < 200) {
      const float* src = (isQ ? qR : dR) + (size_t)(b*200 + j)*200;
      float4 v = {0.f,0.f,0.f,0.f};
      if (l < 50) v = *(const float4*)(src + l*4);
      float s = fmaf(v.x,v.x, fmaf(v.y,v.y, fmaf(v.z,v.z, v.w*v.w)));
#pragma unroll
      for (int m = 32; m; m >>= 1) s += __shfl_xor(s, m);
      if (l == 0) {
        float rr = rsqrtf(fmaxf(s, EPS));
        if (isQ) invqn[b*200 + j] = rr; else invdn[b*200 + j] = rr;
      }
      if (l < 52) {
        ushort4 o = {0,0,0,0};
        if (l < 50) {
          __bf16 h0=(__bf16)v.x, h1=(__bf16)v.y, h2=(__bf16)v.z, h3=(__bf16)v.w;
          o.x = *(unsigned short*)&h0; o.y = *(unsigned short*)&h1;
          o.z = *(unsigned short*)&h2; o.w = *(unsigned short*)&h3;
        }
        *(ushort4*)(dst + l*4) = o;
      }
    } else {
      if (l < 52) { ushort4 z = {0,0,0,0}; *(ushort4*)(dst + l*4) = z; }
    }
  } else {
    int i = (blk - 4096)*256 + tid;
    if (i < 40000) {
      int m = i / 10000, r = i % 10000;
      const float* s = (m==0)?fM:(m==1)?mM:(m==2)?aM:xM;
      float v = s[r];
      m2all[i] = v*v;
    }
    if (i < 224*208) {
      int row = i / 208, k = i % 208;
      unsigned short o = 0;
      if (row < 200 && k < 200) {
        int m = row / 50, c = row % 50;
        const float* s = (m==0)?fM:(m==1)?mM:(m==2)?aM:xM;
        float v = s[c*200 + k];
        __bf16 h = (__bf16)(v*v);
        o = *(unsigned short*)&h;
      }
      m2b16[i] = o;
    }
  }
}

// nsq GEMM + fused rsqrt/scatter (old k_inv). One wave per (row-tile, nt):
// 2807 tasks. rows = [d(6400)|q(6400)|q_last(32)] squared (bf16 on the fly),
// B = m2b16 (N=224). C/D: col=lane&31 (c'), row=(r&3)+8*(r>>2)+4*(lane>>5).
__global__ __launch_bounds__(256,4) void k_gemm1_mfma(
    const float* __restrict__ dR, const float* __restrict__ qR,
    const float* __restrict__ qL, const unsigned short* __restrict__ m2b16,
    float* __restrict__ invfpn, float* __restrict__ invmpn,
    float* __restrict__ invapn, float* __restrict__ invxpn,
    float* __restrict__ invmqn, float* __restrict__ invxqn,
    float* __restrict__ invfqn)
{
  int tid = threadIdx.x;
  int w = tid >> 6, lane = tid & 63;
  int n = lane & 31, h = lane >> 5;
  int task = blockIdx.x*4 + w;
  if (task >= 2807) return;               // wave-uniform
  int rt = task / 7, nt = task % 7;       // rt in [0,401), 401*32 = 12832
  int row = rt*32 + n;

  const float* src;
  if (row < 6400)       src = dR + (size_t)row*200;
  else if (row < 12800) src = qR + (size_t)(row-6400)*200;
  else                  src = qL + (size_t)(row-12800)*200;

  bf16x8 afrag[13];
#pragma unroll
  for (int ks = 0; ks < 13; ks++) {
    int ko = ks*16 + h*8;
    bf16x8 af;
    if (ko < 200) {
      float4 a0 = *(const float4*)(src + ko);
      float4 a1 = *(const float4*)(src + ko + 4);
      af[0] = (__bf16)(a0.x*a0.x); af[1] = (__bf16)(a0.y*a0.y);
      af[2] = (__bf16)(a0.z*a0.z); af[3] = (__bf16)(a0.w*a0.w);
      af[4] = (__bf16)(a1.x*a1.x); af[5] = (__bf16)(a1.y*a1.y);
      af[6] = (__bf16)(a1.z*a1.z); af[7] = (__bf16)(a1.w*a1.w);
    } else {
#pragma unroll
      for (int z = 0; z < 8; z++) af[z] = (__bf16)0.0f;
    }
    afrag[ks] = af;
  }

  f32x16 C;
#pragma unroll
  for (int z = 0; z < 16; z++) C[z] = 0.f;
  const unsigned short* bp = m2b16 + (size_t)(nt*32 + n)*208 + h*8;
#pragma unroll
  for (int ks = 0; ks < 13; ks++) {
    bf16x8 bf = *(const bf16x8*)(bp + ks*16);
    C = __builtin_amdgcn_mfma_f32_32x32x16_bf16(afrag[ks], bf, C, 0, 0, 0);
  }

  int cp = nt*32 + n;                     // c' = m*50 + c
  if (cp < 200) {
    int m = cp / 50, c = cp % 50;
#pragma unroll
    for (int r = 0; r < 16; r++) {
      int grow = rt*32 + (r & 3) + 8*(r >> 2) + 4*h;
      float v = rsqrtf(fmaxf(C[r], EPS));
      if (grow < 6400) {
        if (m == 0)      invfpn[grow*50 + c] = v;
        else if (m == 1) invmpn[grow*50 + c] = v;
        else if (m == 2) invapn[grow*50 + c] = v;
        else             invxpn[grow*50 + c] = v;
      } else if (grow < 12800) {
        int r2 = grow - 6400;
        if (m == 1)      invmqn[c*6400 + r2] = v;
        else if (m == 3) invxqn[r2*50 + c] = v;
      } else {
        if (m == 0)      invfqn[(grow-12800)*50 + c] = v;
      }
    }
  }
}

// Fused rel + wq. block = (b, 8 i's). Phase 1 (lane=j): rel row in regs ->
// relsh (LDS, never hits HBM), argmax (first-max) + 1/(sum+eps) -> LDS.
// Phase 2 (lane=k): wq[i][k] = sum_j relsh[i][j] q[j][k] * invrs. fp32 exact.
__global__ __launch_bounds__(256) void k_relwq(
    const float* __restrict__ dR, const float* __restrict__ qR,
    const float* __restrict__ qMask, const float* __restrict__ dMask,
    const float* __restrict__ invdn, const float* __restrict__ invqn,
    float* __restrict__ wq, int* __restrict__ idxout)
{
  __shared__ float qsh[64*201];            // 51456 B
  __shared__ float relsh[8][256];          // 8 KB
  __shared__ float redv[4][8][2];
  __shared__ int   redi[4][8];
  __shared__ float invrs_sh[8];
  int tid = threadIdx.x;
  int b  = blockIdx.x / 25;
  int i0 = (blockIdx.x % 25) * 8;
  int j = tid, jr = min(j, 199);
  bool jv = j < 200;
  const float* qb = qR + b*40000;
  const float* db = dR + (b*200 + i0)*200;
  float acc[8];
#pragma unroll
  for (int ii = 0; ii < 8; ii++) acc[ii] = 0.f;

  for (int p = 0; p < 4; p++) {
    int kp = p*64;
    __syncthreads();
    if (p < 3) {
      for (int s = tid; s < 200*64; s += 256) { int kk = s & 63, jj = s >> 6; qsh[kk*201 + jj] = qb[jj*200 + kp + kk]; }
    } else {
      for (int s = tid; s < 200*8; s += 256) { int kk = s & 7, jj = s >> 3; qsh[kk*201 + jj] = qb[jj*200 + kp + kk]; }
    }
    __syncthreads();
    int nk = (p < 3) ? 64 : 8;
    for (int k4 = 0; k4 < nk; k4 += 4) {
      float qv[4];
#pragma unroll
      for (int kk = 0; kk < 4; kk++) qv[kk] = qsh[(k4+kk)*201 + jr];
#pragma unroll
      for (int ii = 0; ii < 8; ii++)
#pragma unroll
        for (int kk = 0; kk < 4; kk++)
          acc[ii] = fmaf(db[ii*200 + kp + k4 + kk], qv[kk], acc[ii]);
    }
  }

  float iqn = invqn[b*200 + jr];
  float qm  = qMask[b*200 + jr];
  int w = tid >> 6, l = tid & 63;
  float rv[8];
#pragma unroll
  for (int ii = 0; ii < 8; ii++) {
    float idn = invdn[b*200 + i0 + ii];
    float dm  = dMask[b*200 + i0 + ii];
    float r = acc[ii]*iqn*idn*qm*dm;
    rv[ii] = r;
    relsh[ii][j] = jv ? r : 0.f;
  }
#pragma unroll
  for (int ii = 0; ii < 8; ii++) {
    float vm = jv ? rv[ii] : NEG_HUGE;
    float vs = jv ? rv[ii] : 0.f;
    int bj = jr;
#pragma unroll
    for (int m = 32; m; m >>= 1) {
      float ov = __shfl_xor(vm, m);
      int   oj = __shfl_xor(bj, m);
      vs += __shfl_xor(vs, m);
      if (ov > vm || (ov == vm && oj < bj)) { vm = ov; bj = oj; }  // first-max wins
    }
    if (l == 0) { redv[w][ii][0] = vm; redv[w][ii][1] = vs; redi[w][ii] = bj; }
  }
  __syncthreads();
  if (tid < 8) {
    float bv = redv[0][tid][0], ss = redv[0][tid][1]; int bj = redi[0][tid];
    for (int w2 = 1; w2 < 4; w2++) {
      ss += redv[w2][tid][1];
      float wv = redv[w2][tid][0]; int wj = redi[w2][tid];
      if (wv > bv || (wv == bv && wj < bj)) { bv = wv; bj = wj; }
    }
    invrs_sh[tid] = 1.f/(ss + EPS);
    idxout[b*200 + i0 + tid] = bj;
  }
  __syncthreads();

  // phase 2: lane = k
  int kl = min(tid, 199); bool kv = tid < 200;
  float acw[8];
#pragma unroll
  for (int ii = 0; ii < 8; ii++) acw[ii] = 0.f;
  for (int j0 = 0; j0 < 200; j0 += 8) {
    float qv[8];
#pragma unroll
    for (int jj = 0; jj < 8; jj++) qv[jj] = qb[(j0+jj)*200 + kl];
#pragma unroll
    for (int ii = 0; ii < 8; ii++)
#pragma unroll
      for (int jj = 0; jj < 8; jj++)
        acw[ii] = fmaf(relsh[ii][j0+jj], qv[jj], acw[ii]);
  }
#pragma unroll
  for (int ii = 0; ii < 8; ii++) {
    float v = acw[ii]*invrs_sh[ii];
    if (kv) wq[(size_t)(b*200 + i0 + ii)*200 + tid] = v;
  }
}

// Numerator GEMMs: one wave per (mp, row-tile, nt) — 1600 tasks.
// mp in {0:d*qL, 1:d*wq, 2:wq^2, 3:d*q[argmax]}; B = m2b16 rows msel*50+.
__global__ __launch_bounds__(256,4) void k_gemm2_mfma(
    const float* __restrict__ dR, const float* __restrict__ qR,
    const float* __restrict__ qL, const float* __restrict__ wq,
    const int* __restrict__ idx, const unsigned short* __restrict__ m2b16,
    float* __restrict__ G)
{
  int tid = threadIdx.x;
  int w = tid >> 6, lane = tid & 63;
  int n = lane & 31, h = lane >> 5;
  int task = blockIdx.x*4 + w;             // [0,1600)
  int mp = task / 400;
  int sub = task % 400;
  int rt = sub >> 1, nt = sub & 1;
  int row = rt*32 + n;                     // < 6400
  int bb = row / 200;
  int msel = (mp == 0) ? 0 : (mp == 3) ? 3 : 2;

  const float* s0 = dR + (size_t)row*200;
  const float* s1;
  if (mp == 0)      s1 = qL + (size_t)bb*200;
  else if (mp == 1) s1 = wq + (size_t)row*200;
  else if (mp == 2) { s0 = wq + (size_t)row*200; s1 = s0; }
  else              s1 = qR + (size_t)(bb*200 + idx[row])*200;

  bf16x8 afrag[13];
#pragma unroll
  for (int ks = 0; ks < 13; ks++) {
    int ko = ks*16 + h*8;
    bf16x8 af;
    if (ko < 200) {
      float4 a0 = *(const float4*)(s0 + ko);
      float4 a1 = *(const float4*)(s0 + ko + 4);
      float4 b0 = *(const float4*)(s1 + ko);
      float4 b1 = *(const float4*)(s1 + ko + 4);
      af[0] = (__bf16)(a0.x*b0.x); af[1] = (__bf16)(a0.y*b0.y);
      af[2] = (__bf16)(a0.z*b0.z); af[3] = (__bf16)(a0.w*b0.w);
      af[4] = (__bf16)(a1.x*b1.x); af[5] = (__bf16)(a1.y*b1.y);
      af[6] = (__bf16)(a1.z*b1.z); af[7] = (__bf16)(a1.w*b1.w);
    } else {
#pragma unroll
      for (int z = 0; z < 8; z++) af[z] = (__bf16)0.0f;
    }
    afrag[ks] = af;
  }

  f32x16 C;
#pragma unroll
  for (int z = 0; z < 16; z++) C[z] = 0.f;
  const unsigned short* bp = m2b16 + (size_t)(msel*50 + nt*32 + n)*208 + h*8;
#pragma unroll
  for (int ks = 0; ks < 13; ks++) {
    bf16x8 bf = *(const bf16x8*)(bp + ks*16);
    C = __builtin_amdgcn_mfma_f32_32x32x16_bf16(afrag[ks], bf, C, 0, 0, 0);
  }
  int cc = nt*32 + n;
  if (cc < 50) {
#pragma unroll
    for (int r = 0; r < 16; r++) {
      int mrow = (r & 3) + 8*(r >> 2) + 4*h;
      G[(size_t)(mp*6400 + rt*32 + mrow)*50 + cc] = C[r];
    }
  }
}

// maxpool via MFMA v5. block=(b,c), 8 waves (512 thr), grid 1600.
// Wave w owns i-tile w; A = raw db16 from global (L2-hot). B staged per jh
// with iq & M2_c folded: qsh[j][k] = bf16(q*iq*M2), stride 232 shorts
// (116 words; n*20%32 covers all 8 bank quads -> conflict-free b128).
// Dual interleaved C chains (even/odd ks) for 2x MFMA ILP.
__global__ __launch_bounds__(512,4) void k_maxpool_mfma(
    const unsigned short* __restrict__ db16, const unsigned short* __restrict__ qb16,
    const float* __restrict__ m2all, const float* __restrict__ invmqn,
    float* __restrict__ pmax2, float* __restrict__ psum2)
{
  __shared__ __align__(16) unsigned short qsh[128*232];  // 59392 B -> 2 blk/CU
  int tid = threadIdx.x;
  int b = blockIdx.x / 50, c = blockIdx.x % 50;
  int w = tid >> 6, lane = tid & 63;       // w = i-tile 0..7
  int n = lane & 31, h = lane >> 5;
  const float* M2 = m2all + 10000 + c*200; // maxpool_M^2, f32
  const unsigned short* dbp = db16 + (size_t)(b*256 + w*32 + n)*208 + h*8;

  float vm[16], vs[16];
#pragma unroll
  for (int r = 0; r < 16; r++) { vm[r] = NEG_HUGE; vs[r] = 0.f; }

  for (int jh = 0; jh < 2; jh++) {
    int nrows = jh ? 96 : 128;             // j 0-127, 128-223 (224+ skipped)
    int njt   = jh ? 3 : 4;
    __syncthreads();                       // prior-jh qsh reads done
    {
      const unsigned short* src = qb16 + (size_t)(b*256 + jh*128)*208;
      const float* iqb = invmqn + c*6400 + b*200;
      for (int s = tid; s < nrows*26; s += 512) {
        int r = s / 26, ch = s - r*26;
        int j = jh*128 + r;
        float iq = (j < 200) ? iqb[j] : 0.f;
        int k0 = ch*8;
        bf16x8 v = *(const bf16x8*)(src + (size_t)r*208 + k0);
        float4 m0 = *(const float4*)(M2 + k0);       // k0=200 reads past-row
        float4 m1 = *(const float4*)(M2 + k0 + 4);   // data: finite, x0 = 0. ok
        bf16x8 o;
        o[0] = (__bf16)((float)v[0]*iq*m0.x); o[1] = (__bf16)((float)v[1]*iq*m0.y);
        o[2] = (__bf16)((float)v[2]*iq*m0.z); o[3] = (__bf16)((float)v[3]*iq*m0.w);
        o[4] = (__bf16)((float)v[4]*iq*m1.x); o[5] = (__bf16)((float)v[5]*iq*m1.y);
        o[6] = (__bf16)((float)v[6]*iq*m1.z); o[7] = (__bf16)((float)v[7]*iq*m1.w);
        *(bf16x8*)(qsh + r*232 + k0) = o;
      }
    }
    __syncthreads();

    // raw A fragments (reloaded per jh — L2 hit, no regs across the barrier)
    bf16x8 afrag[13];
#pragma unroll
    for (int ks = 0; ks < 13; ks++) afrag[ks] = *(const bf16x8*)(dbp + ks*16);

    for (int jt = 0; jt < njt; jt++) {
      f32x16 Ca, Cb;
#pragma unroll
      for (int z = 0; z < 16; z++) { Ca[z] = 0.f; Cb[z] = 0.f; }
      const unsigned short* bptr = qsh + (jt*32 + n)*232 + h*8;
#pragma unroll
      for (int ks = 0; ks < 13; ks++) {
        bf16x8 bf = *(const bf16x8*)(bptr + ks*16);
        if (ks & 1) Cb = __builtin_amdgcn_mfma_f32_32x32x16_bf16(afrag[ks], bf, Cb, 0, 0, 0);
        else        Ca = __builtin_amdgcn_mfma_f32_32x32x16_bf16(afrag[ks], bf, Ca, 0, 0, 0);
      }
      bool jv = (jh*128 + jt*32 + n) < 200;  // padded B cols are 0 -> vs safe
#pragma unroll
      for (int r = 0; r < 16; r++) {
        float v = Ca[r] + Cb[r];
        vm[r] = fmaxf(vm[r], jv ? v : NEG_HUGE);
        vs[r] += v;
      }
    }
  }

  // reduce over the 32 j-lanes (xor masks 1..16 stay within n; h is disjoint i)
#pragma unroll
  for (int r = 0; r < 16; r++) {
    float a = vm[r], s = vs[r];
#pragma unroll
    for (int m = 1; m <= 16; m <<= 1) {
      a = fmaxf(a, __shfl_xor(a, m));
      s += __shfl_xor(s, m);
    }
    vm[r] = a; vs[r] = s;
  }
  if (n == 0) {
#pragma unroll
    for (int r = 0; r < 16; r++) {
      int i = w*32 + (r & 3) + 8*(r >> 2) + 4*h;
      pmax2[(size_t)blockIdx.x*256 + i] = vm[r];
      psum2[(size_t)blockIdx.x*256 + i] = vs[r];
    }
  }
}

// Final assembly: out[row][0:250] written lane-coalesced.
__global__ void k_out(
    const float* __restrict__ G, const float* __restrict__ pmax2,
    const float* __restrict__ psum2, const float* __restrict__ invfpn,
    const float* __restrict__ invmpn, const float* __restrict__ invapn,
    const float* __restrict__ invxpn, const float* __restrict__ invfqn,
    const float* __restrict__ invxqn, const int* __restrict__ idx,
    float* __restrict__ out)
{
  int row = blockIdx.x;
  int l = threadIdx.x;
  if (l >= 250) return;
  int b = row / 200, i = row % 200;
  int seg = l / 50, c = l % 50;
  float o;
  if (seg == 0) {
    o = G[(size_t)(0*6400 + row)*50 + c] * invfpn[row*50 + c] * invfqn[b*50 + c];
  } else if (seg == 1) {
    o = pmax2[(size_t)(b*50 + c)*256 + i] * invmpn[row*50 + c];
  } else if (seg == 2) {
    o = psum2[(size_t)(b*50 + c)*256 + i] * invmpn[row*50 + c] * (1.f/200.f);
  } else if (seg == 3) {
    o = G[(size_t)(1*6400 + row)*50 + c] * invapn[row*50 + c]
        * rsqrtf(fmaxf(G[(size_t)(2*6400 + row)*50 + c], EPS));
  } else {
    int jid = idx[row];
    o = G[(size_t)(3*6400 + row)*50 + c] * invxpn[row*50 + c]
        * invxqn[(b*200 + jid)*50 + c];
  }
  out[(size_t)row*250 + l] = o;
}

extern "C" void kernel_launch(void* const* d_in, const int* in_sizes, int n_in,
                              void* d_out, int out_size, void* d_ws, size_t ws_size,
                              hipStream_t stream) {
  const float* qR = (const float*)d_in[0];
  const float* qL = (const float*)d_in[1];
  const float* qM = (const float*)d_in[2];
  const float* dR = (const float*)d_in[3];
  // d_in[4] = d_last: unused by the reference
  const float* dM = (const float*)d_in[5];
  const float* fullM = (const float*)d_in[6];
  const float* mpM   = (const float*)d_in[7];
  const float* attM  = (const float*)d_in[8];
  const float* xM    = (const float*)d_in[9];

  float* ws  = (float*)d_ws;
  float* out = (float*)d_out;

  float* m2all  = ws + OFF_M2ALL;
  unsigned short* m2b16 = (unsigned short*)(ws + OFF_M2B16);
  unsigned short* qb16 = (unsigned short*)(ws + OFF_QB16);
  unsigned short* db16 = (unsigned short*)(ws + OFF_DB16);
  float* invfpn = ws + OFF_INVFPN;
  float* invmpn = ws + OFF_INVMPN;
  float* invapn = ws + OFF_INVAPN;
  float* invxpn = ws + OFF_INVXPN;
  float* invmqn = ws + OFF_INVMQN;
  float* invxqn = ws + OFF_INVXQN;
  float* invfqn = ws + OFF_INVFQN;
  float* invdn  = ws + OFF_INVDN;
  float* invqn  = ws + OFF_INVQN;
  int*   idxp   = (int*)(ws + OFF_IDX);
  float* wqp    = ws + OFF_WQ;
  float* G      = ws + OFF_G;
  float* pmax2  = ws + OFF_PMAX2;
  float* psum2  = ws + OFF_PSUM2;

  k_prep<<<4278, 256, 0, stream>>>(qR, dR, fullM, mpM, attM, xM,
                                   qb16, db16, invdn, invqn, m2all, m2b16);
  k_gemm1_mfma<<<702, 256, 0, stream>>>(dR, qR, qL, m2b16,
                                        invfpn, invmpn, invapn, invxpn,
                                        invmqn, invxqn, invfqn);
  k_relwq<<<800, 256, 0, stream>>>(dR, qR, qM, dM, invdn, invqn, wqp, idxp);
  k_gemm2_mfma<<<400, 256, 0, stream>>>(dR, qR, qL, wqp, idxp, m2b16, G);
  k_maxpool_mfma<<<1600, 512, 0, stream>>>(db16, qb16, m2all, invmqn, pmax2, psum2);
  k_out<<<6400, 256, 0, stream>>>(G, pmax2, psum2, invfpn, invmpn, invapn,
                                  invxpn, invfqn, invxqn, idxp, out);
}

// Round 9
// 278.302 us; speedup vs baseline: 5.6460x; 1.0350x over previous
//
#include <hip/hip_runtime.h>
#include <math.h>

// MultiPerspectiveMatch on MI355X — round 9.
// vs round 8:
//  - k_maxpool v6: single C chain again (r8 dual chain spilled: WRITE 22.6MB);
//    stride back to 216 (232 changed nothing — conflicts come from shfl);
//    __launch_bounds__(512,2): r6/r8 compiler squeezed to VGPR=64 and
//    REMATERIALIZED afrag from L2 inside the jt loop (~1.2GB L2/dispatch).
//    Budget 256 keeps afrag resident; loaded ONCE, held across barriers.
//  - k_relwq v2: qsh in [j][k] layout (68-word rows, 4*17 -> conflict-free
//    b128) so phase1 is 50 b128 reads not 400 b32; relsh read as float4.
// Everything else unchanged from r8.

#define EPS 1e-6f
#define NEG_HUGE -3.4e38f

typedef __bf16 bf16x8 __attribute__((ext_vector_type(8)));
typedef float f32x16 __attribute__((ext_vector_type(16)));

// ---- ws offsets (floats) ----
constexpr size_t OFF_M2ALL = 0;            // f32 [4][50][200] = 40,000
constexpr size_t OFF_M2B16 = 40000;        // bf16 [224][208] = 23,296 fl
constexpr size_t OFF_QB16  = 63296;        // bf16 [32][256][208] = 851,968 fl
constexpr size_t OFF_DB16  = 915264;       // bf16 [32][256][208] = 851,968 fl
constexpr size_t OFF_INVFPN= 1767232;      // [6400][50]
constexpr size_t OFF_INVMPN= 2087232;
constexpr size_t OFF_INVAPN= 2407232;
constexpr size_t OFF_INVXPN= 2727232;
constexpr size_t OFF_INVMQN= 3047232;      // [c(50)][6400]
constexpr size_t OFF_INVXQN= 3367232;      // [6400][50]
constexpr size_t OFF_INVFQN= 3687232;      // [32][50]
constexpr size_t OFF_INVDN = 3688832;      // [6400]
constexpr size_t OFF_INVQN = 3695232;      // [6400]
constexpr size_t OFF_IDX   = 3701632;      // int [6400]
constexpr size_t OFF_WQ    = 3708032;      // [32][200][200] = 1,280,000
constexpr size_t OFF_G     = 4988032;      // [4][6400][50] = 1,280,000
constexpr size_t OFF_PMAX2 = 6268032;      // [1600][256]
constexpr size_t OFF_PSUM2 = 6677632;      // [1600][256]
// end = 7,087,232 floats = 28.3 MB

// Fused prep: blocks [0,4096): d/q rows -> bf16 padded [32][256][208] + plain
// norms (one row per wave). Blocks [4096, 4278): M^2 tables (f32 + bf16).
__global__ __launch_bounds__(256) void k_prep(
    const float* __restrict__ qR, const float* __restrict__ dR,
    const float* __restrict__ fM, const float* __restrict__ mM,
    const float* __restrict__ aM, const float* __restrict__ xM,
    unsigned short* __restrict__ qb16, unsigned short* __restrict__ db16,
    float* __restrict__ invdn, float* __restrict__ invqn,
    float* __restrict__ m2all, unsigned short* __restrict__ m2b16)
{
  int blk = blockIdx.x;
  int tid = threadIdx.x;
  if (blk < 4096) {
    int task = blk*4 + (tid >> 6);        // 0..16383
    int l = tid & 63;
    int isQ = task >= 8192;
    int r = isQ ? task - 8192 : task;     // b*256 + j
    int b = r >> 8, j = r & 255;
    unsigned short* dst = (isQ ? qb16 : db16) + (size_t)r*208;
    if (j < 200) {
      const float* src = (isQ ? qR : dR) + (size_t)(b*200 + j)*200;
      float4 v = {0.f,0.f,0.f,0.f};
      if (l < 50) v = *(const float4*)(src + l*4);
      float s = fmaf(v.x,v.x, fmaf(v.y,v.y, fmaf(v.z,v.z, v.w*v.w)));
#pragma unroll
      for (int m = 32; m; m >>= 1) s += __shfl_xor(s, m);
      if (l == 0) {
        float rr = rsqrtf(fmaxf(s, EPS));
        if (isQ) invqn[b*200 + j] = rr; else invdn[b*200 + j] = rr;
      }
      if (l < 52) {
        ushort4 o = {0,0,0,0};
        if (l < 50) {
          __bf16 h0=(__bf16)v.x, h1=(__bf16)v.y, h2=(__bf16)v.z, h3=(__bf16)v.w;
          o.x = *(unsigned short*)&h0; o.y = *(unsigned short*)&h1;
          o.z = *(unsigned short*)&h2; o.w = *(unsigned short*)&h3;
        }
        *(ushort4*)(dst + l*4) = o;
      }
    } else {
      if (l < 52) { ushort4 z = {0,0,0,0}; *(ushort4*)(dst + l*4) = z; }
    }
  } else {
    int i = (blk - 4096)*256 + tid;
    if (i < 40000) {
      int m = i / 10000, r = i % 10000;
      const float* s = (m==0)?fM:(m==1)?mM:(m==2)?aM:xM;
      float v = s[r];
      m2all[i] = v*v;
    }
    if (i < 224*208) {
      int row = i / 208, k = i % 208;
      unsigned short o = 0;
      if (row < 200 && k < 200) {
        int m = row / 50, c = row % 50;
        const float* s = (m==0)?fM:(m==1)?mM:(m==2)?aM:xM;
        float v = s[c*200 + k];
        __bf16 h = (__bf16)(v*v);
        o = *(unsigned short*)&h;
      }
      m2b16[i] = o;
    }
  }
}

// nsq GEMM + fused rsqrt/scatter. One wave per (row-tile, nt): 2807 tasks.
__global__ __launch_bounds__(256,4) void k_gemm1_mfma(
    const float* __restrict__ dR, const float* __restrict__ qR,
    const float* __restrict__ qL, const unsigned short* __restrict__ m2b16,
    float* __restrict__ invfpn, float* __restrict__ invmpn,
    float* __restrict__ invapn, float* __restrict__ invxpn,
    float* __restrict__ invmqn, float* __restrict__ invxqn,
    float* __restrict__ invfqn)
{
  int tid = threadIdx.x;
  int w = tid >> 6, lane = tid & 63;
  int n = lane & 31, h = lane >> 5;
  int task = blockIdx.x*4 + w;
  if (task >= 2807) return;               // wave-uniform
  int rt = task / 7, nt = task % 7;       // rt in [0,401), 401*32 = 12832
  int row = rt*32 + n;

  const float* src;
  if (row < 6400)       src = dR + (size_t)row*200;
  else if (row < 12800) src = qR + (size_t)(row-6400)*200;
  else                  src = qL + (size_t)(row-12800)*200;

  bf16x8 afrag[13];
#pragma unroll
  for (int ks = 0; ks < 13; ks++) {
    int ko = ks*16 + h*8;
    bf16x8 af;
    if (ko < 200) {
      float4 a0 = *(const float4*)(src + ko);
      float4 a1 = *(const float4*)(src + ko + 4);
      af[0] = (__bf16)(a0.x*a0.x); af[1] = (__bf16)(a0.y*a0.y);
      af[2] = (__bf16)(a0.z*a0.z); af[3] = (__bf16)(a0.w*a0.w);
      af[4] = (__bf16)(a1.x*a1.x); af[5] = (__bf16)(a1.y*a1.y);
      af[6] = (__bf16)(a1.z*a1.z); af[7] = (__bf16)(a1.w*a1.w);
    } else {
#pragma unroll
      for (int z = 0; z < 8; z++) af[z] = (__bf16)0.0f;
    }
    afrag[ks] = af;
  }

  f32x16 C;
#pragma unroll
  for (int z = 0; z < 16; z++) C[z] = 0.f;
  const unsigned short* bp = m2b16 + (size_t)(nt*32 + n)*208 + h*8;
#pragma unroll
  for (int ks = 0; ks < 13; ks++) {
    bf16x8 bf = *(const bf16x8*)(bp + ks*16);
    C = __builtin_amdgcn_mfma_f32_32x32x16_bf16(afrag[ks], bf, C, 0, 0, 0);
  }

  int cp = nt*32 + n;                     // c' = m*50 + c
  if (cp < 200) {
    int m = cp / 50, c = cp % 50;
#pragma unroll
    for (int r = 0; r < 16; r++) {
      int grow = rt*32 + (r & 3) + 8*(r >> 2) + 4*h;
      float v = rsqrtf(fmaxf(C[r], EPS));
      if (grow < 6400) {
        if (m == 0)      invfpn[grow*50 + c] = v;
        else if (m == 1) invmpn[grow*50 + c] = v;
        else if (m == 2) invapn[grow*50 + c] = v;
        else             invxpn[grow*50 + c] = v;
      } else if (grow < 12800) {
        int r2 = grow - 6400;
        if (m == 1)      invmqn[c*6400 + r2] = v;
        else if (m == 3) invxqn[r2*50 + c] = v;
      } else {
        if (m == 0)      invfqn[(grow-12800)*50 + c] = v;
      }
    }
  }
}

// Fused rel + wq, v2. block = (b, 8 i's).
// Phase 1 (lane=j): qsh[j][k-chunk] layout, 68-word rows (4*17 odd-multiple
// -> conflict-free b128); 50 ds_read_b128/thread (was 400 b32).
// Phase 2 (lane=k): relsh rows read as float4 broadcasts (400 b128, was 1600
// b32). fp32 exact throughout (argmax needs it).
__global__ __launch_bounds__(256) void k_relwq(
    const float* __restrict__ dR, const float* __restrict__ qR,
    const float* __restrict__ qMask, const float* __restrict__ dMask,
    const float* __restrict__ invdn, const float* __restrict__ invqn,
    float* __restrict__ wq, int* __restrict__ idxout)
{
  __shared__ __align__(16) float qsh[200*68];  // 54400 B
  __shared__ float relsh[8][256];              // 8 KB
  __shared__ float redv[4][8][2];
  __shared__ int   redi[4][8];
  __shared__ float invrs_sh[8];
  int tid = threadIdx.x;
  int b  = blockIdx.x / 25;
  int i0 = (blockIdx.x % 25) * 8;
  int j = tid, jr = min(j, 199);
  bool jv = j < 200;
  const float* qb = qR + b*40000;
  const float* db = dR + (b*200 + i0)*200;
  float acc[8];
#pragma unroll
  for (int ii = 0; ii < 8; ii++) acc[ii] = 0.f;

  for (int p = 0; p < 4; p++) {
    int kp = p*64; int nk = (p < 3) ? 64 : 8;
    int nch = nk >> 2;                     // float4 chunks per row
    __syncthreads();
    for (int s = tid; s < 200*nch; s += 256) {
      int jj = s / nch, kk4 = (s - jj*nch)*4;
      float4 v = *(const float4*)(qb + jj*200 + kp + kk4);
      *(float4*)(qsh + jj*68 + kk4) = v;
    }
    __syncthreads();
    for (int k4 = 0; k4 < nk; k4 += 4) {
      float4 qv = *(const float4*)(qsh + jr*68 + k4);
#pragma unroll
      for (int ii = 0; ii < 8; ii++) {
        acc[ii] = fmaf(db[ii*200 + kp + k4 + 0], qv.x, acc[ii]);
        acc[ii] = fmaf(db[ii*200 + kp + k4 + 1], qv.y, acc[ii]);
        acc[ii] = fmaf(db[ii*200 + kp + k4 + 2], qv.z, acc[ii]);
        acc[ii] = fmaf(db[ii*200 + kp + k4 + 3], qv.w, acc[ii]);
      }
    }
  }

  float iqn = invqn[b*200 + jr];
  float qm  = qMask[b*200 + jr];
  int w = tid >> 6, l = tid & 63;
  float rv[8];
#pragma unroll
  for (int ii = 0; ii < 8; ii++) {
    float idn = invdn[b*200 + i0 + ii];
    float dm  = dMask[b*200 + i0 + ii];
    float r = acc[ii]*iqn*idn*qm*dm;
    rv[ii] = r;
    relsh[ii][j] = jv ? r : 0.f;
  }
#pragma unroll
  for (int ii = 0; ii < 8; ii++) {
    float vm = jv ? rv[ii] : NEG_HUGE;
    float vs = jv ? rv[ii] : 0.f;
    int bj = jr;
#pragma unroll
    for (int m = 32; m; m >>= 1) {
      float ov = __shfl_xor(vm, m);
      int   oj = __shfl_xor(bj, m);
      vs += __shfl_xor(vs, m);
      if (ov > vm || (ov == vm && oj < bj)) { vm = ov; bj = oj; }  // first-max wins
    }
    if (l == 0) { redv[w][ii][0] = vm; redv[w][ii][1] = vs; redi[w][ii] = bj; }
  }
  __syncthreads();
  if (tid < 8) {
    float bv = redv[0][tid][0], ss = redv[0][tid][1]; int bj = redi[0][tid];
    for (int w2 = 1; w2 < 4; w2++) {
      ss += redv[w2][tid][1];
      float wv = redv[w2][tid][0]; int wj = redi[w2][tid];
      if (wv > bv || (wv == bv && wj < bj)) { bv = wv; bj = wj; }
    }
    invrs_sh[tid] = 1.f/(ss + EPS);
    idxout[b*200 + i0 + tid] = bj;
  }
  __syncthreads();

  // phase 2: lane = k
  int kl = min(tid, 199); bool kv = tid < 200;
  float acw[8];
#pragma unroll
  for (int ii = 0; ii < 8; ii++) acw[ii] = 0.f;
  for (int j0 = 0; j0 < 200; j0 += 4) {
    float qv0 = qb[(j0+0)*200 + kl];
    float qv1 = qb[(j0+1)*200 + kl];
    float qv2 = qb[(j0+2)*200 + kl];
    float qv3 = qb[(j0+3)*200 + kl];
#pragma unroll
    for (int ii = 0; ii < 8; ii++) {
      float4 rs = *(const float4*)&relsh[ii][j0];
      acw[ii] = fmaf(rs.x, qv0, acw[ii]);
      acw[ii] = fmaf(rs.y, qv1, acw[ii]);
      acw[ii] = fmaf(rs.z, qv2, acw[ii]);
      acw[ii] = fmaf(rs.w, qv3, acw[ii]);
    }
  }
#pragma unroll
  for (int ii = 0; ii < 8; ii++) {
    float v = acw[ii]*invrs_sh[ii];
    if (kv) wq[(size_t)(b*200 + i0 + ii)*200 + tid] = v;
  }
}

// Numerator GEMMs: one wave per (mp, row-tile, nt) — 1600 tasks.
__global__ __launch_bounds__(256,4) void k_gemm2_mfma(
    const float* __restrict__ dR, const float* __restrict__ qR,
    const float* __restrict__ qL, const float* __restrict__ wq,
    const int* __restrict__ idx, const unsigned short* __restrict__ m2b16,
    float* __restrict__ G)
{
  int tid = threadIdx.x;
  int w = tid >> 6, lane = tid & 63;
  int n = lane & 31, h = lane >> 5;
  int task = blockIdx.x*4 + w;             // [0,1600)
  int mp = task / 400;
  int sub = task % 400;
  int rt = sub >> 1, nt = sub & 1;
  int row = rt*32 + n;                     // < 6400
  int bb = row / 200;
  int msel = (mp == 0) ? 0 : (mp == 3) ? 3 : 2;

  const float* s0 = dR + (size_t)row*200;
  const float* s1;
  if (mp == 0)      s1 = qL + (size_t)bb*200;
  else if (mp == 1) s1 = wq + (size_t)row*200;
  else if (mp == 2) { s0 = wq + (size_t)row*200; s1 = s0; }
  else              s1 = qR + (size_t)(bb*200 + idx[row])*200;

  bf16x8 afrag[13];
#pragma unroll
  for (int ks = 0; ks < 13; ks++) {
    int ko = ks*16 + h*8;
    bf16x8 af;
    if (ko < 200) {
      float4 a0 = *(const float4*)(s0 + ko);
      float4 a1 = *(const float4*)(s0 + ko + 4);
      float4 b0 = *(const float4*)(s1 + ko);
      float4 b1 = *(const float4*)(s1 + ko + 4);
      af[0] = (__bf16)(a0.x*b0.x); af[1] = (__bf16)(a0.y*b0.y);
      af[2] = (__bf16)(a0.z*b0.z); af[3] = (__bf16)(a0.w*b0.w);
      af[4] = (__bf16)(a1.x*b1.x); af[5] = (__bf16)(a1.y*b1.y);
      af[6] = (__bf16)(a1.z*b1.z); af[7] = (__bf16)(a1.w*b1.w);
    } else {
#pragma unroll
      for (int z = 0; z < 8; z++) af[z] = (__bf16)0.0f;
    }
    afrag[ks] = af;
  }

  f32x16 C;
#pragma unroll
  for (int z = 0; z < 16; z++) C[z] = 0.f;
  const unsigned short* bp = m2b16 + (size_t)(msel*50 + nt*32 + n)*208 + h*8;
#pragma unroll
  for (int ks = 0; ks < 13; ks++) {
    bf16x8 bf = *(const bf16x8*)(bp + ks*16);
    C = __builtin_amdgcn_mfma_f32_32x32x16_bf16(afrag[ks], bf, C, 0, 0, 0);
  }
  int cc = nt*32 + n;
  if (cc < 50) {
#pragma unroll
    for (int r = 0; r < 16; r++) {
      int mrow = (r & 3) + 8*(r >> 2) + 4*h;
      G[(size_t)(mp*6400 + rt*32 + mrow)*50 + cc] = C[r];
    }
  }
}

// maxpool via MFMA v6. block=(b,c), 8 waves (512 thr), grid 1600.
// Wave w owns i-tile w. A = raw db16, loaded ONCE into regs and held across
// barriers — __launch_bounds__(512,2) gives VGPR budget 256 so the compiler
// does NOT squeeze to the 64-reg tier and rematerialize A from L2 per j-tile
// (r6/r8 pathology: VGPR_Count=64, ~1.2GB L2 reads/dispatch).
// B staged per jh with iq & M2_c folded; qsh stride 216 shorts (108 words =
// 4*27, odd multiple of 4 -> conflict-free b128). Single C chain (dual
// spilled in r8). C/D: col=lane&31 (j), row=(r&3)+8*(r>>2)+4*(lane>>5) (i).
__global__ __launch_bounds__(512,2) void k_maxpool_mfma(
    const unsigned short* __restrict__ db16, const unsigned short* __restrict__ qb16,
    const float* __restrict__ m2all, const float* __restrict__ invmqn,
    float* __restrict__ pmax2, float* __restrict__ psum2)
{
  __shared__ __align__(16) unsigned short qsh[128*216];  // 55296 B -> 2 blk/CU
  int tid = threadIdx.x;
  int b = blockIdx.x / 50, c = blockIdx.x % 50;
  int w = tid >> 6, lane = tid & 63;       // w = i-tile 0..7
  int n = lane & 31, h = lane >> 5;
  const float* M2 = m2all + 10000 + c*200; // maxpool_M^2, f32
  const unsigned short* dbp = db16 + (size_t)(b*256 + w*32 + n)*208 + h*8;

  // A resident for the whole kernel (52 VGPR)
  bf16x8 afrag[13];
#pragma unroll
  for (int ks = 0; ks < 13; ks++) afrag[ks] = *(const bf16x8*)(dbp + ks*16);

  float vm[16], vs[16];
#pragma unroll
  for (int r = 0; r < 16; r++) { vm[r] = NEG_HUGE; vs[r] = 0.f; }

  for (int jh = 0; jh < 2; jh++) {
    int nrows = jh ? 96 : 128;             // j 0-127, 128-223 (224+ skipped)
    int njt   = jh ? 3 : 4;
    __syncthreads();                       // prior-jh qsh reads done
    {
      const unsigned short* src = qb16 + (size_t)(b*256 + jh*128)*208;
      const float* iqb = invmqn + c*6400 + b*200;
      for (int s = tid; s < nrows*26; s += 512) {
        int r = s / 26, ch = s - r*26;
        int j = jh*128 + r;
        float iq = (j < 200) ? iqb[j] : 0.f;
        int k0 = ch*8;
        bf16x8 v = *(const bf16x8*)(src + (size_t)r*208 + k0);
        float4 m0 = *(const float4*)(M2 + k0);       // k0=200 reads past-row
        float4 m1 = *(const float4*)(M2 + k0 + 4);   // data: finite, x0 = 0. ok
        bf16x8 o;
        o[0] = (__bf16)((float)v[0]*iq*m0.x); o[1] = (__bf16)((float)v[1]*iq*m0.y);
        o[2] = (__bf16)((float)v[2]*iq*m0.z); o[3] = (__bf16)((float)v[3]*iq*m0.w);
        o[4] = (__bf16)((float)v[4]*iq*m1.x); o[5] = (__bf16)((float)v[5]*iq*m1.y);
        o[6] = (__bf16)((float)v[6]*iq*m1.z); o[7] = (__bf16)((float)v[7]*iq*m1.w);
        *(bf16x8*)(qsh + r*216 + k0) = o;
      }
    }
    __syncthreads();

    for (int jt = 0; jt < njt; jt++) {
      f32x16 C;
#pragma unroll
      for (int z = 0; z < 16; z++) C[z] = 0.f;
      const unsigned short* bptr = qsh + (jt*32 + n)*216 + h*8;
#pragma unroll
      for (int ks = 0; ks < 13; ks++) {
        bf16x8 bf = *(const bf16x8*)(bptr + ks*16);
        C = __builtin_amdgcn_mfma_f32_32x32x16_bf16(afrag[ks], bf, C, 0, 0, 0);
      }
      bool jv = (jh*128 + jt*32 + n) < 200;  // padded B cols are 0 -> vs safe
#pragma unroll
      for (int r = 0; r < 16; r++) {
        vm[r] = fmaxf(vm[r], jv ? C[r] : NEG_HUGE);
        vs[r] += C[r];
      }
    }
  }

  // reduce over the 32 j-lanes (xor masks 1..16 stay within n; h is disjoint i)
#pragma unroll
  for (int r = 0; r < 16; r++) {
    float a = vm[r], s = vs[r];
#pragma unroll
    for (int m = 1; m <= 16; m <<= 1) {
      a = fmaxf(a, __shfl_xor(a, m));
      s += __shfl_xor(s, m);
    }
    vm[r] = a; vs[r] = s;
  }
  if (n == 0) {
#pragma unroll
    for (int r = 0; r < 16; r++) {
      int i = w*32 + (r & 3) + 8*(r >> 2) + 4*h;
      pmax2[(size_t)blockIdx.x*256 + i] = vm[r];
      psum2[(size_t)blockIdx.x*256 + i] = vs[r];
    }
  }
}

// Final assembly: out[row][0:250] written lane-coalesced.
__global__ void k_out(
    const float* __restrict__ G, const float* __restrict__ pmax2,
    const float* __restrict__ psum2, const float* __restrict__ invfpn,
    const float* __restrict__ invmpn, const float* __restrict__ invapn,
    const float* __restrict__ invxpn, const float* __restrict__ invfqn,
    const float* __restrict__ invxqn, const int* __restrict__ idx,
    float* __restrict__ out)
{
  int row = blockIdx.x;
  int l = threadIdx.x;
  if (l >= 250) return;
  int b = row / 200, i = row % 200;
  int seg = l / 50, c = l % 50;
  float o;
  if (seg == 0) {
    o = G[(size_t)(0*6400 + row)*50 + c] * invfpn[row*50 + c] * invfqn[b*50 + c];
  } else if (seg == 1) {
    o = pmax2[(size_t)(b*50 + c)*256 + i] * invmpn[row*50 + c];
  } else if (seg == 2) {
    o = psum2[(size_t)(b*50 + c)*256 + i] * invmpn[row*50 + c] * (1.f/200.f);
  } else if (seg == 3) {
    o = G[(size_t)(1*6400 + row)*50 + c] * invapn[row*50 + c]
        * rsqrtf(fmaxf(G[(size_t)(2*6400 + row)*50 + c], EPS));
  } else {
    int jid = idx[row];
    o = G[(size_t)(3*6400 + row)*50 + c] * invxpn[row*50 + c]
        * invxqn[(b*200 + jid)*50 + c];
  }
  out[(size_t)row*250 + l] = o;
}

extern "C" void kernel_launch(void* const* d_in, const int* in_sizes, int n_in,
                              void* d_out, int out_size, void* d_ws, size_t ws_size,
                              hipStream_t stream) {
  const float* qR = (const float*)d_in[0];
  const float* qL = (const float*)d_in[1];
  const float* qM = (const float*)d_in[2];
  const float* dR = (const float*)d_in[3];
  // d_in[4] = d_last: unused by the reference
  const float* dM = (const float*)d_in[5];
  const float* fullM = (const float*)d_in[6];
  const float* mpM   = (const float*)d_in[7];
  const float* attM  = (const float*)d_in[8];
  const float* xM    = (const float*)d_in[9];

  float* ws  = (float*)d_ws;
  float* out = (float*)d_out;

  float* m2all  = ws + OFF_M2ALL;
  unsigned short* m2b16 = (unsigned short*)(ws + OFF_M2B16);
  unsigned short* qb16 = (unsigned short*)(ws + OFF_QB16);
  unsigned short* db16 = (unsigned short*)(ws + OFF_DB16);
  float* invfpn = ws + OFF_INVFPN;
  float* invmpn = ws + OFF_INVMPN;
  float* invapn = ws + OFF_INVAPN;
  float* invxpn = ws + OFF_INVXPN;
  float* invmqn = ws + OFF_INVMQN;
  float* invxqn = ws + OFF_INVXQN;
  float* invfqn = ws + OFF_INVFQN;
  float* invdn  = ws + OFF_INVDN;
  float* invqn  = ws + OFF_INVQN;
  int*   idxp   = (int*)(ws + OFF_IDX);
  float* wqp    = ws + OFF_WQ;
  float* G      = ws + OFF_G;
  float* pmax2  = ws + OFF_PMAX2;
  float* psum2  = ws + OFF_PSUM2;

  k_prep<<<4278, 256, 0, stream>>>(qR, dR, fullM, mpM, attM, xM,
                                   qb16, db16, invdn, invqn, m2all, m2b16);
  k_gemm1_mfma<<<702, 256, 0, stream>>>(dR, qR, qL, m2b16,
                                        invfpn, invmpn, invapn, invxpn,
                                        invmqn, invxqn, invfqn);
  k_relwq<<<800, 256, 0, stream>>>(dR, qR, qM, dM, invdn, invqn, wqp, idxp);
  k_gemm2_mfma<<<400, 256, 0, stream>>>(dR, qR, qL, wqp, idxp, m2b16, G);
  k_maxpool_mfma<<<1600, 512, 0, stream>>>(db16, qb16, m2all, invmqn, pmax2, psum2);
  k_out<<<6400, 256, 0, stream>>>(G, pmax2, psum2, invfpn, invmpn, invapn,
                                  invxpn, invfqn, invxqn, idxp, out);
}

// Round 10
// 248.079 us; speedup vs baseline: 6.3338x; 1.1218x over previous
//
#include <hip/hip_runtime.h>
#include <math.h>

// MultiPerspectiveMatch on MI355X — round 10.
// vs round 9 (maxpool 84us at its occupancy ceiling; residue 194us over 5
// kernels whose work only justifies ~100us -> ~20us/launch fixed cost):
//  - 4 kernels (was 6), fusing independent stages:
//      k_mid = gemm1 (blocks 0..701) + relwq (blocks 702..1501)
//      k_big = maxpool (blocks 0..1599, dispatched first) + gemm2 (1600..1799)
//  - relwq v3: no qsh LDS staging — lane j reads its q row direct from global
//    (L2-resident, lines fully consumed per-thread; same fma order -> argmax
//    bit-stable). k_mid LDS = 8.3KB.
//  - maxpool internals unchanged from r9 (84us, proven).

#define EPS 1e-6f
#define NEG_HUGE -3.4e38f

typedef __bf16 bf16x8 __attribute__((ext_vector_type(8)));
typedef float f32x16 __attribute__((ext_vector_type(16)));

// ---- ws offsets (floats) ----
constexpr size_t OFF_M2ALL = 0;            // f32 [4][50][200] = 40,000
constexpr size_t OFF_M2B16 = 40000;        // bf16 [224][208] = 23,296 fl
constexpr size_t OFF_QB16  = 63296;        // bf16 [32][256][208] = 851,968 fl
constexpr size_t OFF_DB16  = 915264;       // bf16 [32][256][208] = 851,968 fl
constexpr size_t OFF_INVFPN= 1767232;      // [6400][50]
constexpr size_t OFF_INVMPN= 2087232;
constexpr size_t OFF_INVAPN= 2407232;
constexpr size_t OFF_INVXPN= 2727232;
constexpr size_t OFF_INVMQN= 3047232;      // [c(50)][6400]
constexpr size_t OFF_INVXQN= 3367232;      // [6400][50]
constexpr size_t OFF_INVFQN= 3687232;      // [32][50]
constexpr size_t OFF_INVDN = 3688832;      // [6400]
constexpr size_t OFF_INVQN = 3695232;      // [6400]
constexpr size_t OFF_IDX   = 3701632;      // int [6400]
constexpr size_t OFF_WQ    = 3708032;      // [32][200][200] = 1,280,000
constexpr size_t OFF_G     = 4988032;      // [4][6400][50] = 1,280,000
constexpr size_t OFF_PMAX2 = 6268032;      // [1600][256]
constexpr size_t OFF_PSUM2 = 6677632;      // [1600][256]
// end = 7,087,232 floats = 28.3 MB

// Fused prep: blocks [0,4096): d/q rows -> bf16 padded [32][256][208] + plain
// norms (one row per wave). Blocks [4096, 4278): M^2 tables (f32 + bf16).
__global__ __launch_bounds__(256) void k_prep(
    const float* __restrict__ qR, const float* __restrict__ dR,
    const float* __restrict__ fM, const float* __restrict__ mM,
    const float* __restrict__ aM, const float* __restrict__ xM,
    unsigned short* __restrict__ qb16, unsigned short* __restrict__ db16,
    float* __restrict__ invdn, float* __restrict__ invqn,
    float* __restrict__ m2all, unsigned short* __restrict__ m2b16)
{
  int blk = blockIdx.x;
  int tid = threadIdx.x;
  if (blk < 4096) {
    int task = blk*4 + (tid >> 6);        // 0..16383
    int l = tid & 63;
    int isQ = task >= 8192;
    int r = isQ ? task - 8192 : task;     // b*256 + j
    int b = r >> 8, j = r & 255;
    unsigned short* dst = (isQ ? qb16 : db16) + (size_t)r*208;
    if (j < 200) {
      const float* src = (isQ ? qR : dR) + (size_t)(b*200 + j)*200;
      float4 v = {0.f,0.f,0.f,0.f};
      if (l < 50) v = *(const float4*)(src + l*4);
      float s = fmaf(v.x,v.x, fmaf(v.y,v.y, fmaf(v.z,v.z, v.w*v.w)));
#pragma unroll
      for (int m = 32; m; m >>= 1) s += __shfl_xor(s, m);
      if (l == 0) {
        float rr = rsqrtf(fmaxf(s, EPS));
        if (isQ) invqn[b*200 + j] = rr; else invdn[b*200 + j] = rr;
      }
      if (l < 52) {
        ushort4 o = {0,0,0,0};
        if (l < 50) {
          __bf16 h0=(__bf16)v.x, h1=(__bf16)v.y, h2=(__bf16)v.z, h3=(__bf16)v.w;
          o.x = *(unsigned short*)&h0; o.y = *(unsigned short*)&h1;
          o.z = *(unsigned short*)&h2; o.w = *(unsigned short*)&h3;
        }
        *(ushort4*)(dst + l*4) = o;
      }
    } else {
      if (l < 52) { ushort4 z = {0,0,0,0}; *(ushort4*)(dst + l*4) = z; }
    }
  } else {
    int i = (blk - 4096)*256 + tid;
    if (i < 40000) {
      int m = i / 10000, r = i % 10000;
      const float* s = (m==0)?fM:(m==1)?mM:(m==2)?aM:xM;
      float v = s[r];
      m2all[i] = v*v;
    }
    if (i < 224*208) {
      int row = i / 208, k = i % 208;
      unsigned short o = 0;
      if (row < 200 && k < 200) {
        int m = row / 50, c = row % 50;
        const float* s = (m==0)?fM:(m==1)?mM:(m==2)?aM:xM;
        float v = s[c*200 + k];
        __bf16 h = (__bf16)(v*v);
        o = *(unsigned short*)&h;
      }
      m2b16[i] = o;
    }
  }
}

// k_mid: blocks [0,702) = gemm1 (nsq MFMA + fused rsqrt/scatter, one wave per
// (row-tile,nt), 2807 tasks); blocks [702,1502) = relwq (rel+wq fused, v3:
// per-lane direct global q rows, no qsh staging; relsh stays in LDS).
__global__ __launch_bounds__(256) void k_mid(
    const float* __restrict__ dR, const float* __restrict__ qR,
    const float* __restrict__ qL, const unsigned short* __restrict__ m2b16,
    float* __restrict__ invfpn, float* __restrict__ invmpn,
    float* __restrict__ invapn, float* __restrict__ invxpn,
    float* __restrict__ invmqn, float* __restrict__ invxqn,
    float* __restrict__ invfqn,
    const float* __restrict__ qMask, const float* __restrict__ dMask,
    const float* __restrict__ invdn, const float* __restrict__ invqn,
    float* __restrict__ wq, int* __restrict__ idxout)
{
  int tid = threadIdx.x;
  if (blockIdx.x < 702) {
    // ---------------- gemm1 role ----------------
    int w = tid >> 6, lane = tid & 63;
    int n = lane & 31, h = lane >> 5;
    int task = blockIdx.x*4 + w;
    if (task >= 2807) return;             // wave-uniform
    int rt = task / 7, nt = task % 7;     // rt in [0,401), 401*32 = 12832
    int row = rt*32 + n;

    const float* src;
    if (row < 6400)       src = dR + (size_t)row*200;
    else if (row < 12800) src = qR + (size_t)(row-6400)*200;
    else                  src = qL + (size_t)(row-12800)*200;

    bf16x8 afrag[13];
#pragma unroll
    for (int ks = 0; ks < 13; ks++) {
      int ko = ks*16 + h*8;
      bf16x8 af;
      if (ko < 200) {
        float4 a0 = *(const float4*)(src + ko);
        float4 a1 = *(const float4*)(src + ko + 4);
        af[0] = (__bf16)(a0.x*a0.x); af[1] = (__bf16)(a0.y*a0.y);
        af[2] = (__bf16)(a0.z*a0.z); af[3] = (__bf16)(a0.w*a0.w);
        af[4] = (__bf16)(a1.x*a1.x); af[5] = (__bf16)(a1.y*a1.y);
        af[6] = (__bf16)(a1.z*a1.z); af[7] = (__bf16)(a1.w*a1.w);
      } else {
#pragma unroll
        for (int z = 0; z < 8; z++) af[z] = (__bf16)0.0f;
      }
      afrag[ks] = af;
    }

    f32x16 C;
#pragma unroll
    for (int z = 0; z < 16; z++) C[z] = 0.f;
    const unsigned short* bp = m2b16 + (size_t)(nt*32 + n)*208 + h*8;
#pragma unroll
    for (int ks = 0; ks < 13; ks++) {
      bf16x8 bf = *(const bf16x8*)(bp + ks*16);
      C = __builtin_amdgcn_mfma_f32_32x32x16_bf16(afrag[ks], bf, C, 0, 0, 0);
    }

    int cp = nt*32 + n;                   // c' = m*50 + c
    if (cp < 200) {
      int m = cp / 50, c = cp % 50;
#pragma unroll
      for (int r = 0; r < 16; r++) {
        int grow = rt*32 + (r & 3) + 8*(r >> 2) + 4*h;
        float v = rsqrtf(fmaxf(C[r], EPS));
        if (grow < 6400) {
          if (m == 0)      invfpn[grow*50 + c] = v;
          else if (m == 1) invmpn[grow*50 + c] = v;
          else if (m == 2) invapn[grow*50 + c] = v;
          else             invxpn[grow*50 + c] = v;
        } else if (grow < 12800) {
          int r2 = grow - 6400;
          if (m == 1)      invmqn[c*6400 + r2] = v;
          else if (m == 3) invxqn[r2*50 + c] = v;
        } else {
          if (m == 0)      invfqn[(grow-12800)*50 + c] = v;
        }
      }
    }
  } else {
    // ---------------- relwq role ----------------
    __shared__ float relsh[8][256];            // 8 KB
    __shared__ float redv[4][8][2];
    __shared__ int   redi[4][8];
    __shared__ float invrs_sh[8];
    int blk = blockIdx.x - 702;
    int b  = blk / 25;
    int i0 = (blk % 25) * 8;
    int j = tid, jr = min(j, 199);
    bool jv = j < 200;
    const float* qb = qR + b*40000;
    const float* db = dR + (b*200 + i0)*200;
    float acc[8];
#pragma unroll
    for (int ii = 0; ii < 8; ii++) acc[ii] = 0.f;

    // phase 1: lane=j, q row read direct from global (L2-resident).
    // Same k-ascending 4-chunk fma order as r9 -> bit-identical rel/argmax.
    const float* qrow = qb + jr*200;
    for (int k4 = 0; k4 < 200; k4 += 4) {
      float4 qv = *(const float4*)(qrow + k4);
#pragma unroll
      for (int ii = 0; ii < 8; ii++) {
        acc[ii] = fmaf(db[ii*200 + k4 + 0], qv.x, acc[ii]);
        acc[ii] = fmaf(db[ii*200 + k4 + 1], qv.y, acc[ii]);
        acc[ii] = fmaf(db[ii*200 + k4 + 2], qv.z, acc[ii]);
        acc[ii] = fmaf(db[ii*200 + k4 + 3], qv.w, acc[ii]);
      }
    }

    float iqn = invqn[b*200 + jr];
    float qm  = qMask[b*200 + jr];
    int w = tid >> 6, l = tid & 63;
    float rv[8];
#pragma unroll
    for (int ii = 0; ii < 8; ii++) {
      float idn = invdn[b*200 + i0 + ii];
      float dm  = dMask[b*200 + i0 + ii];
      float r = acc[ii]*iqn*idn*qm*dm;
      rv[ii] = r;
      relsh[ii][j] = jv ? r : 0.f;
    }
#pragma unroll
    for (int ii = 0; ii < 8; ii++) {
      float vm = jv ? rv[ii] : NEG_HUGE;
      float vs = jv ? rv[ii] : 0.f;
      int bj = jr;
#pragma unroll
      for (int m = 32; m; m >>= 1) {
        float ov = __shfl_xor(vm, m);
        int   oj = __shfl_xor(bj, m);
        vs += __shfl_xor(vs, m);
        if (ov > vm || (ov == vm && oj < bj)) { vm = ov; bj = oj; }  // first-max
      }
      if (l == 0) { redv[w][ii][0] = vm; redv[w][ii][1] = vs; redi[w][ii] = bj; }
    }
    __syncthreads();
    if (tid < 8) {
      float bv = redv[0][tid][0], ss = redv[0][tid][1]; int bj = redi[0][tid];
      for (int w2 = 1; w2 < 4; w2++) {
        ss += redv[w2][tid][1];
        float wv = redv[w2][tid][0]; int wj = redi[w2][tid];
        if (wv > bv || (wv == bv && wj < bj)) { bv = wv; bj = wj; }
      }
      invrs_sh[tid] = 1.f/(ss + EPS);
      idxout[b*200 + i0 + tid] = bj;
    }
    __syncthreads();

    // phase 2: lane = k
    int kl = min(tid, 199); bool kv = tid < 200;
    float acw[8];
#pragma unroll
    for (int ii = 0; ii < 8; ii++) acw[ii] = 0.f;
    for (int j0 = 0; j0 < 200; j0 += 4) {
      float qv0 = qb[(j0+0)*200 + kl];
      float qv1 = qb[(j0+1)*200 + kl];
      float qv2 = qb[(j0+2)*200 + kl];
      float qv3 = qb[(j0+3)*200 + kl];
#pragma unroll
      for (int ii = 0; ii < 8; ii++) {
        float4 rs = *(const float4*)&relsh[ii][j0];
        acw[ii] = fmaf(rs.x, qv0, acw[ii]);
        acw[ii] = fmaf(rs.y, qv1, acw[ii]);
        acw[ii] = fmaf(rs.z, qv2, acw[ii]);
        acw[ii] = fmaf(rs.w, qv3, acw[ii]);
      }
    }
#pragma unroll
    for (int ii = 0; ii < 8; ii++) {
      float v = acw[ii]*invrs_sh[ii];
      if (kv) wq[(size_t)(b*200 + i0 + ii)*200 + tid] = v;
    }
  }
}

// k_big: blocks [0,1600) = maxpool (long pole, dispatched first);
// blocks [1600,1800) = gemm2 (8 wave-tasks per 512-thr block, 1600 tasks).
__global__ __launch_bounds__(512,2) void k_big(
    const unsigned short* __restrict__ db16, const unsigned short* __restrict__ qb16,
    const float* __restrict__ m2all, const float* __restrict__ invmqn,
    float* __restrict__ pmax2, float* __restrict__ psum2,
    const float* __restrict__ dR, const float* __restrict__ qR,
    const float* __restrict__ qL, const float* __restrict__ wq,
    const int* __restrict__ idx, const unsigned short* __restrict__ m2b16,
    float* __restrict__ G)
{
  int tid = threadIdx.x;
  int w = tid >> 6, lane = tid & 63;
  int n = lane & 31, h = lane >> 5;
  if (blockIdx.x < 1600) {
    // ---------------- maxpool role (identical to r9 v6) ----------------
    __shared__ __align__(16) unsigned short qsh[128*216];  // 55296 B
    int b = blockIdx.x / 50, c = blockIdx.x % 50;
    const float* M2 = m2all + 10000 + c*200;
    const unsigned short* dbp = db16 + (size_t)(b*256 + w*32 + n)*208 + h*8;

    bf16x8 afrag[13];
#pragma unroll
    for (int ks = 0; ks < 13; ks++) afrag[ks] = *(const bf16x8*)(dbp + ks*16);

    float vm[16], vs[16];
#pragma unroll
    for (int r = 0; r < 16; r++) { vm[r] = NEG_HUGE; vs[r] = 0.f; }

    for (int jh = 0; jh < 2; jh++) {
      int nrows = jh ? 96 : 128;
      int njt   = jh ? 3 : 4;
      __syncthreads();
      {
        const unsigned short* src = qb16 + (size_t)(b*256 + jh*128)*208;
        const float* iqb = invmqn + c*6400 + b*200;
        for (int s = tid; s < nrows*26; s += 512) {
          int r = s / 26, ch = s - r*26;
          int j = jh*128 + r;
          float iq = (j < 200) ? iqb[j] : 0.f;
          int k0 = ch*8;
          bf16x8 v = *(const bf16x8*)(src + (size_t)r*208 + k0);
          float4 m0 = *(const float4*)(M2 + k0);     // k0=200 reads past-row
          float4 m1 = *(const float4*)(M2 + k0 + 4); // data: finite, x0=0. ok
          bf16x8 o;
          o[0] = (__bf16)((float)v[0]*iq*m0.x); o[1] = (__bf16)((float)v[1]*iq*m0.y);
          o[2] = (__bf16)((float)v[2]*iq*m0.z); o[3] = (__bf16)((float)v[3]*iq*m0.w);
          o[4] = (__bf16)((float)v[4]*iq*m1.x); o[5] = (__bf16)((float)v[5]*iq*m1.y);
          o[6] = (__bf16)((float)v[6]*iq*m1.z); o[7] = (__bf16)((float)v[7]*iq*m1.w);
          *(bf16x8*)(qsh + r*216 + k0) = o;
        }
      }
      __syncthreads();

      for (int jt = 0; jt < njt; jt++) {
        f32x16 C;
#pragma unroll
        for (int z = 0; z < 16; z++) C[z] = 0.f;
        const unsigned short* bptr = qsh + (jt*32 + n)*216 + h*8;
#pragma unroll
        for (int ks = 0; ks < 13; ks++) {
          bf16x8 bf = *(const bf16x8*)(bptr + ks*16);
          C = __builtin_amdgcn_mfma_f32_32x32x16_bf16(afrag[ks], bf, C, 0, 0, 0);
        }
        bool jv = (jh*128 + jt*32 + n) < 200;
#pragma unroll
        for (int r = 0; r < 16; r++) {
          vm[r] = fmaxf(vm[r], jv ? C[r] : NEG_HUGE);
          vs[r] += C[r];
        }
      }
    }

#pragma unroll
    for (int r = 0; r < 16; r++) {
      float a = vm[r], s = vs[r];
#pragma unroll
      for (int m = 1; m <= 16; m <<= 1) {
        a = fmaxf(a, __shfl_xor(a, m));
        s += __shfl_xor(s, m);
      }
      vm[r] = a; vs[r] = s;
    }
    if (n == 0) {
#pragma unroll
      for (int r = 0; r < 16; r++) {
        int i = w*32 + (r & 3) + 8*(r >> 2) + 4*h;
        pmax2[(size_t)blockIdx.x*256 + i] = vm[r];
        psum2[(size_t)blockIdx.x*256 + i] = vs[r];
      }
    }
  } else {
    // ---------------- gemm2 role ----------------
    int task = (blockIdx.x - 1600)*8 + w;    // [0,1600)
    int mp = task / 400;
    int sub = task % 400;
    int rt = sub >> 1, nt = sub & 1;
    int row = rt*32 + n;                     // < 6400
    int bb = row / 200;
    int msel = (mp == 0) ? 0 : (mp == 3) ? 3 : 2;

    const float* s0 = dR + (size_t)row*200;
    const float* s1;
    if (mp == 0)      s1 = qL + (size_t)bb*200;
    else if (mp == 1) s1 = wq + (size_t)row*200;
    else if (mp == 2) { s0 = wq + (size_t)row*200; s1 = s0; }
    else              s1 = qR + (size_t)(bb*200 + idx[row])*200;

    bf16x8 afrag[13];
#pragma unroll
    for (int ks = 0; ks < 13; ks++) {
      int ko = ks*16 + h*8;
      bf16x8 af;
      if (ko < 200) {
        float4 a0 = *(const float4*)(s0 + ko);
        float4 a1 = *(const float4*)(s0 + ko + 4);
        float4 b0 = *(const float4*)(s1 + ko);
        float4 b1 = *(const float4*)(s1 + ko + 4);
        af[0] = (__bf16)(a0.x*b0.x); af[1] = (__bf16)(a0.y*b0.y);
        af[2] = (__bf16)(a0.z*b0.z); af[3] = (__bf16)(a0.w*b0.w);
        af[4] = (__bf16)(a1.x*b1.x); af[5] = (__bf16)(a1.y*b1.y);
        af[6] = (__bf16)(a1.z*b1.z); af[7] = (__bf16)(a1.w*b1.w);
      } else {
#pragma unroll
        for (int z = 0; z < 8; z++) af[z] = (__bf16)0.0f;
      }
      afrag[ks] = af;
    }

    f32x16 C;
#pragma unroll
    for (int z = 0; z < 16; z++) C[z] = 0.f;
    const unsigned short* bp = m2b16 + (size_t)(msel*50 + nt*32 + n)*208 + h*8;
#pragma unroll
    for (int ks = 0; ks < 13; ks++) {
      bf16x8 bf = *(const bf16x8*)(bp + ks*16);
      C = __builtin_amdgcn_mfma_f32_32x32x16_bf16(afrag[ks], bf, C, 0, 0, 0);
    }
    int cc = nt*32 + n;
    if (cc < 50) {
#pragma unroll
      for (int r = 0; r < 16; r++) {
        int mrow = (r & 3) + 8*(r >> 2) + 4*h;
        G[(size_t)(mp*6400 + rt*32 + mrow)*50 + cc] = C[r];
      }
    }
  }
}

// Final assembly: out[row][0:250] written lane-coalesced.
__global__ void k_out(
    const float* __restrict__ G, const float* __restrict__ pmax2,
    const float* __restrict__ psum2, const float* __restrict__ invfpn,
    const float* __restrict__ invmpn, const float* __restrict__ invapn,
    const float* __restrict__ invxpn, const float* __restrict__ invfqn,
    const float* __restrict__ invxqn, const int* __restrict__ idx,
    float* __restrict__ out)
{
  int row = blockIdx.x;
  int l = threadIdx.x;
  if (l >= 250) return;
  int b = row / 200, i = row % 200;
  int seg = l / 50, c = l % 50;
  float o;
  if (seg == 0) {
    o = G[(size_t)(0*6400 + row)*50 + c] * invfpn[row*50 + c] * invfqn[b*50 + c];
  } else if (seg == 1) {
    o = pmax2[(size_t)(b*50 + c)*256 + i] * invmpn[row*50 + c];
  } else if (seg == 2) {
    o = psum2[(size_t)(b*50 + c)*256 + i] * invmpn[row*50 + c] * (1.f/200.f);
  } else if (seg == 3) {
    o = G[(size_t)(1*6400 + row)*50 + c] * invapn[row*50 + c]
        * rsqrtf(fmaxf(G[(size_t)(2*6400 + row)*50 + c], EPS));
  } else {
    int jid = idx[row];
    o = G[(size_t)(3*6400 + row)*50 + c] * invxpn[row*50 + c]
        * invxqn[(b*200 + jid)*50 + c];
  }
  out[(size_t)row*250 + l] = o;
}

extern "C" void kernel_launch(void* const* d_in, const int* in_sizes, int n_in,
                              void* d_out, int out_size, void* d_ws, size_t ws_size,
                              hipStream_t stream) {
  const float* qR = (const float*)d_in[0];
  const float* qL = (const float*)d_in[1];
  const float* qM = (const float*)d_in[2];
  const float* dR = (const float*)d_in[3];
  // d_in[4] = d_last: unused by the reference
  const float* dM = (const float*)d_in[5];
  const float* fullM = (const float*)d_in[6];
  const float* mpM   = (const float*)d_in[7];
  const float* attM  = (const float*)d_in[8];
  const float* xM    = (const float*)d_in[9];

  float* ws  = (float*)d_ws;
  float* out = (float*)d_out;

  float* m2all  = ws + OFF_M2ALL;
  unsigned short* m2b16 = (unsigned short*)(ws + OFF_M2B16);
  unsigned short* qb16 = (unsigned short*)(ws + OFF_QB16);
  unsigned short* db16 = (unsigned short*)(ws + OFF_DB16);
  float* invfpn = ws + OFF_INVFPN;
  float* invmpn = ws + OFF_INVMPN;
  float* invapn = ws + OFF_INVAPN;
  float* invxpn = ws + OFF_INVXPN;
  float* invmqn = ws + OFF_INVMQN;
  float* invxqn = ws + OFF_INVXQN;
  float* invfqn = ws + OFF_INVFQN;
  float* invdn  = ws + OFF_INVDN;
  float* invqn  = ws + OFF_INVQN;
  int*   idxp   = (int*)(ws + OFF_IDX);
  float* wqp    = ws + OFF_WQ;
  float* G      = ws + OFF_G;
  float* pmax2  = ws + OFF_PMAX2;
  float* psum2  = ws + OFF_PSUM2;

  k_prep<<<4278, 256, 0, stream>>>(qR, dR, fullM, mpM, attM, xM,
                                   qb16, db16, invdn, invqn, m2all, m2b16);
  k_mid<<<1502, 256, 0, stream>>>(dR, qR, qL, m2b16,
                                  invfpn, invmpn, invapn, invxpn,
                                  invmqn, invxqn, invfqn,
                                  qM, dM, invdn, invqn, wqp, idxp);
  k_big<<<1800, 512, 0, stream>>>(db16, qb16, m2all, invmqn, pmax2, psum2,
                                  dR, qR, qL, wqp, idxp, m2b16, G);
  k_out<<<6400, 256, 0, stream>>>(G, pmax2, psum2, invfpn, invmpn, invapn,
                                  invxpn, invfqn, invxqn, idxp, out);
}